// Round 1
// baseline (405.723 us; speedup 1.0000x reference)
//
#include <hip/hip_runtime.h>
#include <hip/hip_cooperative_groups.h>
#include <cmath>

#pragma clang fp contract(off)

namespace cg = cooperative_groups;

typedef unsigned int u32;
typedef unsigned short u16;
typedef unsigned long long u64;

#define K_PER_LVL 1000
#define KTOT 5000            // 5 levels * 1000
#define NIMG 2
#define BINS 16384           // histogram bins = top 14 bits of fkey (binade/32)
#define BIN_SHIFT 18
#define SEGW (BINS / 256)    // 64 bins per resolve segment
#define EQ_CAP 2048
#define ECAP 32768           // max suppression edges per image (est ~4k; 8x margin)
#define LECAP 24576          // edges held in LDS; overflow spills to global
#define CBUF 1024            // per-block staging capacity in compact
#define RNK_IB 512           // rank: i-candidates per block (2 per thread)
#define RNK_JB 250           // rank: j-keys per block
#define RNK_NJ (KTOT / RNK_JB)   // 20 j-blocks
#define RNK_TILES 200        // 10 i-blk * 20 j-blk
#define EDGE_TILES 820       // sum_{bi=0..19} (79 - 4*bi)
#define NTILES (RNK_TILES + EDGE_TILES)
#define GRID_ALL 256         // cooperative grid: 1 block/CU (LDS-limited), 256 CUs

__constant__ int c_LG[5] = {512, 256, 128, 64, 32};      // grid dim (square)
__constant__ int c_LS[5] = {4, 8, 16, 32, 64};           // stride
__constant__ int c_LZ[5] = {32, 64, 128, 256, 512};      // anchor size
__constant__ int c_LM[5] = {786432, 196608, 49152, 12288, 3072}; // 3*G*G

struct Ptrs { const float* o[5]; const float* b[5]; };

struct Args {
    Ptrs P;
    u32* hist; u32* gcnt; u32* ecnt; u32* gec;
    int* binB; int* kneed; int* g0; int* sel;
    u64* eq; u64* key64;
    float* csc; float* cbox; float* cobox;
    u32* pairs; u16* espill; u32* rpart;
    float* out;
};

// monotone float -> uint key (larger float => larger key)
__device__ inline u32 fkey(float f) {
    u32 u = __float_as_uint(f);
    return (u & 0x80000000u) ? ~u : (u | 0x80000000u);
}

// block -> (p, slice, nslices) work-proportional mapping for hist/compact.
// Per image (128 blocks): L0:94, L1:24, L2:6, L3:2, L4:2.
__device__ inline void histMap(int b, int& p, int& sl, int& nsl) {
    int n = b >> 7, r = b & 127;
    int l, s0, c;
    if (r < 94)       { l = 0; s0 = 0;   c = 94; }
    else if (r < 118) { l = 1; s0 = 94;  c = 24; }
    else if (r < 124) { l = 2; s0 = 118; c = 6;  }
    else if (r < 126) { l = 3; s0 = 124; c = 2;  }
    else              { l = 4; s0 = 126; c = 2;  }
    p = n * 5 + l; sl = r - s0; nsl = c;
}

// featurize one selected candidate (anchor + decode + clip + score + 64b order key)
__device__ inline void featOneM(const Args& A, int p, int s, int m) {
    int n = p / 5, l = p % 5;
    int G = c_LG[l], S = c_LS[l], Z = c_LZ[l];
    int gg = G * G;
    int a = m % 3; int pix = m / 3; int h = pix / G; int w = pix - h * G;

    const float ars[3] = {0.5f, 1.0f, 2.0f};
    float ar = ars[a];
    float hr = sqrtf(ar), wr = 1.0f / hr;
    float wsz = wr * (float)Z, hsz = hr * (float)Z;
    float bx1 = rintf(-0.5f * wsz), by1 = rintf(-0.5f * hsz);
    float bx2 = rintf(0.5f * wsz),  by2 = rintf(0.5f * hsz);
    float sx = (float)(w * S), sy = (float)(h * S);
    float ax1 = sx + bx1, ay1 = sy + by1, ax2 = sx + bx2, ay2 = sy + by2;
    float wa = ax2 - ax1, ha = ay2 - ay1;
    float cxa = ax1 + 0.5f * wa, cya = ay1 + 0.5f * ha;

    const float* bb = A.P.b[l] + (size_t)n * 12 * gg;
    float dx = bb[(a * 4 + 0) * gg + pix];
    float dy = bb[(a * 4 + 1) * gg + pix];
    const float CLIPV = 4.135166556742356f;  // log(1000/16)
    float dw = fminf(bb[(a * 4 + 2) * gg + pix], CLIPV);
    float dh = fminf(bb[(a * 4 + 3) * gg + pix], CLIPV);
    float cx = dx * wa + cxa, cy = dy * ha + cya;
    float ww = expf(dw) * wa, hh = expf(dh) * ha;
    float x1 = cx - 0.5f * ww, y1 = cy - 0.5f * hh;
    float x2 = cx + 0.5f * ww, y2 = cy + 0.5f * hh;
    x1 = fminf(fmaxf(x1, 0.f), 2048.f);
    y1 = fminf(fmaxf(y1, 0.f), 2048.f);
    x2 = fminf(fmaxf(x2, 0.f), 2048.f);
    y2 = fminf(fmaxf(y2, 0.f), 2048.f);

    float raw = A.P.o[l][(size_t)n * 3 * gg + a * gg + pix];
    float sc = 1.0f / (1.0f + expf(-raw));
    bool keep = (x2 - x1 >= 1e-3f) && (y2 - y1 >= 1e-3f) && (sc > 0.0f);

    int slot = n * KTOT + l * K_PER_LVL + s;
    u32 tb = ((u32)l << 20) | (u32)m;          // m < 2^20, l < 8 -> unique
    u32 kk = keep ? fkey(raw) : 0u;
    A.key64[slot] = ((u64)kk << 23) | (u64)(tb ^ 0x7FFFFFu);

    A.csc[slot] = keep ? sc : -INFINITY;
    A.cbox[slot * 4 + 0] = x1; A.cbox[slot * 4 + 1] = y1;
    A.cbox[slot * 4 + 2] = x2; A.cbox[slot * 4 + 3] = y2;
    float off = 4097.0f * (float)l;            // lvl * (W+H+1), batched_nms offset
    A.cobox[slot * 4 + 0] = x1 + off; A.cobox[slot * 4 + 1] = y1 + off;
    A.cobox[slot * 4 + 2] = x2 + off; A.cobox[slot * 4 + 3] = y2 + off;
}

// ---------------- LDS union shared by all phases of the mega-kernel ----------------
struct __align__(16) SmHist { u32 lh[BINS]; };                       // 64 KB
struct __align__(16) SmResolve { u32 seg[256]; u32 tail[SEGW]; int sgS; u32 GS; };
struct __align__(16) SmCompact { u64 leq[CBUF]; u32 lsel[CBUF]; u32 cSel, cEq, baseSel, baseEq; };
struct __align__(16) SmEqsel { u64 a[EQ_CAP]; };                     // 16 KB
struct __align__(16) SmRedge { u64 kj[RNK_JB]; float cb[64][4]; };
struct __align__(16) SmNms {
    u32 cnt[KTOT];           // 20 KB (count, then fill cursor)
    u32 offs[KTOT + 1];      // 20 KB
    u32 rem32[160];          // dead bitmap (2 u32 per 64-word)
    u32 colLo[64], colHi[64];
    u32 scanb[256];
    int picksS;
    u16 rankL[KTOT];         // rank of original index
    u16 invL[KTOT];          // original index of rank
    u16 edges[LECAP];        // 48 KB
};
union SmAll { SmHist h; SmResolve r; SmCompact c; SmEqsel e; SmRedge g; SmNms n; };
static_assert(sizeof(SmAll) <= 160 * 1024, "LDS union too large");

// ---------------- workspace layout (shared by coop + fallback paths) ----------------
constexpr size_t OFF_HIST   = 0;
constexpr size_t OFF_GCNT   = OFF_HIST + 10 * BINS * 4;
constexpr size_t OFF_ECNT   = OFF_GCNT + 64;
constexpr size_t OFF_GEC    = OFF_ECNT + 64;
constexpr size_t ZERO_WORDS = (10 * BINS * 4 + 192) / 4;
constexpr size_t OFF_BINB   = OFF_GEC + 64;
constexpr size_t OFF_KNEED  = OFF_BINB + 64;
constexpr size_t OFF_G0     = OFF_KNEED + 64;
constexpr size_t OFF_SEL    = OFF_G0 + 64;
constexpr size_t OFF_EQ     = OFF_SEL + 10 * K_PER_LVL * 4;
constexpr size_t OFF_KEY64  = OFF_EQ + (size_t)10 * EQ_CAP * 8;
constexpr size_t OFF_CSC    = OFF_KEY64 + (size_t)NIMG * KTOT * 8;
constexpr size_t OFF_CBOX   = OFF_CSC + (size_t)NIMG * KTOT * 4;
constexpr size_t OFF_COBOX  = OFF_CBOX + (size_t)NIMG * KTOT * 16;
constexpr size_t OFF_SSC    = OFF_COBOX + (size_t)NIMG * KTOT * 16;   // fallback only
constexpr size_t OFF_SBOX   = OFF_SSC + (size_t)NIMG * KTOT * 4;      // fallback only
constexpr size_t OFF_RANK   = OFF_SBOX + (size_t)NIMG * KTOT * 16;    // fallback only
constexpr size_t OFF_PAIRS  = OFF_RANK + (size_t)NIMG * KTOT * 4;
constexpr size_t OFF_ESPILL = OFF_PAIRS + (size_t)NIMG * ECAP * 4;
constexpr size_t OFF_RPART  = OFF_ESPILL + (size_t)NIMG * ECAP * 2;
constexpr size_t WS_NEEDED  = OFF_RPART + (size_t)RNK_NJ * NIMG * KTOT * 4;

// ==================================================================================
//   COOPERATIVE MEGA-KERNEL: 7 phases, 6 grid syncs, one dispatch
// ==================================================================================
__global__ __launch_bounds__(256, 1) void k_all(Args A) {
    cg::grid_group grid = cg::this_grid();
    __shared__ SmAll sm;
    const int tid = threadIdx.x;
    const int b = blockIdx.x;

    // ---- P0: zero hist + counters ----
    {
        const int nw = (int)ZERO_WORDS;
        for (int i = b * 256 + tid; i < nw; i += GRID_ALL * 256) A.hist[i] = 0;
    }
    grid.sync();

    // ---- P1: one-pass 16384-bin histogram (LDS pre-agg, weighted block map) ----
    {
        int p, sl, nsl; histMap(b, p, sl, nsl);
        int l = p % 5, n = p / 5;
        int M4 = c_LM[l] >> 2;
        const float4* base = (const float4*)(A.P.o[l] + (size_t)n * c_LM[l]);
        for (int i = tid; i < BINS; i += 256) sm.h.lh[i] = 0;
        __syncthreads();
        for (int i = sl * 256 + tid; i < M4; i += nsl * 256) {
            float4 v = base[i];
            atomicAdd(&sm.h.lh[fkey(v.x) >> BIN_SHIFT], 1u);
            atomicAdd(&sm.h.lh[fkey(v.y) >> BIN_SHIFT], 1u);
            atomicAdd(&sm.h.lh[fkey(v.z) >> BIN_SHIFT], 1u);
            atomicAdd(&sm.h.lh[fkey(v.w) >> BIN_SHIFT], 1u);
        }
        __syncthreads();
        for (int i = tid; i < BINS; i += 256) {
            u32 c = sm.h.lh[i];
            if (c) atomicAdd(&A.hist[p * BINS + i], c);
        }
    }
    grid.sync();

    // ---- P2: resolve threshold bin per (n,l) [blocks 0..9] ----
    if (b < 10) {
        int p = b, t = tid;
        u32 s = 0;
        const u32* hb = A.hist + p * BINS;
        int base0 = t * SEGW;
        for (int q = 0; q < SEGW; ++q) s += hb[base0 + q];
        sm.r.seg[t] = s;
        __syncthreads();
        if (t == 0) {
            u32 G = 0; int sg = 255;
            for (; sg > 0; --sg) {
                if (G + sm.r.seg[sg] >= (u32)K_PER_LVL) break;
                G += sm.r.seg[sg];
            }
            sm.r.sgS = sg; sm.r.GS = G;
        }
        __syncthreads();
        int sg = sm.r.sgS;
        if (t < SEGW) sm.r.tail[t] = hb[sg * SEGW + t];
        __syncthreads();
        if (t == 0) {
            u32 G = sm.r.GS; int B = sg * SEGW;
            for (int q = SEGW - 1; q >= 0; --q) {
                u32 c = sm.r.tail[q];
                if (G + c >= (u32)K_PER_LVL) { B = sg * SEGW + q; break; }
                G += c;
            }
            A.binB[p] = B;
            A.kneed[p] = K_PER_LVL - (int)G;
            A.g0[p] = (int)G;
        }
    }
    grid.sync();

    // ---- P3: compact (LDS staging, one reservation atomic per block) ----
    {
        int p, sl, nsl; histMap(b, p, sl, nsl);
        int l = p % 5, n = p / 5;
        int M4 = c_LM[l] >> 2; int gg = c_LM[l] / 3;
        const float4* base = (const float4*)(A.P.o[l] + (size_t)n * c_LM[l]);
        int B = A.binB[p];
        if (tid == 0) { sm.c.cSel = 0; sm.c.cEq = 0; }
        __syncthreads();
        for (int i4 = sl * 256 + tid; i4 < M4; i4 += nsl * 256) {
            float4 v = base[i4];
            float vv[4] = {v.x, v.y, v.z, v.w};
            #pragma unroll
            for (int q = 0; q < 4; ++q) {
                u32 k = fkey(vv[q]);
                int bin = (int)(k >> BIN_SHIFT);
                if (bin < B) continue;
                int i = i4 * 4 + q;
                int a = i / gg; int pix = i - a * gg; int m = pix * 3 + a;
                if (bin > B) {
                    u32 t = atomicAdd(&sm.c.cSel, 1u);
                    if (t < CBUF) sm.c.lsel[t] = (u32)m;
                    else { u32 pos = atomicAdd(&A.gcnt[p], 1u); A.sel[p * K_PER_LVL + pos] = m; }
                } else {
                    u64 pk = ((u64)k << 20) | (u64)(0xFFFFFu ^ (u32)m);
                    u32 t = atomicAdd(&sm.c.cEq, 1u);
                    if (t < CBUF) sm.c.leq[t] = pk;
                    else { u32 e = atomicAdd(&A.ecnt[p], 1u); if (e < EQ_CAP) A.eq[(size_t)p * EQ_CAP + e] = pk; }
                }
            }
        }
        __syncthreads();
        if (tid == 0) {
            u32 ns = sm.c.cSel < CBUF ? sm.c.cSel : CBUF;
            u32 ne = sm.c.cEq < CBUF ? sm.c.cEq : CBUF;
            sm.c.baseSel = ns ? atomicAdd(&A.gcnt[p], ns) : 0u;
            sm.c.baseEq  = ne ? atomicAdd(&A.ecnt[p], ne) : 0u;
        }
        __syncthreads();
        u32 ns = sm.c.cSel < CBUF ? sm.c.cSel : CBUF;
        u32 ne = sm.c.cEq < CBUF ? sm.c.cEq : CBUF;
        for (u32 i = tid; i < ns; i += 256) A.sel[p * K_PER_LVL + sm.c.baseSel + i] = (int)sm.c.lsel[i];
        for (u32 i = tid; i < ne; i += 256) {
            u32 slot = sm.c.baseEq + i;
            if (slot < EQ_CAP) A.eq[(size_t)p * EQ_CAP + slot] = sm.c.leq[i];
        }
    }
    grid.sync();

    // ---- P4: eqsel (blocks 0..9, feeds its boundary items straight to feat)
    //          + main feat (blocks 10..255) ----
    if (b < 10) {
        int p = b, t = tid;
        int E = (int)A.ecnt[p]; if (E > EQ_CAP) E = EQ_CAP;
        int KF = A.kneed[p]; int G0 = A.g0[p];
        for (int i = t; i < E; i += 256) sm.e.a[i] = A.eq[(size_t)p * EQ_CAP + i];
        __syncthreads();
        u64 mine[8]; int rk[8];
        #pragma unroll
        for (int q = 0; q < 8; ++q) {
            int i = t + q * 256;
            mine[q] = (i < E) ? sm.e.a[i] : 0ULL;
            rk[q] = 0;
        }
        for (int j = 0; j < E; ++j) {
            u64 v = sm.e.a[j];
            #pragma unroll
            for (int q = 0; q < 8; ++q) rk[q] += (v > mine[q]) ? 1 : 0;
        }
        #pragma unroll
        for (int q = 0; q < 8; ++q) {
            int i = t + q * 256;
            if (i < E && rk[q] < KF) {
                int m = (int)(0xFFFFFu ^ (u32)(mine[q] & 0xFFFFFu));
                featOneM(A, p, G0 + rk[q], m);   // boundary slot, m known in-register
            }
        }
    } else {
        for (int idx = (b - 10) * 256 + tid; idx < 10 * K_PER_LVL; idx += (GRID_ALL - 10) * 256) {
            int p = idx / K_PER_LVL, s = idx - p * K_PER_LVL;
            if (s < A.g0[p]) featOneM(A, p, s, A.sel[p * K_PER_LVL + s]);
        }
    }
    grid.sync();

    // ---- P5: rank partials + IoU edges, tiles looped over all blocks ----
    for (int tile = b; tile < NIMG * NTILES; tile += GRID_ALL) {
        int n = tile / NTILES;
        int x = tile - n * NTILES;
        if (x < RNK_TILES) {
            int i0 = (x / 20) * RNK_IB;
            int j0 = (x % 20) * RNK_JB;
            const u64* kb = A.key64 + (size_t)n * KTOT;
            for (int t = tid; t < RNK_JB; t += 256) sm.g.kj[t] = kb[j0 + t];
            __syncthreads();
            int i1 = i0 + tid, i2 = i1 + 256;
            u64 k1 = (i1 < KTOT) ? kb[i1] : ~0ULL;
            u64 k2 = (i2 < KTOT) ? kb[i2] : ~0ULL;
            u32 r1 = 0, r2 = 0;
            #pragma unroll 10
            for (int j = 0; j < RNK_JB; ++j) {
                u64 v = sm.g.kj[j];
                r1 += (v > k1) ? 1u : 0u;
                r2 += (v > k2) ? 1u : 0u;
            }
            u32* rp = A.rpart + (size_t)(x % 20) * (NIMG * KTOT) + n * KTOT;
            if (i1 < KTOT) rp[i1] = r1;
            if (i2 < KTOT) rp[i2] = r2;
        } else {
            int e = x - RNK_TILES, bi = 0;
            while (true) { int c = 79 - 4 * bi; if (e < c) break; e -= c; ++bi; }
            int bj = 4 * bi + e;
            int i = bi * 256 + tid;
            int j0 = bj * 64;
            if (tid < 64) {
                int jl = j0 + tid;
                if (jl < KTOT) {
                    sm.g.cb[tid][0] = A.cobox[(size_t)(n * KTOT + jl) * 4 + 0];
                    sm.g.cb[tid][1] = A.cobox[(size_t)(n * KTOT + jl) * 4 + 1];
                    sm.g.cb[tid][2] = A.cobox[(size_t)(n * KTOT + jl) * 4 + 2];
                    sm.g.cb[tid][3] = A.cobox[(size_t)(n * KTOT + jl) * 4 + 3];
                } else {
                    sm.g.cb[tid][0] = 0.f; sm.g.cb[tid][1] = 0.f;
                    sm.g.cb[tid][2] = 0.f; sm.g.cb[tid][3] = 0.f;
                }
            }
            __syncthreads();
            if (i < KTOT) {
                float x1 = A.cobox[(size_t)(n * KTOT + i) * 4 + 0];
                float y1 = A.cobox[(size_t)(n * KTOT + i) * 4 + 1];
                float x2 = A.cobox[(size_t)(n * KTOT + i) * 4 + 2];
                float y2 = A.cobox[(size_t)(n * KTOT + i) * 4 + 3];
                float areai = fmaxf(x2 - x1, 0.f) * fmaxf(y2 - y1, 0.f);
                int lim = KTOT - j0; if (lim > 64) lim = 64;
                for (int jj = 0; jj < lim; ++jj) {
                    int j = j0 + jj;
                    if (j <= i) continue;
                    float bx1 = sm.g.cb[jj][0], by1 = sm.g.cb[jj][1];
                    float bx2 = sm.g.cb[jj][2], by2 = sm.g.cb[jj][3];
                    float areaj = fmaxf(bx2 - bx1, 0.f) * fmaxf(by2 - by1, 0.f);
                    float ltx = fmaxf(x1, bx1), lty = fmaxf(y1, by1);
                    float rbx = fminf(x2, bx2), rby = fminf(y2, by2);
                    float iw = fmaxf(rbx - ltx, 0.f), ih = fmaxf(rby - lty, 0.f);
                    float inter = iw * ih;
                    float iou = inter / (areai + areaj - inter + 1e-9f);
                    if (iou > 0.7f) {
                        u32 pos = atomicAdd(&A.gec[n], 1u);
                        if (pos < ECAP) A.pairs[(size_t)n * ECAP + pos] = ((u32)i << 13) | (u32)j;
                    }
                }
            }
        }
        __syncthreads();   // LDS reused next tile
    }
    grid.sync();

    // ---- P6: fused scat + greedy NMS sweep [blocks 0..1, one per image] ----
    if (b >= NIMG) return;
    {
        int n = b;
        int lane = tid & 63, wv = tid >> 6;
        SmNms& S = sm.n;

        for (int i = tid; i < KTOT; i += 256) S.cnt[i] = 0;
        if (tid < 160) S.rem32[tid] = 0;
        __syncthreads();

        // ranks from partials; inverse map; dead bits by rank
        for (int i = tid; i < KTOT; i += 256) {
            u32 r = 0;
            #pragma unroll
            for (int jb = 0; jb < RNK_NJ; ++jb)
                r += A.rpart[(size_t)jb * (NIMG * KTOT) + n * KTOT + i];
            S.rankL[i] = (u16)r;
            S.invL[r] = (u16)i;
            if (!(A.csc[n * KTOT + i] > -INFINITY))
                atomicOr(&S.rem32[r >> 5], 1u << (r & 31));
        }
        __syncthreads();
        if (tid == 0) {  // pad ranks 5000..5119 dead (words 78 tail + 79)
            S.rem32[156] |= 0xFFFFFF00u;
            S.rem32[157] = 0xFFFFFFFFu;
            S.rem32[158] = 0xFFFFFFFFu;
            S.rem32[159] = 0xFFFFFFFFu;
        }

        // ---- CSR build: pairs are original indices; remap via rankL ----
        int E = (int)A.gec[n]; if (E > ECAP) E = ECAP;
        for (int k = tid; k < E; k += 256) {
            u32 pr = A.pairs[(size_t)n * ECAP + k];
            u32 ra = S.rankL[pr >> 13], rb = S.rankL[pr & 0x1FFFu];
            u32 src = ra < rb ? ra : rb;
            atomicAdd(&S.cnt[src], 1u);
        }
        __syncthreads();
        u32 s0 = 0; int base0 = tid * 20;
        if (tid < 250) for (int q = 0; q < 20; ++q) s0 += S.cnt[base0 + q];
        S.scanb[tid] = s0;
        __syncthreads();
        for (int off = 1; off < 256; off <<= 1) {
            u32 v = (tid >= off) ? S.scanb[tid - off] : 0;
            __syncthreads();
            S.scanb[tid] += v;
            __syncthreads();
        }
        u32 tbase = (tid == 0) ? 0u : S.scanb[tid - 1];
        if (tid < 250) {
            u32 run = tbase;
            for (int q = 0; q < 20; ++q) { S.offs[base0 + q] = run; run += S.cnt[base0 + q]; }
        }
        if (tid == 0) S.offs[KTOT] = S.scanb[255];
        __syncthreads();
        for (int i = tid; i < KTOT; i += 256) S.cnt[i] = 0;
        __syncthreads();
        for (int k = tid; k < E; k += 256) {
            u32 pr = A.pairs[(size_t)n * ECAP + k];
            u32 ra = S.rankL[pr >> 13], rb = S.rankL[pr & 0x1FFFu];
            u32 src = ra < rb ? ra : rb, dst = ra < rb ? rb : ra;
            u32 slot = S.offs[src] + atomicAdd(&S.cnt[src], 1u);
            if (slot < LECAP) S.edges[slot] = (u16)dst;
            else A.espill[(size_t)n * ECAP + slot] = (u16)dst;
        }
        __syncthreads();

        // ---- wave-0 sweep in rank order; output via inverse permutation ----
        if (wv == 0) {
            int picks = 0;
            for (int w = 0; w < 79 && picks < 1000; ++w) {
                u64 rw = ((u64)S.rem32[2 * w + 1] << 32) | S.rem32[2 * w];
                u64 alive = ~rw;
                if (alive == 0ULL) continue;
                int c = w * 64 + lane;
                bool amAlive = ((alive >> lane) & 1ULL) != 0ULL;
                int e0 = 0, e1 = 0;
                if (amAlive) { e0 = (int)S.offs[c]; e1 = (int)S.offs[c + 1]; }
                S.colLo[lane] = 0; S.colHi[lane] = 0;
                bool anyIntra = false;
                for (int k = e0; k < e1; ++k) {
                    int dst = (k < LECAP) ? (int)S.edges[k] : (int)A.espill[(size_t)n * ECAP + k];
                    if ((dst >> 6) == w) {
                        if (lane < 32) atomicOr(&S.colLo[dst & 63], 1u << lane);
                        else           atomicOr(&S.colHi[dst & 63], 1u << (lane - 32));
                        anyIntra = true;
                    }
                }
                u64 cm;
                if (__ballot(anyIntra) == 0ULL) {
                    cm = alive;
                } else {
                    u64 col = ((u64)S.colHi[lane] << 32) | S.colLo[lane];
                    cm = 0ULL;
                    for (int e2 = 0; e2 < 64; ++e2) {
                        if (!((alive >> e2) & 1ULL)) continue;
                        u64 ce = __shfl(col, e2);
                        if ((cm & ce) == 0ULL) cm |= (1ULL << e2);
                    }
                }
                int allowed = 1000 - picks;
                int ncom = __popcll(cm);
                while (ncom > allowed) { cm &= ~(1ULL << (63 - __clzll(cm))); --ncom; }
                if ((cm >> lane) & 1ULL) {
                    int pos = picks + (int)__popcll(cm & ((1ULL << lane) - 1ULL));
                    int orig = (int)S.invL[c];
                    const float* bp = &A.cbox[(size_t)(n * KTOT + orig) * 4];
                    float* op = &A.out[(n * 1000 + pos) * 5];
                    op[0] = bp[0]; op[1] = bp[1]; op[2] = bp[2]; op[3] = bp[3];
                    op[4] = A.csc[n * KTOT + orig];
                    for (int k = e0; k < e1; ++k) {
                        int dst = (k < LECAP) ? (int)S.edges[k] : (int)A.espill[(size_t)n * ECAP + k];
                        atomicOr(&S.rem32[dst >> 5], 1u << (dst & 31));
                    }
                }
                picks += ncom;
            }
            if (lane == 0) S.picksS = picks;
        }
        __syncthreads();
        int picksF = S.picksS;
        int basec = (n * 1000 + picksF) * 5, cntz = (1000 - picksF) * 5;
        for (int t2 = tid; t2 < cntz; t2 += 256) A.out[basec + t2] = 0.f;
    }
}

// ==================================================================================
//   FALLBACK: original 9-kernel pipeline (used if cooperative launch unavailable)
// ==================================================================================
__global__ __launch_bounds__(256) void k_zero(u32* __restrict__ z, int nwords) {
    int i = blockIdx.x * 256 + threadIdx.x;
    int stride = gridDim.x * 256;
    for (; i < nwords; i += stride) z[i] = 0;
}

__global__ __launch_bounds__(256) void k_hist(Ptrs P, u32* __restrict__ hist) {
    int p = blockIdx.y; int l = p % 5; int n = p / 5;
    int M4 = c_LM[l] >> 2;
    const float4* base = (const float4*)(P.o[l] + (size_t)n * c_LM[l]);
    __shared__ u32 lh[BINS];
    for (int i = threadIdx.x; i < BINS; i += 256) lh[i] = 0;
    __syncthreads();
    int stride = gridDim.x * 256;
    for (int i = blockIdx.x * 256 + threadIdx.x; i < M4; i += stride) {
        float4 v = base[i];
        atomicAdd(&lh[fkey(v.x) >> BIN_SHIFT], 1u);
        atomicAdd(&lh[fkey(v.y) >> BIN_SHIFT], 1u);
        atomicAdd(&lh[fkey(v.z) >> BIN_SHIFT], 1u);
        atomicAdd(&lh[fkey(v.w) >> BIN_SHIFT], 1u);
    }
    __syncthreads();
    for (int i = threadIdx.x; i < BINS; i += 256) {
        u32 c = lh[i];
        if (c) atomicAdd(&hist[p * BINS + i], c);
    }
}

__global__ __launch_bounds__(256) void k_resolve(const u32* __restrict__ hist,
                                                 int* __restrict__ binB, int* __restrict__ kneed,
                                                 int* __restrict__ g0) {
    int p = blockIdx.x, t = threadIdx.x;
    __shared__ u32 seg[256];
    __shared__ u32 tail[SEGW];
    __shared__ int sgS; __shared__ u32 GS;
    u32 s = 0;
    const u32* hb = hist + p * BINS;
    int base = t * SEGW;
    for (int q = 0; q < SEGW; ++q) s += hb[base + q];
    seg[t] = s;
    __syncthreads();
    if (t == 0) {
        u32 G = 0; int sg = 255;
        for (; sg > 0; --sg) {
            if (G + seg[sg] >= (u32)K_PER_LVL) break;
            G += seg[sg];
        }
        sgS = sg; GS = G;
    }
    __syncthreads();
    int sg = sgS;
    if (t < SEGW) tail[t] = hb[sg * SEGW + t];
    __syncthreads();
    if (t == 0) {
        u32 G = GS; int B = sg * SEGW;
        for (int q = SEGW - 1; q >= 0; --q) {
            u32 c = tail[q];
            if (G + c >= (u32)K_PER_LVL) { B = sg * SEGW + q; break; }
            G += c;
        }
        binB[p] = B;
        kneed[p] = K_PER_LVL - (int)G;
        g0[p] = (int)G;
    }
}

__global__ __launch_bounds__(256) void k_compact(Ptrs P, const int* __restrict__ binB,
                                                 u32* gcnt, u32* ecnt,
                                                 int* __restrict__ sel, u64* __restrict__ eq) {
    int p = blockIdx.y; int l = p % 5; int n = p / 5;
    int M4 = c_LM[l] >> 2; int gg = c_LM[l] / 3;
    const float4* base = (const float4*)(P.o[l] + (size_t)n * c_LM[l]);
    int B = binB[p];
    __shared__ u32 lsel[CBUF];
    __shared__ u64 leq[CBUF];
    __shared__ u32 cSel, cEq, baseSel, baseEq;
    if (threadIdx.x == 0) { cSel = 0; cEq = 0; }
    __syncthreads();
    int stride = gridDim.x * 256;
    for (int i4 = blockIdx.x * 256 + threadIdx.x; i4 < M4; i4 += stride) {
        float4 v = base[i4];
        float vv[4] = {v.x, v.y, v.z, v.w};
        #pragma unroll
        for (int q = 0; q < 4; ++q) {
            u32 k = fkey(vv[q]);
            int bin = (int)(k >> BIN_SHIFT);
            if (bin < B) continue;
            int i = i4 * 4 + q;
            int a = i / gg; int pix = i - a * gg; int m = pix * 3 + a;
            if (bin > B) {
                u32 t = atomicAdd(&cSel, 1u);
                if (t < CBUF) lsel[t] = (u32)m;
                else { u32 pos = atomicAdd(&gcnt[p], 1u); sel[p * K_PER_LVL + pos] = m; }
            } else {
                u64 pk = ((u64)k << 20) | (u64)(0xFFFFFu ^ (u32)m);
                u32 t = atomicAdd(&cEq, 1u);
                if (t < CBUF) leq[t] = pk;
                else { u32 e = atomicAdd(&ecnt[p], 1u); if (e < EQ_CAP) eq[(size_t)p * EQ_CAP + e] = pk; }
            }
        }
    }
    __syncthreads();
    if (threadIdx.x == 0) {
        u32 ns = cSel < CBUF ? cSel : CBUF;
        u32 ne = cEq < CBUF ? cEq : CBUF;
        baseSel = ns ? atomicAdd(&gcnt[p], ns) : 0u;
        baseEq  = ne ? atomicAdd(&ecnt[p], ne) : 0u;
    }
    __syncthreads();
    u32 ns = cSel < CBUF ? cSel : CBUF;
    u32 ne = cEq < CBUF ? cEq : CBUF;
    for (u32 i = threadIdx.x; i < ns; i += 256) sel[p * K_PER_LVL + baseSel + i] = (int)lsel[i];
    for (u32 i = threadIdx.x; i < ne; i += 256) {
        u32 slot = baseEq + i;
        if (slot < EQ_CAP) eq[(size_t)p * EQ_CAP + slot] = leq[i];
    }
}

__global__ __launch_bounds__(256) void k_eqsel(const u32* __restrict__ ecnt, const int* __restrict__ kneed,
                                               const int* __restrict__ g0,
                                               const u64* __restrict__ eq, int* __restrict__ sel) {
    int p = blockIdx.x, t = threadIdx.x;
    int E = (int)ecnt[p]; if (E > EQ_CAP) E = EQ_CAP;
    int KF = kneed[p]; int G0 = g0[p];
    __shared__ u64 a[EQ_CAP];
    for (int i = t; i < E; i += 256) a[i] = eq[(size_t)p * EQ_CAP + i];
    __syncthreads();
    u64 mine[8]; int rk[8];
    #pragma unroll
    for (int q = 0; q < 8; ++q) {
        int i = t + q * 256;
        mine[q] = (i < E) ? a[i] : 0ULL;
        rk[q] = 0;
    }
    for (int j = 0; j < E; ++j) {
        u64 v = a[j];
        #pragma unroll
        for (int q = 0; q < 8; ++q) rk[q] += (v > mine[q]) ? 1 : 0;
    }
    #pragma unroll
    for (int q = 0; q < 8; ++q) {
        int i = t + q * 256;
        if (i < E && rk[q] < KF) {
            int m = (int)(0xFFFFFu ^ (u32)(mine[q] & 0xFFFFFu));
            sel[p * K_PER_LVL + G0 + rk[q]] = m;
        }
    }
}

__global__ void k_feat(Ptrs P, const int* __restrict__ sel, u64* __restrict__ key64,
                       float* __restrict__ csc, float* __restrict__ cbox, float* __restrict__ cobox) {
    int tid = blockIdx.x * 256 + threadIdx.x;
    if (tid >= NIMG * KTOT) return;
    int p = tid / K_PER_LVL, s = tid - p * K_PER_LVL;
    Args A;
    A.P = P; A.sel = (int*)sel; A.key64 = key64; A.csc = csc; A.cbox = cbox; A.cobox = cobox;
    featOneM(A, p, s, sel[p * K_PER_LVL + s]);
}

__global__ __launch_bounds__(256) void k_redge(const u64* __restrict__ key64, u32* __restrict__ rpart,
                                               const float* __restrict__ cobox,
                                               u32* __restrict__ gE, u32* __restrict__ gPairs) {
    int n = blockIdx.y;
    int x = blockIdx.x;
    __shared__ u64 kj[RNK_JB];
    __shared__ float cb[64][4];
    if (x < RNK_TILES) {
        int i0 = (x / 20) * RNK_IB;
        int j0 = (x % 20) * RNK_JB;
        const u64* kb = key64 + (size_t)n * KTOT;
        for (int t = threadIdx.x; t < RNK_JB; t += 256) kj[t] = kb[j0 + t];
        __syncthreads();
        int i1 = i0 + threadIdx.x, i2 = i1 + 256;
        u64 k1 = (i1 < KTOT) ? kb[i1] : ~0ULL;
        u64 k2 = (i2 < KTOT) ? kb[i2] : ~0ULL;
        u32 r1 = 0, r2 = 0;
        #pragma unroll 10
        for (int j = 0; j < RNK_JB; ++j) {
            u64 v = kj[j];
            r1 += (v > k1) ? 1u : 0u;
            r2 += (v > k2) ? 1u : 0u;
        }
        u32* rp = rpart + (size_t)(x % 20) * (NIMG * KTOT) + n * KTOT;
        if (i1 < KTOT) rp[i1] = r1;
        if (i2 < KTOT) rp[i2] = r2;
        return;
    }
    int e = x - RNK_TILES, bi = 0;
    while (true) { int c = 79 - 4 * bi; if (e < c) break; e -= c; ++bi; }
    int bj = 4 * bi + e;
    int i = bi * 256 + threadIdx.x;
    int j0 = bj * 64;
    if (threadIdx.x < 64) {
        int jl = j0 + threadIdx.x;
        if (jl < KTOT) {
            cb[threadIdx.x][0] = cobox[(size_t)(n * KTOT + jl) * 4 + 0];
            cb[threadIdx.x][1] = cobox[(size_t)(n * KTOT + jl) * 4 + 1];
            cb[threadIdx.x][2] = cobox[(size_t)(n * KTOT + jl) * 4 + 2];
            cb[threadIdx.x][3] = cobox[(size_t)(n * KTOT + jl) * 4 + 3];
        } else {
            cb[threadIdx.x][0] = 0.f; cb[threadIdx.x][1] = 0.f;
            cb[threadIdx.x][2] = 0.f; cb[threadIdx.x][3] = 0.f;
        }
    }
    __syncthreads();
    if (i >= KTOT) return;
    float x1 = cobox[(size_t)(n * KTOT + i) * 4 + 0];
    float y1 = cobox[(size_t)(n * KTOT + i) * 4 + 1];
    float x2 = cobox[(size_t)(n * KTOT + i) * 4 + 2];
    float y2 = cobox[(size_t)(n * KTOT + i) * 4 + 3];
    float areai = fmaxf(x2 - x1, 0.f) * fmaxf(y2 - y1, 0.f);
    int lim = KTOT - j0; if (lim > 64) lim = 64;
    for (int jj = 0; jj < lim; ++jj) {
        int j = j0 + jj;
        if (j <= i) continue;
        float bx1 = cb[jj][0], by1 = cb[jj][1], bx2 = cb[jj][2], by2 = cb[jj][3];
        float areaj = fmaxf(bx2 - bx1, 0.f) * fmaxf(by2 - by1, 0.f);
        float ltx = fmaxf(x1, bx1), lty = fmaxf(y1, by1);
        float rbx = fminf(x2, bx2), rby = fminf(y2, by2);
        float iw = fmaxf(rbx - ltx, 0.f), ih = fmaxf(rby - lty, 0.f);
        float inter = iw * ih;
        float iou = inter / (areai + areaj - inter + 1e-9f);
        if (iou > 0.7f) {
            u32 pos = atomicAdd(&gE[n], 1u);
            if (pos < ECAP) gPairs[(size_t)n * ECAP + pos] = ((u32)i << 13) | (u32)j;
        }
    }
}

__global__ __launch_bounds__(256) void k_scat(const u32* __restrict__ rpart, const float* __restrict__ csc,
                       const float* __restrict__ cbox,
                       float* __restrict__ ssc, float* __restrict__ sbox, u32* __restrict__ rankArr) {
    int n = blockIdx.y;
    int i = blockIdx.x * 256 + threadIdx.x;
    if (i >= KTOT) return;
    int idx = n * KTOT + i;
    u32 rank = 0;
    #pragma unroll
    for (int jb = 0; jb < RNK_NJ; ++jb) rank += rpart[(size_t)jb * (NIMG * KTOT) + idx];
    rankArr[idx] = rank;
    int src = idx, dst = n * KTOT + (int)rank;
    ssc[dst] = csc[src];
    sbox[dst * 4 + 0] = cbox[src * 4 + 0]; sbox[dst * 4 + 1] = cbox[src * 4 + 1];
    sbox[dst * 4 + 2] = cbox[src * 4 + 2]; sbox[dst * 4 + 3] = cbox[src * 4 + 3];
}

__global__ __launch_bounds__(256, 1) void k_nms(const float* __restrict__ ssc,
                      const float* __restrict__ sbox, const u32* __restrict__ rankArr,
                      const u32* __restrict__ gE, const u32* __restrict__ gPairs,
                      u16* __restrict__ gEdges, float* __restrict__ out) {
    int n = blockIdx.x, tid = threadIdx.x;
    int lane = tid & 63, wv = tid >> 6;
    __shared__ u32 cnt[KTOT];
    __shared__ u32 offs[KTOT + 1];
    __shared__ u16 edges[LECAP];
    __shared__ u32 rem32[160];
    __shared__ u32 colLo[64], colHi[64];
    __shared__ u32 scanb[256];
    __shared__ int picksS;

    for (int i = tid; i < KTOT; i += 256) cnt[i] = 0;
    if (tid < 160) rem32[tid] = 0xFFFFFFFFu;
    __syncthreads();
    for (int w = wv; w < 79; w += 4) {
        int i = w * 64 + lane;
        bool dead = (i >= KTOT) || !(ssc[n * KTOT + i] > -INFINITY);
        u64 db = __ballot(dead);
        if (lane == 0) { rem32[2 * w] = (u32)db; rem32[2 * w + 1] = (u32)(db >> 32); }
    }
    __syncthreads();

    int E = (int)gE[n]; if (E > ECAP) E = ECAP;
    for (int k = tid; k < E; k += 256) {
        u32 p = gPairs[(size_t)n * ECAP + k];
        u32 ra = rankArr[n * KTOT + (p >> 13)], rb = rankArr[n * KTOT + (p & 0x1FFFu)];
        u32 src = ra < rb ? ra : rb;
        atomicAdd(&cnt[src], 1u);
    }
    __syncthreads();
    u32 s = 0; int base = tid * 20;
    if (tid < 250) for (int q = 0; q < 20; ++q) s += cnt[base + q];
    scanb[tid] = s;
    __syncthreads();
    for (int off = 1; off < 256; off <<= 1) {
        u32 v = (tid >= off) ? scanb[tid - off] : 0;
        __syncthreads();
        scanb[tid] += v;
        __syncthreads();
    }
    u32 tbase = (tid == 0) ? 0u : scanb[tid - 1];
    if (tid < 250) {
        u32 run = tbase;
        for (int q = 0; q < 20; ++q) { offs[base + q] = run; run += cnt[base + q]; }
    }
    if (tid == 0) offs[KTOT] = scanb[255];
    __syncthreads();
    for (int i = tid; i < KTOT; i += 256) cnt[i] = 0;
    __syncthreads();
    for (int k = tid; k < E; k += 256) {
        u32 p = gPairs[(size_t)n * ECAP + k];
        u32 ra = rankArr[n * KTOT + (p >> 13)], rb = rankArr[n * KTOT + (p & 0x1FFFu)];
        u32 src = ra < rb ? ra : rb, dst = ra < rb ? rb : ra;
        u32 slot = offs[src] + atomicAdd(&cnt[src], 1u);
        if (slot < LECAP) edges[slot] = (u16)dst;
        else gEdges[(size_t)n * ECAP + slot] = (u16)dst;
    }
    __syncthreads();

    if (wv == 0) {
        int picks = 0;
        for (int w = 0; w < 79 && picks < 1000; ++w) {
            u64 rw = ((u64)rem32[2 * w + 1] << 32) | rem32[2 * w];
            u64 alive = ~rw;
            if (alive == 0ULL) continue;
            int c = w * 64 + lane;
            bool amAlive = ((alive >> lane) & 1ULL) != 0ULL;
            int e0 = 0, e1 = 0;
            if (amAlive) { e0 = (int)offs[c]; e1 = (int)offs[c + 1]; }
            colLo[lane] = 0; colHi[lane] = 0;
            bool anyIntra = false;
            for (int k = e0; k < e1; ++k) {
                int dst = (k < LECAP) ? (int)edges[k] : (int)gEdges[(size_t)n * ECAP + k];
                if ((dst >> 6) == w) {
                    if (lane < 32) atomicOr(&colLo[dst & 63], 1u << lane);
                    else           atomicOr(&colHi[dst & 63], 1u << (lane - 32));
                    anyIntra = true;
                }
            }
            u64 cm;
            if (__ballot(anyIntra) == 0ULL) {
                cm = alive;
            } else {
                u64 col = ((u64)colHi[lane] << 32) | colLo[lane];
                cm = 0ULL;
                for (int e = 0; e < 64; ++e) {
                    if (!((alive >> e) & 1ULL)) continue;
                    u64 ce = __shfl(col, e);
                    if ((cm & ce) == 0ULL) cm |= (1ULL << e);
                }
            }
            int allowed = 1000 - picks;
            int ncom = __popcll(cm);
            while (ncom > allowed) { cm &= ~(1ULL << (63 - __clzll(cm))); --ncom; }
            if ((cm >> lane) & 1ULL) {
                int pos = picks + (int)__popcll(cm & ((1ULL << lane) - 1ULL));
                const float* bp = &sbox[(size_t)(n * KTOT + c) * 4];
                float* op = &out[(n * 1000 + pos) * 5];
                op[0] = bp[0]; op[1] = bp[1]; op[2] = bp[2]; op[3] = bp[3];
                op[4] = ssc[n * KTOT + c];
                for (int k = e0; k < e1; ++k) {
                    int dst = (k < LECAP) ? (int)edges[k] : (int)gEdges[(size_t)n * ECAP + k];
                    atomicOr(&rem32[dst >> 5], 1u << (dst & 31));
                }
            }
            picks += ncom;
        }
        if (lane == 0) picksS = picks;
    }
    __syncthreads();
    int picksF = picksS;
    int basec = (n * 1000 + picksF) * 5, cntz = (1000 - picksF) * 5;
    for (int t = tid; t < cntz; t += 256) out[basec + t] = 0.f;
}

// ==================================================================================
extern "C" void kernel_launch(void* const* d_in, const int* in_sizes, int n_in,
                              void* d_out, int out_size, void* d_ws, size_t ws_size,
                              hipStream_t stream) {
    if (ws_size < WS_NEEDED) return;

    bool dictOrder = (in_sizes[1] > in_sizes[0]);
    Ptrs P;
    for (int l = 0; l < 5; ++l) {
        P.o[l] = (const float*)d_in[dictOrder ? (2 * l)     : l];
        P.b[l] = (const float*)d_in[dictOrder ? (2 * l + 1) : (5 + l)];
    }
    char* ws = (char*)d_ws;
    u32*   hist   = (u32*)(ws + OFF_HIST);
    u32*   gcnt   = (u32*)(ws + OFF_GCNT);
    u32*   ecnt   = (u32*)(ws + OFF_ECNT);
    u32*   gec    = (u32*)(ws + OFF_GEC);
    int*   binB   = (int*)(ws + OFF_BINB);
    int*   kneed  = (int*)(ws + OFF_KNEED);
    int*   g0     = (int*)(ws + OFF_G0);
    int*   sel    = (int*)(ws + OFF_SEL);
    u64*   eq     = (u64*)(ws + OFF_EQ);
    u64*   key64  = (u64*)(ws + OFF_KEY64);
    float* csc    = (float*)(ws + OFF_CSC);
    float* cbox   = (float*)(ws + OFF_CBOX);
    float* cobox  = (float*)(ws + OFF_COBOX);
    float* ssc    = (float*)(ws + OFF_SSC);
    float* sbox   = (float*)(ws + OFF_SBOX);
    u32*   rankA  = (u32*)(ws + OFF_RANK);
    u32*   pairs  = (u32*)(ws + OFF_PAIRS);
    u16*   espill = (u16*)(ws + OFF_ESPILL);
    u32*   rpart  = (u32*)(ws + OFF_RPART);
    float* out    = (float*)d_out;

    Args A;
    A.P = P;
    A.hist = hist; A.gcnt = gcnt; A.ecnt = ecnt; A.gec = gec;
    A.binB = binB; A.kneed = kneed; A.g0 = g0; A.sel = sel;
    A.eq = eq; A.key64 = key64;
    A.csc = csc; A.cbox = cbox; A.cobox = cobox;
    A.pairs = pairs; A.espill = espill; A.rpart = rpart;
    A.out = out;

    int dev = 0, coop = 0;
    hipGetDevice(&dev);
    hipDeviceGetAttribute(&coop, hipDeviceAttributeCooperativeLaunch, dev);

    hipError_t err = hipErrorUnknown;
    if (coop) {
        void* kargs[] = { (void*)&A };
        err = hipLaunchCooperativeKernel((const void*)k_all, dim3(GRID_ALL), dim3(256),
                                         kargs, 0, stream);
    }
    if (err != hipSuccess) {
        // fallback: proven 9-kernel pipeline
        k_zero<<<dim3(64), 256, 0, stream>>>(hist, (int)ZERO_WORDS);
        k_hist<<<dim3(32, 10), 256, 0, stream>>>(P, hist);
        k_resolve<<<10, 256, 0, stream>>>(hist, binB, kneed, g0);
        k_compact<<<dim3(64, 10), 256, 0, stream>>>(P, binB, gcnt, ecnt, sel, eq);
        k_eqsel<<<10, 256, 0, stream>>>(ecnt, kneed, g0, eq, sel);
        k_feat<<<dim3((NIMG * KTOT + 255) / 256), 256, 0, stream>>>(P, sel, key64, csc, cbox, cobox);
        k_redge<<<dim3(RNK_TILES + EDGE_TILES, NIMG), 256, 0, stream>>>(key64, rpart, cobox, gec, pairs);
        k_scat<<<dim3((KTOT + 255) / 256, NIMG), 256, 0, stream>>>(rpart, csc, cbox, ssc, sbox, rankA);
        k_nms<<<NIMG, 256, 0, stream>>>(ssc, sbox, rankA, gec, pairs, espill, out);
    }
}

// Round 2
// 357.341 us; speedup vs baseline: 1.1354x; 1.1354x over previous
//
#include <hip/hip_runtime.h>
#include <cmath>

#pragma clang fp contract(off)

typedef unsigned int u32;
typedef unsigned short u16;
typedef unsigned long long u64;

#define K_PER_LVL 1000
#define KTOT 5000            // 5 levels * 1000
#define NIMG 2
#define BINS 16384           // histogram bins = top 14 bits of fkey (binade/32)
#define BIN_SHIFT 18
#define SEGW (BINS / 256)    // 64 bins per resolve segment
#define EQ_CAP 2048
#define ECAP 32768           // max suppression edges per image (est ~4k; 8x margin)
#define LECAP 24576          // fallback k_nms LDS edge capacity
#define CBUF 1024            // per-block staging capacity in compact
#define RNK_IB 512           // rank: i-candidates per block (2 per thread)
#define RNK_JB 250           // rank: j-keys per block
#define RNK_NJ (KTOT / RNK_JB)   // 20 j-blocks
#define RNK_TILES 200        // 10 i-blk * 20 j-blk
#define EDGE_TILES 820       // sum_{bi=0..19} (79 - 4*bi)
#define NTILES (RNK_TILES + EDGE_TILES)
#define GRID_A 512           // preferred coop grid: 2 blocks/CU (64 KB LDS)
#define GRID_B 256           // fallback coop grid: 1 block/CU

__constant__ int c_LG[5] = {512, 256, 128, 64, 32};      // grid dim (square)
__constant__ int c_LS[5] = {4, 8, 16, 32, 64};           // stride
__constant__ int c_LZ[5] = {32, 64, 128, 256, 512};      // anchor size
__constant__ int c_LM[5] = {786432, 196608, 49152, 12288, 3072}; // 3*G*G

struct Ptrs { const float* o[5]; const float* b[5]; };

struct Args {
    Ptrs P;
    u32* hist; u32* gcnt; u32* ecnt; u32* gec;
    int* binB; int* kneed; int* g0; int* sel;
    u64* eq; u64* key64;
    float* csc; float* cbox; float* cobox;
    u32* pairs; u16* espill; u32* rpart;
    float* out;
};

// ---------------- cache-bypassing (agent-scope, relaxed) accessors ----------------
// These compile to global_load/store with sc0 sc1 on gfx950: coherent at the LLC,
// no L2 residency -> cross-XCD visible without any fence/flush at barriers.
template <typename T>
__device__ inline T ldA(const T* p) {
    return __hip_atomic_load(p, __ATOMIC_RELAXED, __HIP_MEMORY_SCOPE_AGENT);
}
template <typename T>
__device__ inline void stA(T* p, T v) {
    __hip_atomic_store(p, v, __ATOMIC_RELAXED, __HIP_MEMORY_SCOPE_AGENT);
}
__device__ inline void stBox4(float* base, size_t slot2, float x1, float y1, float x2, float y2) {
    u64* p = reinterpret_cast<u64*>(base) + slot2;
    stA(p,     ((u64)__float_as_uint(y1) << 32) | (u64)__float_as_uint(x1));
    stA(p + 1, ((u64)__float_as_uint(y2) << 32) | (u64)__float_as_uint(x2));
}
__device__ inline void ldBox4(const float* base, size_t slot2, float& x1, float& y1, float& x2, float& y2) {
    const u64* p = reinterpret_cast<const u64*>(base) + slot2;
    u64 w0 = ldA(p), w1 = ldA(p + 1);
    x1 = __uint_as_float((u32)w0); y1 = __uint_as_float((u32)(w0 >> 32));
    x2 = __uint_as_float((u32)w1); y2 = __uint_as_float((u32)(w1 >> 32));
}

// ---------------- fence-free grid barrier (monotonic, survives re-launch) ----------------
// __syncthreads() drains each wave's vmcnt before arrival (compiler-guaranteed), and all
// cross-phase traffic is LLC-coherent (ldA/stA), so RELAXED atomics suffice: no L2
// writeback/invalidate per sync (the ~33us/sync cost of cg::grid::sync on 8 XCDs).
__device__ __attribute__((aligned(64))) u32 g_barCnt;
__device__ __attribute__((aligned(64))) u32 g_barGen;

template <int NB>
__device__ inline void gridBar() {
    __syncthreads();
    if (threadIdx.x == 0) {
        u32 a = __hip_atomic_fetch_add(&g_barCnt, 1u, __ATOMIC_RELAXED, __HIP_MEMORY_SCOPE_AGENT);
        u32 m1 = a / (u32)NB + 1u;                 // target generation for this barrier
        if ((a & (u32)(NB - 1)) == (u32)(NB - 1)) {
            stA(&g_barGen, m1);                    // releaser
        } else {
            while (ldA(&g_barGen) < m1) __builtin_amdgcn_s_sleep(1);
        }
    }
    __syncthreads();
}

// monotone float -> uint key (larger float => larger key)
__device__ inline u32 fkey(float f) {
    u32 u = __float_as_uint(f);
    return (u & 0x80000000u) ? ~u : (u | 0x80000000u);
}

// block -> (p, slice, nslices) work-proportional mapping for hist/compact.
template <int NB>
__device__ inline void histMap(int b, int& p, int& sl, int& nsl) {
    constexpr int H = NB / 2;                      // blocks per image
    int n = b / H, r = b % H;
    int l, s0, c;
    if constexpr (NB == 512) {                     // L0:188 L1:48 L2:12 L3:4 L4:4
        if (r < 188)      { l = 0; s0 = 0;   c = 188; }
        else if (r < 236) { l = 1; s0 = 188; c = 48;  }
        else if (r < 248) { l = 2; s0 = 236; c = 12;  }
        else if (r < 252) { l = 3; s0 = 248; c = 4;   }
        else              { l = 4; s0 = 252; c = 4;   }
    } else {                                       // L0:94 L1:24 L2:6 L3:2 L4:2
        if (r < 94)       { l = 0; s0 = 0;   c = 94; }
        else if (r < 118) { l = 1; s0 = 94;  c = 24; }
        else if (r < 124) { l = 2; s0 = 118; c = 6;  }
        else if (r < 126) { l = 3; s0 = 124; c = 2;  }
        else              { l = 4; s0 = 126; c = 2;  }
    }
    p = n * 5 + l; sl = r - s0; nsl = c;
}

// featurize one selected candidate (anchor + decode + clip + score + 64b order key)
__device__ inline void featOneM(const Args& A, int p, int s, int m) {
    int n = p / 5, l = p % 5;
    int G = c_LG[l], S = c_LS[l], Z = c_LZ[l];
    int gg = G * G;
    int a = m % 3; int pix = m / 3; int h = pix / G; int w = pix - h * G;

    const float ars[3] = {0.5f, 1.0f, 2.0f};
    float ar = ars[a];
    float hr = sqrtf(ar), wr = 1.0f / hr;
    float wsz = wr * (float)Z, hsz = hr * (float)Z;
    float bx1 = rintf(-0.5f * wsz), by1 = rintf(-0.5f * hsz);
    float bx2 = rintf(0.5f * wsz),  by2 = rintf(0.5f * hsz);
    float sx = (float)(w * S), sy = (float)(h * S);
    float ax1 = sx + bx1, ay1 = sy + by1, ax2 = sx + bx2, ay2 = sy + by2;
    float wa = ax2 - ax1, ha = ay2 - ay1;
    float cxa = ax1 + 0.5f * wa, cya = ay1 + 0.5f * ha;

    const float* bb = A.P.b[l] + (size_t)n * 12 * gg;
    float dx = bb[(a * 4 + 0) * gg + pix];
    float dy = bb[(a * 4 + 1) * gg + pix];
    const float CLIPV = 4.135166556742356f;  // log(1000/16)
    float dw = fminf(bb[(a * 4 + 2) * gg + pix], CLIPV);
    float dh = fminf(bb[(a * 4 + 3) * gg + pix], CLIPV);
    float cx = dx * wa + cxa, cy = dy * ha + cya;
    float ww = expf(dw) * wa, hh = expf(dh) * ha;
    float x1 = cx - 0.5f * ww, y1 = cy - 0.5f * hh;
    float x2 = cx + 0.5f * ww, y2 = cy + 0.5f * hh;
    x1 = fminf(fmaxf(x1, 0.f), 2048.f);
    y1 = fminf(fmaxf(y1, 0.f), 2048.f);
    x2 = fminf(fmaxf(x2, 0.f), 2048.f);
    y2 = fminf(fmaxf(y2, 0.f), 2048.f);

    float raw = A.P.o[l][(size_t)n * 3 * gg + a * gg + pix];
    float sc = 1.0f / (1.0f + expf(-raw));
    bool keep = (x2 - x1 >= 1e-3f) && (y2 - y1 >= 1e-3f) && (sc > 0.0f);

    int slot = n * KTOT + l * K_PER_LVL + s;
    u32 tb = ((u32)l << 20) | (u32)m;          // m < 2^20, l < 8 -> unique
    u32 kk = keep ? fkey(raw) : 0u;
    stA(&A.key64[slot], ((u64)kk << 23) | (u64)(tb ^ 0x7FFFFFu));

    stA(&A.csc[slot], keep ? sc : -INFINITY);
    stBox4(A.cbox, (size_t)slot * 2, x1, y1, x2, y2);
    float off = 4097.0f * (float)l;            // lvl * (W+H+1), batched_nms offset
    stBox4(A.cobox, (size_t)slot * 2, x1 + off, y1 + off, x2 + off, y2 + off);
}

// ---------------- LDS union (<= 64 KB so 2 blocks/CU at GRID_A=512) ----------------
struct __align__(16) SmHist { u32 lh[BINS]; };                       // 64 KB exactly
struct __align__(16) SmResolve { u32 seg[256]; u32 tail[SEGW]; int sgS; u32 GS; };
struct __align__(16) SmCompact { u64 leq[CBUF]; u32 lsel[CBUF]; u32 cSel, cEq, baseSel, baseEq; };
struct __align__(16) SmEqsel { u64 a[EQ_CAP]; };                     // 16 KB
struct __align__(16) SmRedge { u64 kj[RNK_JB]; float cb[64][4]; };
struct __align__(16) SmNms {                                         // ~62.2 KB (edges now global)
    u32 cnt[KTOT];
    u32 offs[KTOT + 1];
    u32 rem32[160];
    u32 colLo[64], colHi[64];
    u32 scanb[256];
    int picksS;
    u16 rankL[KTOT];
    u16 invL[KTOT];
};
union SmAll { SmHist h; SmResolve r; SmCompact c; SmEqsel e; SmRedge g; SmNms n; };
static_assert(sizeof(SmAll) <= 65536, "LDS union must fit 64 KB for 2 blocks/CU");

// ---------------- workspace layout (shared by coop + fallback paths) ----------------
constexpr size_t OFF_HIST   = 0;
constexpr size_t OFF_GCNT   = OFF_HIST + 10 * BINS * 4;
constexpr size_t OFF_ECNT   = OFF_GCNT + 64;
constexpr size_t OFF_GEC    = OFF_ECNT + 64;
constexpr size_t ZERO_WORDS = (10 * BINS * 4 + 192) / 4;
constexpr size_t OFF_BINB   = OFF_GEC + 64;
constexpr size_t OFF_KNEED  = OFF_BINB + 64;
constexpr size_t OFF_G0     = OFF_KNEED + 64;
constexpr size_t OFF_SEL    = OFF_G0 + 64;
constexpr size_t OFF_EQ     = OFF_SEL + 10 * K_PER_LVL * 4;
constexpr size_t OFF_KEY64  = OFF_EQ + (size_t)10 * EQ_CAP * 8;
constexpr size_t OFF_CSC    = OFF_KEY64 + (size_t)NIMG * KTOT * 8;
constexpr size_t OFF_CBOX   = OFF_CSC + (size_t)NIMG * KTOT * 4;
constexpr size_t OFF_COBOX  = OFF_CBOX + (size_t)NIMG * KTOT * 16;
constexpr size_t OFF_SSC    = OFF_COBOX + (size_t)NIMG * KTOT * 16;   // fallback only
constexpr size_t OFF_SBOX   = OFF_SSC + (size_t)NIMG * KTOT * 4;      // fallback only
constexpr size_t OFF_RANK   = OFF_SBOX + (size_t)NIMG * KTOT * 16;    // fallback only
constexpr size_t OFF_PAIRS  = OFF_RANK + (size_t)NIMG * KTOT * 4;
constexpr size_t OFF_ESPILL = OFF_PAIRS + (size_t)NIMG * ECAP * 4;
constexpr size_t OFF_RPART  = OFF_ESPILL + (size_t)NIMG * ECAP * 2;
constexpr size_t WS_NEEDED  = OFF_RPART + (size_t)RNK_NJ * NIMG * KTOT * 4;

// ==================================================================================
//   COOPERATIVE MEGA-KERNEL: 7 phases, 6 fence-free barriers, one dispatch
// ==================================================================================
template <int NB>
__global__ __launch_bounds__(256, 1) void k_all(Args A) {
    __shared__ SmAll sm;
    const int tid = threadIdx.x;
    const int b = blockIdx.x;

    // ---- P0: zero hist + counters (bypass stores -> no stale L2 copies anywhere) ----
    {
        const int nw = (int)ZERO_WORDS;
        for (int i = b * 256 + tid; i < nw; i += NB * 256) stA(&A.hist[i], 0u);
        for (int i = tid; i < BINS; i += 256) sm.h.lh[i] = 0;   // LDS hist zero, overlapped
    }
    gridBar<NB>();

    // ---- P1: one-pass 16384-bin histogram (LDS pre-agg, weighted block map) ----
    {
        int p, sl, nsl; histMap<NB>(b, p, sl, nsl);
        int l = p % 5;
        int M4 = c_LM[l] >> 2;
        const float4* base = (const float4*)(A.P.o[l] + (size_t)(p / 5) * c_LM[l]);
        for (int i = sl * 256 + tid; i < M4; i += nsl * 256) {
            float4 v = base[i];
            atomicAdd(&sm.h.lh[fkey(v.x) >> BIN_SHIFT], 1u);
            atomicAdd(&sm.h.lh[fkey(v.y) >> BIN_SHIFT], 1u);
            atomicAdd(&sm.h.lh[fkey(v.z) >> BIN_SHIFT], 1u);
            atomicAdd(&sm.h.lh[fkey(v.w) >> BIN_SHIFT], 1u);
        }
        __syncthreads();
        for (int i = tid; i < BINS; i += 256) {
            u32 c = sm.h.lh[i];
            if (c) atomicAdd(&A.hist[p * BINS + i], c);   // device-scope RMW (LLC)
        }
    }
    gridBar<NB>();

    // ---- P2: resolve threshold bin per (n,l) [blocks 0..9] ----
    if (b < 10) {
        int p = b, t = tid;
        const u32* hb = A.hist + p * BINS;
        // coalesced LLC staging (bypass loads don't cache; strided reads would re-fetch lines)
        for (int i = t; i < BINS; i += 256) sm.h.lh[i] = ldA(&hb[i]);
        __syncthreads();
        u32 s = 0; int base0 = t * SEGW;
        for (int q = 0; q < SEGW; ++q) s += sm.h.lh[base0 + q];
        __syncthreads();                 // lh reads done before seg overwrites alias
        sm.r.seg[t] = s;
        __syncthreads();
        if (t == 0) {
            u32 G = 0; int sg = 255;
            for (; sg > 0; --sg) {
                if (G + sm.r.seg[sg] >= (u32)K_PER_LVL) break;
                G += sm.r.seg[sg];
            }
            sm.r.sgS = sg; sm.r.GS = G;
        }
        __syncthreads();
        int sg = sm.r.sgS;
        if (t < SEGW) sm.r.tail[t] = ldA(&hb[sg * SEGW + t]);
        __syncthreads();
        if (t == 0) {
            u32 G = sm.r.GS; int B = sg * SEGW;
            for (int q = SEGW - 1; q >= 0; --q) {
                u32 c = sm.r.tail[q];
                if (G + c >= (u32)K_PER_LVL) { B = sg * SEGW + q; break; }
                G += c;
            }
            stA(&A.binB[p], B);
            stA(&A.kneed[p], K_PER_LVL - (int)G);
            stA(&A.g0[p], (int)G);
        }
    }
    gridBar<NB>();

    // ---- P3: compact (LDS staging, one reservation atomic per block) ----
    {
        int p, sl, nsl; histMap<NB>(b, p, sl, nsl);
        int l = p % 5;
        int M4 = c_LM[l] >> 2; int gg = c_LM[l] / 3;
        const float4* base = (const float4*)(A.P.o[l] + (size_t)(p / 5) * c_LM[l]);
        int B = ldA(&A.binB[p]);
        if (tid == 0) { sm.c.cSel = 0; sm.c.cEq = 0; }
        __syncthreads();
        for (int i4 = sl * 256 + tid; i4 < M4; i4 += nsl * 256) {
            float4 v = base[i4];
            float vv[4] = {v.x, v.y, v.z, v.w};
            #pragma unroll
            for (int q = 0; q < 4; ++q) {
                u32 k = fkey(vv[q]);
                int bin = (int)(k >> BIN_SHIFT);
                if (bin < B) continue;
                int i = i4 * 4 + q;
                int a = i / gg; int pix = i - a * gg; int m = pix * 3 + a;
                if (bin > B) {
                    u32 t = atomicAdd(&sm.c.cSel, 1u);
                    if (t < CBUF) sm.c.lsel[t] = (u32)m;
                    else { u32 pos = atomicAdd(&A.gcnt[p], 1u); stA(&A.sel[p * K_PER_LVL + pos], m); }
                } else {
                    u64 pk = ((u64)k << 20) | (u64)(0xFFFFFu ^ (u32)m);
                    u32 t = atomicAdd(&sm.c.cEq, 1u);
                    if (t < CBUF) sm.c.leq[t] = pk;
                    else { u32 e = atomicAdd(&A.ecnt[p], 1u); if (e < EQ_CAP) stA(&A.eq[(size_t)p * EQ_CAP + e], pk); }
                }
            }
        }
        __syncthreads();
        if (tid == 0) {
            u32 ns = sm.c.cSel < CBUF ? sm.c.cSel : CBUF;
            u32 ne = sm.c.cEq < CBUF ? sm.c.cEq : CBUF;
            sm.c.baseSel = ns ? atomicAdd(&A.gcnt[p], ns) : 0u;
            sm.c.baseEq  = ne ? atomicAdd(&A.ecnt[p], ne) : 0u;
        }
        __syncthreads();
        u32 ns = sm.c.cSel < CBUF ? sm.c.cSel : CBUF;
        u32 ne = sm.c.cEq < CBUF ? sm.c.cEq : CBUF;
        for (u32 i = tid; i < ns; i += 256) stA(&A.sel[p * K_PER_LVL + sm.c.baseSel + i], (int)sm.c.lsel[i]);
        for (u32 i = tid; i < ne; i += 256) {
            u32 slot = sm.c.baseEq + i;
            if (slot < EQ_CAP) stA(&A.eq[(size_t)p * EQ_CAP + slot], sm.c.leq[i]);
        }
    }
    gridBar<NB>();

    // ---- P4: eqsel (blocks 0..9, boundary items featurized in-register)
    //          + main feat (blocks 10..NB-1) ----
    if (b < 10) {
        int p = b, t = tid;
        int E = (int)ldA(&A.ecnt[p]); if (E > EQ_CAP) E = EQ_CAP;
        int KF = ldA(&A.kneed[p]); int G0 = ldA(&A.g0[p]);
        for (int i = t; i < E; i += 256) sm.e.a[i] = ldA(&A.eq[(size_t)p * EQ_CAP + i]);
        __syncthreads();
        u64 mine[8]; int rk[8];
        #pragma unroll
        for (int q = 0; q < 8; ++q) {
            int i = t + q * 256;
            mine[q] = (i < E) ? sm.e.a[i] : 0ULL;
            rk[q] = 0;
        }
        for (int j = 0; j < E; ++j) {
            u64 v = sm.e.a[j];
            #pragma unroll
            for (int q = 0; q < 8; ++q) rk[q] += (v > mine[q]) ? 1 : 0;
        }
        #pragma unroll
        for (int q = 0; q < 8; ++q) {
            int i = t + q * 256;
            if (i < E && rk[q] < KF) {
                int m = (int)(0xFFFFFu ^ (u32)(mine[q] & 0xFFFFFu));
                featOneM(A, p, G0 + rk[q], m);
            }
        }
    } else {
        for (int idx = (b - 10) * 256 + tid; idx < 10 * K_PER_LVL; idx += (NB - 10) * 256) {
            int p = idx / K_PER_LVL, s = idx - p * K_PER_LVL;
            if (s < ldA(&A.g0[p])) featOneM(A, p, s, ldA(&A.sel[p * K_PER_LVL + s]));
        }
    }
    gridBar<NB>();

    // ---- P5: rank partials + IoU edges, tiles looped over all blocks ----
    for (int tile = b; tile < NIMG * NTILES; tile += NB) {
        int n = tile / NTILES;
        int x = tile - n * NTILES;
        if (x < RNK_TILES) {
            int i0 = (x / 20) * RNK_IB;
            int j0 = (x % 20) * RNK_JB;
            const u64* kb = A.key64 + (size_t)n * KTOT;
            for (int t = tid; t < RNK_JB; t += 256) sm.g.kj[t] = ldA(&kb[j0 + t]);
            __syncthreads();
            int i1 = i0 + tid, i2 = i1 + 256;
            u64 k1 = (i1 < KTOT) ? ldA(&kb[i1]) : ~0ULL;
            u64 k2 = (i2 < KTOT) ? ldA(&kb[i2]) : ~0ULL;
            u32 r1 = 0, r2 = 0;
            #pragma unroll 10
            for (int j = 0; j < RNK_JB; ++j) {
                u64 v = sm.g.kj[j];
                r1 += (v > k1) ? 1u : 0u;
                r2 += (v > k2) ? 1u : 0u;
            }
            u32* rp = A.rpart + (size_t)(x % 20) * (NIMG * KTOT) + n * KTOT;
            if (i1 < KTOT) stA(&rp[i1], r1);
            if (i2 < KTOT) stA(&rp[i2], r2);
        } else {
            int e = x - RNK_TILES, bi = 0;
            while (true) { int c = 79 - 4 * bi; if (e < c) break; e -= c; ++bi; }
            int bj = 4 * bi + e;
            int i = bi * 256 + tid;
            int j0 = bj * 64;
            if (tid < 64) {
                int jl = j0 + tid;
                if (jl < KTOT) {
                    ldBox4(A.cobox, (size_t)(n * KTOT + jl) * 2,
                           sm.g.cb[tid][0], sm.g.cb[tid][1], sm.g.cb[tid][2], sm.g.cb[tid][3]);
                } else {
                    sm.g.cb[tid][0] = 0.f; sm.g.cb[tid][1] = 0.f;
                    sm.g.cb[tid][2] = 0.f; sm.g.cb[tid][3] = 0.f;
                }
            }
            __syncthreads();
            if (i < KTOT) {
                float x1, y1, x2, y2;
                ldBox4(A.cobox, (size_t)(n * KTOT + i) * 2, x1, y1, x2, y2);
                float areai = fmaxf(x2 - x1, 0.f) * fmaxf(y2 - y1, 0.f);
                int lim = KTOT - j0; if (lim > 64) lim = 64;
                for (int jj = 0; jj < lim; ++jj) {
                    int j = j0 + jj;
                    if (j <= i) continue;
                    float bx1 = sm.g.cb[jj][0], by1 = sm.g.cb[jj][1];
                    float bx2 = sm.g.cb[jj][2], by2 = sm.g.cb[jj][3];
                    float areaj = fmaxf(bx2 - bx1, 0.f) * fmaxf(by2 - by1, 0.f);
                    float ltx = fmaxf(x1, bx1), lty = fmaxf(y1, by1);
                    float rbx = fminf(x2, bx2), rby = fminf(y2, by2);
                    float iw = fmaxf(rbx - ltx, 0.f), ih = fmaxf(rby - lty, 0.f);
                    float inter = iw * ih;
                    float iou = inter / (areai + areaj - inter + 1e-9f);
                    if (iou > 0.7f) {
                        u32 pos = atomicAdd(&A.gec[n], 1u);
                        if (pos < ECAP) stA(&A.pairs[(size_t)n * ECAP + pos], ((u32)i << 13) | (u32)j);
                    }
                }
            }
        }
        __syncthreads();   // LDS reused next tile
    }
    gridBar<NB>();

    // ---- P6: fused scat + greedy NMS sweep [blocks 0..1, one per image] ----
    if (b >= NIMG) return;
    {
        int n = b;
        int lane = tid & 63, wv = tid >> 6;
        SmNms& S = sm.n;
        u16* eb = A.espill + (size_t)n * ECAP;   // this block's edge array (same-block: normal ops)

        for (int i = tid; i < KTOT; i += 256) S.cnt[i] = 0;
        if (tid < 160) S.rem32[tid] = 0;
        __syncthreads();

        // ranks from partials; inverse map; dead bits by rank
        for (int i = tid; i < KTOT; i += 256) {
            u32 r = 0;
            #pragma unroll
            for (int jb = 0; jb < RNK_NJ; ++jb)
                r += ldA(&A.rpart[(size_t)jb * (NIMG * KTOT) + n * KTOT + i]);
            S.rankL[i] = (u16)r;
            S.invL[r] = (u16)i;
            if (!(ldA(&A.csc[n * KTOT + i]) > -INFINITY))
                atomicOr(&S.rem32[r >> 5], 1u << (r & 31));
        }
        __syncthreads();
        if (tid == 0) {  // pad ranks 5000..5119 dead
            S.rem32[156] |= 0xFFFFFF00u;
            S.rem32[157] = 0xFFFFFFFFu;
            S.rem32[158] = 0xFFFFFFFFu;
            S.rem32[159] = 0xFFFFFFFFu;
        }

        // ---- CSR build: pairs are original indices; remap via rankL ----
        int E = (int)ldA(&A.gec[n]); if (E > ECAP) E = ECAP;
        for (int k = tid; k < E; k += 256) {
            u32 pr = ldA(&A.pairs[(size_t)n * ECAP + k]);
            u32 ra = S.rankL[pr >> 13], rb = S.rankL[pr & 0x1FFFu];
            u32 src = ra < rb ? ra : rb;
            atomicAdd(&S.cnt[src], 1u);
        }
        __syncthreads();
        u32 s0 = 0; int base0 = tid * 20;
        if (tid < 250) for (int q = 0; q < 20; ++q) s0 += S.cnt[base0 + q];
        S.scanb[tid] = s0;
        __syncthreads();
        for (int off = 1; off < 256; off <<= 1) {
            u32 v = (tid >= off) ? S.scanb[tid - off] : 0;
            __syncthreads();
            S.scanb[tid] += v;
            __syncthreads();
        }
        u32 tbase = (tid == 0) ? 0u : S.scanb[tid - 1];
        if (tid < 250) {
            u32 run = tbase;
            for (int q = 0; q < 20; ++q) { S.offs[base0 + q] = run; run += S.cnt[base0 + q]; }
        }
        if (tid == 0) S.offs[KTOT] = S.scanb[255];
        __syncthreads();
        for (int i = tid; i < KTOT; i += 256) S.cnt[i] = 0;
        __syncthreads();
        for (int k = tid; k < E; k += 256) {
            u32 pr = ldA(&A.pairs[(size_t)n * ECAP + k]);
            u32 ra = S.rankL[pr >> 13], rb = S.rankL[pr & 0x1FFFu];
            u32 src = ra < rb ? ra : rb, dst = ra < rb ? rb : ra;
            u32 slot = S.offs[src] + atomicAdd(&S.cnt[src], 1u);
            if (slot < ECAP) eb[slot] = (u16)dst;
        }
        __syncthreads();

        // ---- wave-0 sweep in rank order; output via inverse permutation ----
        if (wv == 0) {
            int picks = 0;
            for (int w = 0; w < 79 && picks < 1000; ++w) {
                u64 rw = ((u64)S.rem32[2 * w + 1] << 32) | S.rem32[2 * w];
                u64 alive = ~rw;
                if (alive == 0ULL) continue;
                int c = w * 64 + lane;
                bool amAlive = ((alive >> lane) & 1ULL) != 0ULL;
                int e0 = 0, e1 = 0;
                if (amAlive) { e0 = (int)S.offs[c]; e1 = (int)S.offs[c + 1]; }
                S.colLo[lane] = 0; S.colHi[lane] = 0;
                bool anyIntra = false;
                for (int k = e0; k < e1; ++k) {
                    int dst = (int)eb[k];
                    if ((dst >> 6) == w) {
                        if (lane < 32) atomicOr(&S.colLo[dst & 63], 1u << lane);
                        else           atomicOr(&S.colHi[dst & 63], 1u << (lane - 32));
                        anyIntra = true;
                    }
                }
                u64 cm;
                if (__ballot(anyIntra) == 0ULL) {
                    cm = alive;
                } else {
                    u64 col = ((u64)S.colHi[lane] << 32) | S.colLo[lane];
                    cm = 0ULL;
                    for (int e2 = 0; e2 < 64; ++e2) {
                        if (!((alive >> e2) & 1ULL)) continue;
                        u64 ce = __shfl(col, e2);
                        if ((cm & ce) == 0ULL) cm |= (1ULL << e2);
                    }
                }
                int allowed = 1000 - picks;
                int ncom = __popcll(cm);
                while (ncom > allowed) { cm &= ~(1ULL << (63 - __clzll(cm))); --ncom; }
                if ((cm >> lane) & 1ULL) {
                    int pos = picks + (int)__popcll(cm & ((1ULL << lane) - 1ULL));
                    int orig = (int)S.invL[c];
                    float bx1, by1, bx2, by2;
                    ldBox4(A.cbox, (size_t)(n * KTOT + orig) * 2, bx1, by1, bx2, by2);
                    float* op = &A.out[(n * 1000 + pos) * 5];
                    op[0] = bx1; op[1] = by1; op[2] = bx2; op[3] = by2;
                    op[4] = ldA(&A.csc[n * KTOT + orig]);
                    for (int k = e0; k < e1; ++k) {
                        int dst = (int)eb[k];
                        atomicOr(&S.rem32[dst >> 5], 1u << (dst & 31));
                    }
                }
                picks += ncom;
            }
            if (lane == 0) S.picksS = picks;
        }
        __syncthreads();
        int picksF = S.picksS;
        int basec = (n * 1000 + picksF) * 5, cntz = (1000 - picksF) * 5;
        for (int t2 = tid; t2 < cntz; t2 += 256) A.out[basec + t2] = 0.f;
    }
}

// ==================================================================================
//   FALLBACK: original 9-kernel pipeline (used if cooperative launch unavailable)
// ==================================================================================
__global__ __launch_bounds__(256) void k_zero(u32* __restrict__ z, int nwords) {
    int i = blockIdx.x * 256 + threadIdx.x;
    int stride = gridDim.x * 256;
    for (; i < nwords; i += stride) z[i] = 0;
}

__global__ __launch_bounds__(256) void k_hist(Ptrs P, u32* __restrict__ hist) {
    int p = blockIdx.y; int l = p % 5; int n = p / 5;
    int M4 = c_LM[l] >> 2;
    const float4* base = (const float4*)(P.o[l] + (size_t)n * c_LM[l]);
    __shared__ u32 lh[BINS];
    for (int i = threadIdx.x; i < BINS; i += 256) lh[i] = 0;
    __syncthreads();
    int stride = gridDim.x * 256;
    for (int i = blockIdx.x * 256 + threadIdx.x; i < M4; i += stride) {
        float4 v = base[i];
        atomicAdd(&lh[fkey(v.x) >> BIN_SHIFT], 1u);
        atomicAdd(&lh[fkey(v.y) >> BIN_SHIFT], 1u);
        atomicAdd(&lh[fkey(v.z) >> BIN_SHIFT], 1u);
        atomicAdd(&lh[fkey(v.w) >> BIN_SHIFT], 1u);
    }
    __syncthreads();
    for (int i = threadIdx.x; i < BINS; i += 256) {
        u32 c = lh[i];
        if (c) atomicAdd(&hist[p * BINS + i], c);
    }
}

__global__ __launch_bounds__(256) void k_resolve(const u32* __restrict__ hist,
                                                 int* __restrict__ binB, int* __restrict__ kneed,
                                                 int* __restrict__ g0) {
    int p = blockIdx.x, t = threadIdx.x;
    __shared__ u32 seg[256];
    __shared__ u32 tail[SEGW];
    __shared__ int sgS; __shared__ u32 GS;
    u32 s = 0;
    const u32* hb = hist + p * BINS;
    int base = t * SEGW;
    for (int q = 0; q < SEGW; ++q) s += hb[base + q];
    seg[t] = s;
    __syncthreads();
    if (t == 0) {
        u32 G = 0; int sg = 255;
        for (; sg > 0; --sg) {
            if (G + seg[sg] >= (u32)K_PER_LVL) break;
            G += seg[sg];
        }
        sgS = sg; GS = G;
    }
    __syncthreads();
    int sg = sgS;
    if (t < SEGW) tail[t] = hb[sg * SEGW + t];
    __syncthreads();
    if (t == 0) {
        u32 G = GS; int B = sg * SEGW;
        for (int q = SEGW - 1; q >= 0; --q) {
            u32 c = tail[q];
            if (G + c >= (u32)K_PER_LVL) { B = sg * SEGW + q; break; }
            G += c;
        }
        binB[p] = B;
        kneed[p] = K_PER_LVL - (int)G;
        g0[p] = (int)G;
    }
}

__global__ __launch_bounds__(256) void k_compact(Ptrs P, const int* __restrict__ binB,
                                                 u32* gcnt, u32* ecnt,
                                                 int* __restrict__ sel, u64* __restrict__ eq) {
    int p = blockIdx.y; int l = p % 5; int n = p / 5;
    int M4 = c_LM[l] >> 2; int gg = c_LM[l] / 3;
    const float4* base = (const float4*)(P.o[l] + (size_t)n * c_LM[l]);
    int B = binB[p];
    __shared__ u32 lsel[CBUF];
    __shared__ u64 leq[CBUF];
    __shared__ u32 cSel, cEq, baseSel, baseEq;
    if (threadIdx.x == 0) { cSel = 0; cEq = 0; }
    __syncthreads();
    int stride = gridDim.x * 256;
    for (int i4 = blockIdx.x * 256 + threadIdx.x; i4 < M4; i4 += stride) {
        float4 v = base[i4];
        float vv[4] = {v.x, v.y, v.z, v.w};
        #pragma unroll
        for (int q = 0; q < 4; ++q) {
            u32 k = fkey(vv[q]);
            int bin = (int)(k >> BIN_SHIFT);
            if (bin < B) continue;
            int i = i4 * 4 + q;
            int a = i / gg; int pix = i - a * gg; int m = pix * 3 + a;
            if (bin > B) {
                u32 t = atomicAdd(&cSel, 1u);
                if (t < CBUF) lsel[t] = (u32)m;
                else { u32 pos = atomicAdd(&gcnt[p], 1u); sel[p * K_PER_LVL + pos] = m; }
            } else {
                u64 pk = ((u64)k << 20) | (u64)(0xFFFFFu ^ (u32)m);
                u32 t = atomicAdd(&cEq, 1u);
                if (t < CBUF) leq[t] = pk;
                else { u32 e = atomicAdd(&ecnt[p], 1u); if (e < EQ_CAP) eq[(size_t)p * EQ_CAP + e] = pk; }
            }
        }
    }
    __syncthreads();
    if (threadIdx.x == 0) {
        u32 ns = cSel < CBUF ? cSel : CBUF;
        u32 ne = cEq < CBUF ? cEq : CBUF;
        baseSel = ns ? atomicAdd(&gcnt[p], ns) : 0u;
        baseEq  = ne ? atomicAdd(&ecnt[p], ne) : 0u;
    }
    __syncthreads();
    u32 ns = cSel < CBUF ? cSel : CBUF;
    u32 ne = cEq < CBUF ? cEq : CBUF;
    for (u32 i = threadIdx.x; i < ns; i += 256) sel[p * K_PER_LVL + baseSel + i] = (int)lsel[i];
    for (u32 i = threadIdx.x; i < ne; i += 256) {
        u32 slot = baseEq + i;
        if (slot < EQ_CAP) eq[(size_t)p * EQ_CAP + slot] = leq[i];
    }
}

__global__ __launch_bounds__(256) void k_eqsel(const u32* __restrict__ ecnt, const int* __restrict__ kneed,
                                               const int* __restrict__ g0,
                                               const u64* __restrict__ eq, int* __restrict__ sel) {
    int p = blockIdx.x, t = threadIdx.x;
    int E = (int)ecnt[p]; if (E > EQ_CAP) E = EQ_CAP;
    int KF = kneed[p]; int G0 = g0[p];
    __shared__ u64 a[EQ_CAP];
    for (int i = t; i < E; i += 256) a[i] = eq[(size_t)p * EQ_CAP + i];
    __syncthreads();
    u64 mine[8]; int rk[8];
    #pragma unroll
    for (int q = 0; q < 8; ++q) {
        int i = t + q * 256;
        mine[q] = (i < E) ? a[i] : 0ULL;
        rk[q] = 0;
    }
    for (int j = 0; j < E; ++j) {
        u64 v = a[j];
        #pragma unroll
        for (int q = 0; q < 8; ++q) rk[q] += (v > mine[q]) ? 1 : 0;
    }
    #pragma unroll
    for (int q = 0; q < 8; ++q) {
        int i = t + q * 256;
        if (i < E && rk[q] < KF) {
            int m = (int)(0xFFFFFu ^ (u32)(mine[q] & 0xFFFFFu));
            sel[p * K_PER_LVL + G0 + rk[q]] = m;
        }
    }
}

__global__ void k_feat(Ptrs P, const int* __restrict__ sel, u64* __restrict__ key64,
                       float* __restrict__ csc, float* __restrict__ cbox, float* __restrict__ cobox) {
    int tid = blockIdx.x * 256 + threadIdx.x;
    if (tid >= NIMG * KTOT) return;
    int p = tid / K_PER_LVL, s = tid - p * K_PER_LVL;
    Args A;
    A.P = P; A.sel = (int*)sel; A.key64 = key64; A.csc = csc; A.cbox = cbox; A.cobox = cobox;
    featOneM(A, p, s, sel[p * K_PER_LVL + s]);
}

__global__ __launch_bounds__(256) void k_redge(const u64* __restrict__ key64, u32* __restrict__ rpart,
                                               const float* __restrict__ cobox,
                                               u32* __restrict__ gE, u32* __restrict__ gPairs) {
    int n = blockIdx.y;
    int x = blockIdx.x;
    __shared__ u64 kj[RNK_JB];
    __shared__ float cb[64][4];
    if (x < RNK_TILES) {
        int i0 = (x / 20) * RNK_IB;
        int j0 = (x % 20) * RNK_JB;
        const u64* kb = key64 + (size_t)n * KTOT;
        for (int t = threadIdx.x; t < RNK_JB; t += 256) kj[t] = kb[j0 + t];
        __syncthreads();
        int i1 = i0 + threadIdx.x, i2 = i1 + 256;
        u64 k1 = (i1 < KTOT) ? kb[i1] : ~0ULL;
        u64 k2 = (i2 < KTOT) ? kb[i2] : ~0ULL;
        u32 r1 = 0, r2 = 0;
        #pragma unroll 10
        for (int j = 0; j < RNK_JB; ++j) {
            u64 v = kj[j];
            r1 += (v > k1) ? 1u : 0u;
            r2 += (v > k2) ? 1u : 0u;
        }
        u32* rp = rpart + (size_t)(x % 20) * (NIMG * KTOT) + n * KTOT;
        if (i1 < KTOT) rp[i1] = r1;
        if (i2 < KTOT) rp[i2] = r2;
        return;
    }
    int e = x - RNK_TILES, bi = 0;
    while (true) { int c = 79 - 4 * bi; if (e < c) break; e -= c; ++bi; }
    int bj = 4 * bi + e;
    int i = bi * 256 + threadIdx.x;
    int j0 = bj * 64;
    if (threadIdx.x < 64) {
        int jl = j0 + threadIdx.x;
        if (jl < KTOT) {
            cb[threadIdx.x][0] = cobox[(size_t)(n * KTOT + jl) * 4 + 0];
            cb[threadIdx.x][1] = cobox[(size_t)(n * KTOT + jl) * 4 + 1];
            cb[threadIdx.x][2] = cobox[(size_t)(n * KTOT + jl) * 4 + 2];
            cb[threadIdx.x][3] = cobox[(size_t)(n * KTOT + jl) * 4 + 3];
        } else {
            cb[threadIdx.x][0] = 0.f; cb[threadIdx.x][1] = 0.f;
            cb[threadIdx.x][2] = 0.f; cb[threadIdx.x][3] = 0.f;
        }
    }
    __syncthreads();
    if (i >= KTOT) return;
    float x1 = cobox[(size_t)(n * KTOT + i) * 4 + 0];
    float y1 = cobox[(size_t)(n * KTOT + i) * 4 + 1];
    float x2 = cobox[(size_t)(n * KTOT + i) * 4 + 2];
    float y2 = cobox[(size_t)(n * KTOT + i) * 4 + 3];
    float areai = fmaxf(x2 - x1, 0.f) * fmaxf(y2 - y1, 0.f);
    int lim = KTOT - j0; if (lim > 64) lim = 64;
    for (int jj = 0; jj < lim; ++jj) {
        int j = j0 + jj;
        if (j <= i) continue;
        float bx1 = cb[jj][0], by1 = cb[jj][1], bx2 = cb[jj][2], by2 = cb[jj][3];
        float areaj = fmaxf(bx2 - bx1, 0.f) * fmaxf(by2 - by1, 0.f);
        float ltx = fmaxf(x1, bx1), lty = fmaxf(y1, by1);
        float rbx = fminf(x2, bx2), rby = fminf(y2, by2);
        float iw = fmaxf(rbx - ltx, 0.f), ih = fmaxf(rby - lty, 0.f);
        float inter = iw * ih;
        float iou = inter / (areai + areaj - inter + 1e-9f);
        if (iou > 0.7f) {
            u32 pos = atomicAdd(&gE[n], 1u);
            if (pos < ECAP) gPairs[(size_t)n * ECAP + pos] = ((u32)i << 13) | (u32)j;
        }
    }
}

__global__ __launch_bounds__(256) void k_scat(const u32* __restrict__ rpart, const float* __restrict__ csc,
                       const float* __restrict__ cbox,
                       float* __restrict__ ssc, float* __restrict__ sbox, u32* __restrict__ rankArr) {
    int n = blockIdx.y;
    int i = blockIdx.x * 256 + threadIdx.x;
    if (i >= KTOT) return;
    int idx = n * KTOT + i;
    u32 rank = 0;
    #pragma unroll
    for (int jb = 0; jb < RNK_NJ; ++jb) rank += rpart[(size_t)jb * (NIMG * KTOT) + idx];
    rankArr[idx] = rank;
    int src = idx, dst = n * KTOT + (int)rank;
    ssc[dst] = csc[src];
    sbox[dst * 4 + 0] = cbox[src * 4 + 0]; sbox[dst * 4 + 1] = cbox[src * 4 + 1];
    sbox[dst * 4 + 2] = cbox[src * 4 + 2]; sbox[dst * 4 + 3] = cbox[src * 4 + 3];
}

__global__ __launch_bounds__(256, 1) void k_nms(const float* __restrict__ ssc,
                      const float* __restrict__ sbox, const u32* __restrict__ rankArr,
                      const u32* __restrict__ gE, const u32* __restrict__ gPairs,
                      u16* __restrict__ gEdges, float* __restrict__ out) {
    int n = blockIdx.x, tid = threadIdx.x;
    int lane = tid & 63, wv = tid >> 6;
    __shared__ u32 cnt[KTOT];
    __shared__ u32 offs[KTOT + 1];
    __shared__ u16 edges[LECAP];
    __shared__ u32 rem32[160];
    __shared__ u32 colLo[64], colHi[64];
    __shared__ u32 scanb[256];
    __shared__ int picksS;

    for (int i = tid; i < KTOT; i += 256) cnt[i] = 0;
    if (tid < 160) rem32[tid] = 0xFFFFFFFFu;
    __syncthreads();
    for (int w = wv; w < 79; w += 4) {
        int i = w * 64 + lane;
        bool dead = (i >= KTOT) || !(ssc[n * KTOT + i] > -INFINITY);
        u64 db = __ballot(dead);
        if (lane == 0) { rem32[2 * w] = (u32)db; rem32[2 * w + 1] = (u32)(db >> 32); }
    }
    __syncthreads();

    int E = (int)gE[n]; if (E > ECAP) E = ECAP;
    for (int k = tid; k < E; k += 256) {
        u32 p = gPairs[(size_t)n * ECAP + k];
        u32 ra = rankArr[n * KTOT + (p >> 13)], rb = rankArr[n * KTOT + (p & 0x1FFFu)];
        u32 src = ra < rb ? ra : rb;
        atomicAdd(&cnt[src], 1u);
    }
    __syncthreads();
    u32 s = 0; int base = tid * 20;
    if (tid < 250) for (int q = 0; q < 20; ++q) s += cnt[base + q];
    scanb[tid] = s;
    __syncthreads();
    for (int off = 1; off < 256; off <<= 1) {
        u32 v = (tid >= off) ? scanb[tid - off] : 0;
        __syncthreads();
        scanb[tid] += v;
        __syncthreads();
    }
    u32 tbase = (tid == 0) ? 0u : scanb[tid - 1];
    if (tid < 250) {
        u32 run = tbase;
        for (int q = 0; q < 20; ++q) { offs[base + q] = run; run += cnt[base + q]; }
    }
    if (tid == 0) offs[KTOT] = scanb[255];
    __syncthreads();
    for (int i = tid; i < KTOT; i += 256) cnt[i] = 0;
    __syncthreads();
    for (int k = tid; k < E; k += 256) {
        u32 p = gPairs[(size_t)n * ECAP + k];
        u32 ra = rankArr[n * KTOT + (p >> 13)], rb = rankArr[n * KTOT + (p & 0x1FFFu)];
        u32 src = ra < rb ? ra : rb, dst = ra < rb ? rb : ra;
        u32 slot = offs[src] + atomicAdd(&cnt[src], 1u);
        if (slot < LECAP) edges[slot] = (u16)dst;
        else gEdges[(size_t)n * ECAP + slot] = (u16)dst;
    }
    __syncthreads();

    if (wv == 0) {
        int picks = 0;
        for (int w = 0; w < 79 && picks < 1000; ++w) {
            u64 rw = ((u64)rem32[2 * w + 1] << 32) | rem32[2 * w];
            u64 alive = ~rw;
            if (alive == 0ULL) continue;
            int c = w * 64 + lane;
            bool amAlive = ((alive >> lane) & 1ULL) != 0ULL;
            int e0 = 0, e1 = 0;
            if (amAlive) { e0 = (int)offs[c]; e1 = (int)offs[c + 1]; }
            colLo[lane] = 0; colHi[lane] = 0;
            bool anyIntra = false;
            for (int k = e0; k < e1; ++k) {
                int dst = (k < LECAP) ? (int)edges[k] : (int)gEdges[(size_t)n * ECAP + k];
                if ((dst >> 6) == w) {
                    if (lane < 32) atomicOr(&colLo[dst & 63], 1u << lane);
                    else           atomicOr(&colHi[dst & 63], 1u << (lane - 32));
                    anyIntra = true;
                }
            }
            u64 cm;
            if (__ballot(anyIntra) == 0ULL) {
                cm = alive;
            } else {
                u64 col = ((u64)colHi[lane] << 32) | colLo[lane];
                cm = 0ULL;
                for (int e = 0; e < 64; ++e) {
                    if (!((alive >> e) & 1ULL)) continue;
                    u64 ce = __shfl(col, e);
                    if ((cm & ce) == 0ULL) cm |= (1ULL << e);
                }
            }
            int allowed = 1000 - picks;
            int ncom = __popcll(cm);
            while (ncom > allowed) { cm &= ~(1ULL << (63 - __clzll(cm))); --ncom; }
            if ((cm >> lane) & 1ULL) {
                int pos = picks + (int)__popcll(cm & ((1ULL << lane) - 1ULL));
                const float* bp = &sbox[(size_t)(n * KTOT + c) * 4];
                float* op = &out[(n * 1000 + pos) * 5];
                op[0] = bp[0]; op[1] = bp[1]; op[2] = bp[2]; op[3] = bp[3];
                op[4] = ssc[n * KTOT + c];
                for (int k = e0; k < e1; ++k) {
                    int dst = (k < LECAP) ? (int)edges[k] : (int)gEdges[(size_t)n * ECAP + k];
                    atomicOr(&rem32[dst >> 5], 1u << (dst & 31));
                }
            }
            picks += ncom;
        }
        if (lane == 0) picksS = picks;
    }
    __syncthreads();
    int picksF = picksS;
    int basec = (n * 1000 + picksF) * 5, cntz = (1000 - picksF) * 5;
    for (int t = tid; t < cntz; t += 256) out[basec + t] = 0.f;
}

// ==================================================================================
extern "C" void kernel_launch(void* const* d_in, const int* in_sizes, int n_in,
                              void* d_out, int out_size, void* d_ws, size_t ws_size,
                              hipStream_t stream) {
    if (ws_size < WS_NEEDED) return;

    bool dictOrder = (in_sizes[1] > in_sizes[0]);
    Ptrs P;
    for (int l = 0; l < 5; ++l) {
        P.o[l] = (const float*)d_in[dictOrder ? (2 * l)     : l];
        P.b[l] = (const float*)d_in[dictOrder ? (2 * l + 1) : (5 + l)];
    }
    char* ws = (char*)d_ws;
    u32*   hist   = (u32*)(ws + OFF_HIST);
    u32*   gcnt   = (u32*)(ws + OFF_GCNT);
    u32*   ecnt   = (u32*)(ws + OFF_ECNT);
    u32*   gec    = (u32*)(ws + OFF_GEC);
    int*   binB   = (int*)(ws + OFF_BINB);
    int*   kneed  = (int*)(ws + OFF_KNEED);
    int*   g0     = (int*)(ws + OFF_G0);
    int*   sel    = (int*)(ws + OFF_SEL);
    u64*   eq     = (u64*)(ws + OFF_EQ);
    u64*   key64  = (u64*)(ws + OFF_KEY64);
    float* csc    = (float*)(ws + OFF_CSC);
    float* cbox   = (float*)(ws + OFF_CBOX);
    float* cobox  = (float*)(ws + OFF_COBOX);
    float* ssc    = (float*)(ws + OFF_SSC);
    float* sbox   = (float*)(ws + OFF_SBOX);
    u32*   rankA  = (u32*)(ws + OFF_RANK);
    u32*   pairs  = (u32*)(ws + OFF_PAIRS);
    u16*   espill = (u16*)(ws + OFF_ESPILL);
    u32*   rpart  = (u32*)(ws + OFF_RPART);
    float* out    = (float*)d_out;

    Args A;
    A.P = P;
    A.hist = hist; A.gcnt = gcnt; A.ecnt = ecnt; A.gec = gec;
    A.binB = binB; A.kneed = kneed; A.g0 = g0; A.sel = sel;
    A.eq = eq; A.key64 = key64;
    A.csc = csc; A.cbox = cbox; A.cobox = cobox;
    A.pairs = pairs; A.espill = espill; A.rpart = rpart;
    A.out = out;

    int dev = 0, coop = 0;
    hipGetDevice(&dev);
    hipDeviceGetAttribute(&coop, hipDeviceAttributeCooperativeLaunch, dev);

    hipError_t err = hipErrorUnknown;
    if (coop) {
        // pick the largest co-residable grid (2 blocks/CU needs 64 KB LDS + <=132 VGPR)
        int mb = 0;
        if (hipOccupancyMaxActiveBlocksPerMultiprocessor(&mb, k_all<GRID_A>, 256, 0) != hipSuccess)
            mb = 1;
        void* kargs[] = { (void*)&A };
        if (mb >= 2) {
            err = hipLaunchCooperativeKernel((const void*)k_all<GRID_A>, dim3(GRID_A), dim3(256),
                                             kargs, 0, stream);
        } else {
            err = hipLaunchCooperativeKernel((const void*)k_all<GRID_B>, dim3(GRID_B), dim3(256),
                                             kargs, 0, stream);
        }
    }
    if (err != hipSuccess) {
        // fallback: proven 9-kernel pipeline
        k_zero<<<dim3(64), 256, 0, stream>>>(hist, (int)ZERO_WORDS);
        k_hist<<<dim3(32, 10), 256, 0, stream>>>(P, hist);
        k_resolve<<<10, 256, 0, stream>>>(hist, binB, kneed, g0);
        k_compact<<<dim3(64, 10), 256, 0, stream>>>(P, binB, gcnt, ecnt, sel, eq);
        k_eqsel<<<10, 256, 0, stream>>>(ecnt, kneed, g0, eq, sel);
        k_feat<<<dim3((NIMG * KTOT + 255) / 256), 256, 0, stream>>>(P, sel, key64, csc, cbox, cobox);
        k_redge<<<dim3(RNK_TILES + EDGE_TILES, NIMG), 256, 0, stream>>>(key64, rpart, cobox, gec, pairs);
        k_scat<<<dim3((KTOT + 255) / 256, NIMG), 256, 0, stream>>>(rpart, csc, cbox, ssc, sbox, rankA);
        k_nms<<<NIMG, 256, 0, stream>>>(ssc, sbox, rankA, gec, pairs, espill, out);
    }
}

// Round 4
// 312.949 us; speedup vs baseline: 1.2965x; 1.1419x over previous
//
#include <hip/hip_runtime.h>
#include <cmath>

#pragma clang fp contract(off)

typedef unsigned int u32;
typedef unsigned short u16;
typedef unsigned long long u64;

#define K_PER_LVL 1000
#define KTOT 5000            // 5 levels * 1000
#define NIMG 2
#define BINS 16384           // histogram bins = top 14 bits of fkey
#define BIN_SHIFT 18
#define SEGW 64              // bins per resolve segment (BINS/256)
#define EQ_CAP 2048
#define ECAP 32768           // max suppression edges per image
#define LECAP 24576          // fallback k_nms LDS edge capacity
#define LECAP2 10240         // coop NMS LDS edge capacity (fits 64 KB union)
#define CBUF 1024            // per-block staging capacity in compact
#define RNK_IB 512           // rank: i-candidates per tile (2 per thread)
#define RNK_JB 250           // rank: j-keys per tile
#define RNK_NJ 20
#define RNK_TILES 200        // 10 i-blk * 20 j-blk
#define EDGE_TILES 820       // sum_{bi=0..19} (79 - 4*bi)
#define NTILES (RNK_TILES + EDGE_TILES)
#define GRID_A 512           // coop grid: 2 blocks/CU (64 KB LDS)
#define GRID_B 256           // coop grid fallback: 1 block/CU

__constant__ int c_LG[5] = {512, 256, 128, 64, 32};
__constant__ int c_LS[5] = {4, 8, 16, 32, 64};
__constant__ int c_LZ[5] = {32, 64, 128, 256, 512};
__constant__ int c_LM[5] = {786432, 196608, 49152, 12288, 3072}; // 3*G*G

struct Ptrs { const float* o[5]; const float* b[5]; };

struct Args {
    Ptrs P;
    u32* hist; u32* gcnt; u32* ecnt; u32* gec;
    int* binB; int* kneed; int* g0; int* sel;
    u64* eq; u64* key64;
    float* csc; float* cbox; float* cobox;
    float* ssc; float* sbox;
    u32* rank; u32* dead;
    u32* pairs; u16* espill; u32* rpart;
    float* out;
};

// ---------------- cache-bypassing (agent-scope, relaxed) accessors ----------------
// Compile to global_load/store sc0 sc1 on gfx950: LLC-coherent, no stale per-XCD L2
// copies -> cross-XCD visible without fences at barriers.
template <typename T>
__device__ inline T ldA(const T* p) {
    return __hip_atomic_load(p, __ATOMIC_RELAXED, __HIP_MEMORY_SCOPE_AGENT);
}
template <typename T>
__device__ inline void stA(T* p, T v) {
    __hip_atomic_store(p, v, __ATOMIC_RELAXED, __HIP_MEMORY_SCOPE_AGENT);
}
__device__ inline void stBox4(float* base, size_t slot2, float x1, float y1, float x2, float y2) {
    u64* p = reinterpret_cast<u64*>(base) + slot2;
    stA(p,     ((u64)__float_as_uint(y1) << 32) | (u64)__float_as_uint(x1));
    stA(p + 1, ((u64)__float_as_uint(y2) << 32) | (u64)__float_as_uint(x2));
}
__device__ inline void ldBox4(const float* base, size_t slot2, float& x1, float& y1, float& x2, float& y2) {
    const u64* p = reinterpret_cast<const u64*>(base) + slot2;
    u64 w0 = ldA(p), w1 = ldA(p + 1);
    x1 = __uint_as_float((u32)w0); y1 = __uint_as_float((u32)(w0 >> 32));
    x2 = __uint_as_float((u32)w1); y2 = __uint_as_float((u32)(w1 >> 32));
}

// ---------------- fence-free grid barrier (round-2 proven; monotonic, replay-safe) ----
// __syncthreads() drains each wave's vmcnt before arrival (compiler-guaranteed), and all
// cross-phase traffic is LLC-coherent (ldA/stA/device atomics), so RELAXED counters are
// valid release points -- no L2 writeback/invalidate per sync.
__device__ __attribute__((aligned(64))) u32 g_barCnt;
__device__ __attribute__((aligned(64))) u32 g_barGen;

template <int NB>
__device__ inline void gridBar() {
    __syncthreads();
    if (threadIdx.x == 0) {
        u32 a = __hip_atomic_fetch_add(&g_barCnt, 1u, __ATOMIC_RELAXED, __HIP_MEMORY_SCOPE_AGENT);
        u32 m1 = a / (u32)NB + 1u;                 // target generation for this barrier
        if ((a & (u32)(NB - 1)) == (u32)(NB - 1)) {
            stA(&g_barGen, m1);                    // releaser
        } else {
            while (ldA(&g_barGen) < m1) __builtin_amdgcn_s_sleep(1);
        }
    }
    __syncthreads();
}

// monotone float -> uint key (larger float => larger key)
__device__ inline u32 fkey(float f) {
    u32 u = __float_as_uint(f);
    return (u & 0x80000000u) ? ~u : (u | 0x80000000u);
}

// block -> (p, slice, nslices) work-proportional mapping for hist/compact
template <int NB>
__device__ inline void histMap(int b, int& p, int& sl, int& nsl) {
    constexpr int H = NB / 2;
    int n = b / H, r = b % H;
    int l, s0, c;
    if constexpr (NB == 512) {                     // L0:188 L1:48 L2:12 L3:4 L4:4
        if (r < 188)      { l = 0; s0 = 0;   c = 188; }
        else if (r < 236) { l = 1; s0 = 188; c = 48;  }
        else if (r < 248) { l = 2; s0 = 236; c = 12;  }
        else if (r < 252) { l = 3; s0 = 248; c = 4;   }
        else              { l = 4; s0 = 252; c = 4;   }
    } else {                                       // L0:94 L1:24 L2:6 L3:2 L4:2
        if (r < 94)       { l = 0; s0 = 0;   c = 94; }
        else if (r < 118) { l = 1; s0 = 94;  c = 24; }
        else if (r < 124) { l = 2; s0 = 118; c = 6;  }
        else if (r < 126) { l = 3; s0 = 124; c = 2;  }
        else              { l = 4; s0 = 126; c = 2;  }
    }
    p = n * 5 + l; sl = r - s0; nsl = c;
}

// featurize one selected candidate (anchor + decode + clip + score + 64b order key)
__device__ inline void featOneM(const Args& A, int p, int s, int m) {
    int n = p / 5, l = p % 5;
    int G = c_LG[l], S = c_LS[l], Z = c_LZ[l];
    int gg = G * G;
    int a = m % 3; int pix = m / 3; int h = pix / G; int w = pix - h * G;

    const float ars[3] = {0.5f, 1.0f, 2.0f};
    float ar = ars[a];
    float hr = sqrtf(ar), wr = 1.0f / hr;
    float wsz = wr * (float)Z, hsz = hr * (float)Z;
    float bx1 = rintf(-0.5f * wsz), by1 = rintf(-0.5f * hsz);
    float bx2 = rintf(0.5f * wsz),  by2 = rintf(0.5f * hsz);
    float sx = (float)(w * S), sy = (float)(h * S);
    float ax1 = sx + bx1, ay1 = sy + by1, ax2 = sx + bx2, ay2 = sy + by2;
    float wa = ax2 - ax1, ha = ay2 - ay1;
    float cxa = ax1 + 0.5f * wa, cya = ay1 + 0.5f * ha;

    const float* bb = A.P.b[l] + (size_t)n * 12 * gg;
    float dx = bb[(a * 4 + 0) * gg + pix];
    float dy = bb[(a * 4 + 1) * gg + pix];
    const float CLIPV = 4.135166556742356f;  // log(1000/16)
    float dw = fminf(bb[(a * 4 + 2) * gg + pix], CLIPV);
    float dh = fminf(bb[(a * 4 + 3) * gg + pix], CLIPV);
    float cx = dx * wa + cxa, cy = dy * ha + cya;
    float ww = expf(dw) * wa, hh = expf(dh) * ha;
    float x1 = cx - 0.5f * ww, y1 = cy - 0.5f * hh;
    float x2 = cx + 0.5f * ww, y2 = cy + 0.5f * hh;
    x1 = fminf(fmaxf(x1, 0.f), 2048.f);
    y1 = fminf(fmaxf(y1, 0.f), 2048.f);
    x2 = fminf(fmaxf(x2, 0.f), 2048.f);
    y2 = fminf(fmaxf(y2, 0.f), 2048.f);

    float raw = A.P.o[l][(size_t)n * 3 * gg + a * gg + pix];
    float sc = 1.0f / (1.0f + expf(-raw));
    bool keep = (x2 - x1 >= 1e-3f) && (y2 - y1 >= 1e-3f) && (sc > 0.0f);

    int slot = n * KTOT + l * K_PER_LVL + s;
    u32 tb = ((u32)l << 20) | (u32)m;          // m < 2^20, l < 8 -> unique
    u32 kk = keep ? fkey(raw) : 0u;
    stA(&A.key64[slot], ((u64)kk << 23) | (u64)(tb ^ 0x7FFFFFu));

    stA(&A.csc[slot], keep ? sc : -INFINITY);
    stBox4(A.cbox, (size_t)slot * 2, x1, y1, x2, y2);
    float off = 4097.0f * (float)l;            // lvl * (W+H+1), batched_nms offset
    stBox4(A.cobox, (size_t)slot * 2, x1 + off, y1 + off, x2 + off, y2 + off);
}

// ---------------- LDS union (<= 64 KB -> 2 blocks/CU at GRID_A) ----------------
struct __align__(16) SmHist { u32 lh[BINS]; };                       // 64 KB exactly
struct __align__(16) SmResolve { u32 seg[256]; u32 tail[SEGW]; int sgS; u32 GS; };
struct __align__(16) SmCompact { u64 leq[CBUF]; u32 lsel[CBUF]; u32 cSel, cEq, baseSel, baseEq; };
struct __align__(16) SmEqsel { u64 a[EQ_CAP]; };
struct __align__(16) SmRedge { u64 kj[RNK_JB]; float cb[64][4]; };
struct __align__(16) SmNms {                                         // ~62.6 KB
    u32 cnt[KTOT];           // 20 KB (count, then fill cursor)
    u32 offs[KTOT + 1];      // 20 KB
    u32 rem32[160];          // dead bitmap (by rank)
    u32 colLo[64], colHi[64];
    u32 scanb[256];
    int picksS;
    u16 edges[LECAP2];       // 20 KB
};
union SmAll { SmHist h; SmResolve r; SmCompact c; SmEqsel e; SmRedge g; SmNms n; };
static_assert(sizeof(SmAll) <= 65536, "LDS union must fit 64 KB for 2 blocks/CU");

// ---------------- workspace layout (shared by coop + fallback paths) ----------------
constexpr size_t OFF_HIST   = 0;
constexpr size_t OFF_GCNT   = OFF_HIST + 10 * BINS * 4;
constexpr size_t OFF_ECNT   = OFF_GCNT + 64;
constexpr size_t OFF_GEC    = OFF_ECNT + 64;
constexpr size_t ZERO_WORDS = (10 * BINS * 4 + 192) / 4;
constexpr size_t OFF_BINB   = OFF_GEC + 64;
constexpr size_t OFF_KNEED  = OFF_BINB + 64;
constexpr size_t OFF_G0     = OFF_KNEED + 64;
constexpr size_t OFF_SEL    = OFF_G0 + 64;
constexpr size_t OFF_EQ     = OFF_SEL + 10 * K_PER_LVL * 4;
constexpr size_t OFF_KEY64  = OFF_EQ + (size_t)10 * EQ_CAP * 8;
constexpr size_t OFF_CSC    = OFF_KEY64 + (size_t)NIMG * KTOT * 8;
constexpr size_t OFF_CBOX   = OFF_CSC + (size_t)NIMG * KTOT * 4;
constexpr size_t OFF_COBOX  = OFF_CBOX + (size_t)NIMG * KTOT * 16;
constexpr size_t OFF_SSC    = OFF_COBOX + (size_t)NIMG * KTOT * 16;
constexpr size_t OFF_SBOX   = OFF_SSC + (size_t)NIMG * KTOT * 4;
constexpr size_t OFF_RANK   = OFF_SBOX + (size_t)NIMG * KTOT * 16;
constexpr size_t OFF_PAIRS  = OFF_RANK + (size_t)NIMG * KTOT * 4;
constexpr size_t OFF_ESPILL = OFF_PAIRS + (size_t)NIMG * ECAP * 4;
constexpr size_t OFF_RPART  = OFF_ESPILL + (size_t)NIMG * ECAP * 2;
constexpr size_t OFF_DEAD   = OFF_RPART + (size_t)RNK_NJ * NIMG * KTOT * 4;
constexpr size_t WS_NEEDED  = OFF_DEAD + (size_t)NIMG * 160 * 4;

// ==================================================================================
//   COOPERATIVE MEGA-KERNEL: 8 phases, 7 fence-free barriers, one dispatch
// ==================================================================================
template <int NB>
__global__ __launch_bounds__(256, 1) void k_all(Args A) {
    __shared__ SmAll sm;
    const int tid = threadIdx.x;
    const int b = blockIdx.x;

    // ---- P0: zero hist + counters + dead (bypass stores; no stale L2 copies) ----
    {
        const int nw = (int)ZERO_WORDS;
        for (int i = b * 256 + tid; i < nw; i += NB * 256) stA(&A.hist[i], 0u);
        for (int i = b * 256 + tid; i < NIMG * 160; i += NB * 256) stA(&A.dead[i], 0u);
        for (int i = tid; i < BINS; i += 256) sm.h.lh[i] = 0;   // LDS hist zero, overlapped
    }
    gridBar<NB>();

    // ---- P1: one-pass 16384-bin histogram (LDS pre-agg, weighted block map) ----
    {
        int p, sl, nsl; histMap<NB>(b, p, sl, nsl);
        int l = p % 5;
        int M4 = c_LM[l] >> 2;
        const float4* base = (const float4*)(A.P.o[l] + (size_t)(p / 5) * c_LM[l]);
        for (int i = sl * 256 + tid; i < M4; i += nsl * 256) {
            float4 v = base[i];
            atomicAdd(&sm.h.lh[fkey(v.x) >> BIN_SHIFT], 1u);
            atomicAdd(&sm.h.lh[fkey(v.y) >> BIN_SHIFT], 1u);
            atomicAdd(&sm.h.lh[fkey(v.z) >> BIN_SHIFT], 1u);
            atomicAdd(&sm.h.lh[fkey(v.w) >> BIN_SHIFT], 1u);
        }
        __syncthreads();
        for (int i = tid; i < BINS; i += 256) {
            u32 c = sm.h.lh[i];
            if (c) atomicAdd(&A.hist[p * BINS + i], c);   // device-scope RMW (LLC)
        }
    }
    gridBar<NB>();

    // ---- P2: resolve threshold bin per (n,l) [blocks 0..9] ----
    if (b < 10) {
        int p = b, t = tid;
        const u32* hb = A.hist + p * BINS;
        for (int i = t; i < BINS; i += 256) sm.h.lh[i] = ldA(&hb[i]);
        __syncthreads();
        u32 s = 0; int base0 = t * SEGW;
        for (int q = 0; q < SEGW; ++q) s += sm.h.lh[base0 + q];
        __syncthreads();                 // lh reads done before seg overwrites alias
        sm.r.seg[t] = s;
        __syncthreads();
        if (t == 0) {
            u32 G = 0; int sg = 255;
            for (; sg > 0; --sg) {
                if (G + sm.r.seg[sg] >= (u32)K_PER_LVL) break;
                G += sm.r.seg[sg];
            }
            sm.r.sgS = sg; sm.r.GS = G;
        }
        __syncthreads();
        int sg = sm.r.sgS;
        if (t < SEGW) sm.r.tail[t] = ldA(&hb[sg * SEGW + t]);
        __syncthreads();
        if (t == 0) {
            u32 G = sm.r.GS; int B = sg * SEGW;
            for (int q = SEGW - 1; q >= 0; --q) {
                u32 c = sm.r.tail[q];
                if (G + c >= (u32)K_PER_LVL) { B = sg * SEGW + q; break; }
                G += c;
            }
            stA(&A.binB[p], B);
            stA(&A.kneed[p], K_PER_LVL - (int)G);
            stA(&A.g0[p], (int)G);
        }
    }
    gridBar<NB>();

    // ---- P3: compact (LDS staging, one reservation atomic per block) ----
    {
        int p, sl, nsl; histMap<NB>(b, p, sl, nsl);
        int l = p % 5;
        int M4 = c_LM[l] >> 2; int gg = c_LM[l] / 3;
        const float4* base = (const float4*)(A.P.o[l] + (size_t)(p / 5) * c_LM[l]);
        int B = ldA(&A.binB[p]);
        if (tid == 0) { sm.c.cSel = 0; sm.c.cEq = 0; }
        __syncthreads();
        for (int i4 = sl * 256 + tid; i4 < M4; i4 += nsl * 256) {
            float4 v = base[i4];
            float vv[4] = {v.x, v.y, v.z, v.w};
            #pragma unroll
            for (int q = 0; q < 4; ++q) {
                u32 k = fkey(vv[q]);
                int bin = (int)(k >> BIN_SHIFT);
                if (bin < B) continue;
                int i = i4 * 4 + q;
                int a = i / gg; int pix = i - a * gg; int m = pix * 3 + a;
                if (bin > B) {
                    u32 t = atomicAdd(&sm.c.cSel, 1u);
                    if (t < CBUF) sm.c.lsel[t] = (u32)m;
                    else { u32 pos = atomicAdd(&A.gcnt[p], 1u); stA(&A.sel[p * K_PER_LVL + pos], m); }
                } else {
                    u64 pk = ((u64)k << 20) | (u64)(0xFFFFFu ^ (u32)m);
                    u32 t = atomicAdd(&sm.c.cEq, 1u);
                    if (t < CBUF) sm.c.leq[t] = pk;
                    else { u32 e = atomicAdd(&A.ecnt[p], 1u); if (e < EQ_CAP) stA(&A.eq[(size_t)p * EQ_CAP + e], pk); }
                }
            }
        }
        __syncthreads();
        if (tid == 0) {
            u32 ns = sm.c.cSel < CBUF ? sm.c.cSel : CBUF;
            u32 ne = sm.c.cEq < CBUF ? sm.c.cEq : CBUF;
            sm.c.baseSel = ns ? atomicAdd(&A.gcnt[p], ns) : 0u;
            sm.c.baseEq  = ne ? atomicAdd(&A.ecnt[p], ne) : 0u;
        }
        __syncthreads();
        u32 ns = sm.c.cSel < CBUF ? sm.c.cSel : CBUF;
        u32 ne = sm.c.cEq < CBUF ? sm.c.cEq : CBUF;
        for (u32 i = tid; i < ns; i += 256) stA(&A.sel[p * K_PER_LVL + sm.c.baseSel + i], (int)sm.c.lsel[i]);
        for (u32 i = tid; i < ne; i += 256) {
            u32 slot = sm.c.baseEq + i;
            if (slot < EQ_CAP) stA(&A.eq[(size_t)p * EQ_CAP + slot], sm.c.leq[i]);
        }
    }
    gridBar<NB>();

    // ---- P4: eqsel (blocks 0..9, boundary items featurized in-register)
    //          + main feat (blocks 10..NB-1) ----
    if (b < 10) {
        int p = b, t = tid;
        int E = (int)ldA(&A.ecnt[p]); if (E > EQ_CAP) E = EQ_CAP;
        int KF = ldA(&A.kneed[p]); int G0 = ldA(&A.g0[p]);
        for (int i = t; i < E; i += 256) sm.e.a[i] = ldA(&A.eq[(size_t)p * EQ_CAP + i]);
        __syncthreads();
        u64 mine[8]; int rk[8];
        #pragma unroll
        for (int q = 0; q < 8; ++q) {
            int i = t + q * 256;
            mine[q] = (i < E) ? sm.e.a[i] : 0ULL;
            rk[q] = 0;
        }
        for (int j = 0; j < E; ++j) {
            u64 v = sm.e.a[j];
            #pragma unroll
            for (int q = 0; q < 8; ++q) rk[q] += (v > mine[q]) ? 1 : 0;
        }
        #pragma unroll
        for (int q = 0; q < 8; ++q) {
            int i = t + q * 256;
            if (i < E && rk[q] < KF) {
                int m = (int)(0xFFFFFu ^ (u32)(mine[q] & 0xFFFFFu));
                featOneM(A, p, G0 + rk[q], m);
            }
        }
    } else {
        for (int idx = (b - 10) * 256 + tid; idx < 10 * K_PER_LVL; idx += (NB - 10) * 256) {
            int p = idx / K_PER_LVL, s = idx - p * K_PER_LVL;
            if (s < ldA(&A.g0[p])) featOneM(A, p, s, ldA(&A.sel[p * K_PER_LVL + s]));
        }
    }
    gridBar<NB>();

    // ---- P5: rank partials + IoU edges, tiles looped over all blocks ----
    for (int tile = b; tile < NIMG * NTILES; tile += NB) {
        int n = tile / NTILES;
        int x = tile - n * NTILES;
        if (x < RNK_TILES) {
            int i0 = (x / 20) * RNK_IB;
            int j0 = (x % 20) * RNK_JB;
            const u64* kb = A.key64 + (size_t)n * KTOT;
            for (int t = tid; t < RNK_JB; t += 256) sm.g.kj[t] = ldA(&kb[j0 + t]);
            __syncthreads();
            int i1 = i0 + tid, i2 = i1 + 256;
            u64 k1 = (i1 < KTOT) ? ldA(&kb[i1]) : ~0ULL;
            u64 k2 = (i2 < KTOT) ? ldA(&kb[i2]) : ~0ULL;
            u32 r1 = 0, r2 = 0;
            #pragma unroll 10
            for (int j = 0; j < RNK_JB; ++j) {
                u64 v = sm.g.kj[j];
                r1 += (v > k1) ? 1u : 0u;
                r2 += (v > k2) ? 1u : 0u;
            }
            u32* rp = A.rpart + (size_t)(x % 20) * (NIMG * KTOT) + n * KTOT;
            if (i1 < KTOT) stA(&rp[i1], r1);
            if (i2 < KTOT) stA(&rp[i2], r2);
        } else {
            int e = x - RNK_TILES, bi = 0;
            while (true) { int c = 79 - 4 * bi; if (e < c) break; e -= c; ++bi; }
            int bj = 4 * bi + e;
            int i = bi * 256 + tid;
            int j0 = bj * 64;
            if (tid < 64) {
                int jl = j0 + tid;
                if (jl < KTOT) {
                    ldBox4(A.cobox, (size_t)(n * KTOT + jl) * 2,
                           sm.g.cb[tid][0], sm.g.cb[tid][1], sm.g.cb[tid][2], sm.g.cb[tid][3]);
                } else {
                    sm.g.cb[tid][0] = 0.f; sm.g.cb[tid][1] = 0.f;
                    sm.g.cb[tid][2] = 0.f; sm.g.cb[tid][3] = 0.f;
                }
            }
            __syncthreads();
            if (i < KTOT) {
                float x1, y1, x2, y2;
                ldBox4(A.cobox, (size_t)(n * KTOT + i) * 2, x1, y1, x2, y2);
                float areai = fmaxf(x2 - x1, 0.f) * fmaxf(y2 - y1, 0.f);
                int lim = KTOT - j0; if (lim > 64) lim = 64;
                for (int jj = 0; jj < lim; ++jj) {
                    int j = j0 + jj;
                    if (j <= i) continue;
                    float bx1 = sm.g.cb[jj][0], by1 = sm.g.cb[jj][1];
                    float bx2 = sm.g.cb[jj][2], by2 = sm.g.cb[jj][3];
                    float areaj = fmaxf(bx2 - bx1, 0.f) * fmaxf(by2 - by1, 0.f);
                    float ltx = fmaxf(x1, bx1), lty = fmaxf(y1, by1);
                    float rbx = fminf(x2, bx2), rby = fminf(y2, by2);
                    float iw = fmaxf(rbx - ltx, 0.f), ih = fmaxf(rby - lty, 0.f);
                    float inter = iw * ih;
                    float iou = inter / (areai + areaj - inter + 1e-9f);
                    if (iou > 0.7f) {
                        u32 pos = atomicAdd(&A.gec[n], 1u);
                        if (pos < ECAP) stA(&A.pairs[(size_t)n * ECAP + pos], ((u32)i << 13) | (u32)j);
                    }
                }
            }
        }
        __syncthreads();   // LDS reused next tile
    }
    gridBar<NB>();

    // ---- P5b: PARALLEL scat (all blocks, one item/thread): rank finalize +
    //           scatter ssc/sbox by rank + dead bitmap. Removes the serial-tail
    //           rank reduction that capped round-2 occupancy at 16/25. ----
    {
        int idx = b * 256 + tid;
        if (idx < NIMG * KTOT) {
            int n = idx / KTOT;
            u32 r = 0;
            #pragma unroll
            for (int jb = 0; jb < RNK_NJ; ++jb)
                r += ldA(&A.rpart[(size_t)jb * (NIMG * KTOT) + idx]);
            stA(&A.rank[idx], r);
            float sc = ldA(&A.csc[idx]);
            stA(&A.ssc[n * KTOT + r], sc);
            float x1, y1, x2, y2;
            ldBox4(A.cbox, (size_t)idx * 2, x1, y1, x2, y2);
            stBox4(A.sbox, (size_t)(n * KTOT + r) * 2, x1, y1, x2, y2);
            if (!(sc > -INFINITY)) atomicOr(&A.dead[n * 160 + (r >> 5)], 1u << (r & 31));
        }
    }
    gridBar<NB>();

    // ---- P6: CSR + greedy NMS sweep [blocks 0..1, one per image] ----
    if (b >= NIMG) return;
    {
        int n = b;
        int lane = tid & 63, wv = tid >> 6;
        SmNms& S = sm.n;

        for (int i = tid; i < KTOT; i += 256) S.cnt[i] = 0;
        if (tid < 160) S.rem32[tid] = ldA(&A.dead[n * 160 + tid]);
        __syncthreads();
        if (tid == 0) {  // pad ranks 5000..5119 dead
            S.rem32[156] |= 0xFFFFFF00u;
            S.rem32[157] = 0xFFFFFFFFu;
            S.rem32[158] = 0xFFFFFFFFu;
            S.rem32[159] = 0xFFFFFFFFu;
        }

        // ---- CSR count pass: remap pairs (orig idx) -> ranks, store remapped in place ----
        int E = (int)ldA(&A.gec[n]); if (E > ECAP) E = ECAP;
        for (int k = tid; k < E; k += 256) {
            u32 pr = ldA(&A.pairs[(size_t)n * ECAP + k]);
            u32 ra = ldA(&A.rank[n * KTOT + (pr >> 13)]);
            u32 rb = ldA(&A.rank[n * KTOT + (pr & 0x1FFFu)]);
            u32 src = ra < rb ? ra : rb, dst = ra < rb ? rb : ra;
            stA(&A.pairs[(size_t)n * ECAP + k], (src << 13) | dst);
            atomicAdd(&S.cnt[src], 1u);
        }
        __syncthreads();
        u32 s0 = 0; int base0 = tid * 20;
        if (tid < 250) for (int q = 0; q < 20; ++q) s0 += S.cnt[base0 + q];
        S.scanb[tid] = s0;
        __syncthreads();
        for (int off = 1; off < 256; off <<= 1) {
            u32 v = (tid >= off) ? S.scanb[tid - off] : 0;
            __syncthreads();
            S.scanb[tid] += v;
            __syncthreads();
        }
        u32 tbase = (tid == 0) ? 0u : S.scanb[tid - 1];
        if (tid < 250) {
            u32 run = tbase;
            for (int q = 0; q < 20; ++q) { S.offs[base0 + q] = run; run += S.cnt[base0 + q]; }
        }
        if (tid == 0) S.offs[KTOT] = S.scanb[255];
        __syncthreads();
        for (int i = tid; i < KTOT; i += 256) S.cnt[i] = 0;
        __syncthreads();
        // ---- CSR fill pass: one load per edge (pairs already remapped) ----
        for (int k = tid; k < E; k += 256) {
            u32 pr = ldA(&A.pairs[(size_t)n * ECAP + k]);
            u32 src = pr >> 13, dst = pr & 0x1FFFu;
            u32 slot = S.offs[src] + atomicAdd(&S.cnt[src], 1u);
            if (slot < LECAP2) S.edges[slot] = (u16)dst;
            else A.espill[(size_t)n * ECAP + slot] = (u16)dst;   // same-block traffic
        }
        __syncthreads();

        // ---- wave-0 sweep in rank order ----
        if (wv == 0) {
            int picks = 0;
            for (int w = 0; w < 79 && picks < 1000; ++w) {
                u64 rw = ((u64)S.rem32[2 * w + 1] << 32) | S.rem32[2 * w];
                u64 alive = ~rw;
                if (alive == 0ULL) continue;
                int c = w * 64 + lane;
                bool amAlive = ((alive >> lane) & 1ULL) != 0ULL;
                int e0 = 0, e1 = 0;
                if (amAlive) { e0 = (int)S.offs[c]; e1 = (int)S.offs[c + 1]; }
                S.colLo[lane] = 0; S.colHi[lane] = 0;
                bool anyIntra = false;
                for (int k = e0; k < e1; ++k) {
                    int dst = (k < LECAP2) ? (int)S.edges[k] : (int)A.espill[(size_t)n * ECAP + k];
                    if ((dst >> 6) == w) {
                        if (lane < 32) atomicOr(&S.colLo[dst & 63], 1u << lane);
                        else           atomicOr(&S.colHi[dst & 63], 1u << (lane - 32));
                        anyIntra = true;
                    }
                }
                u64 cm;
                if (__ballot(anyIntra) == 0ULL) {
                    cm = alive;
                } else {
                    u64 col = ((u64)S.colHi[lane] << 32) | S.colLo[lane];
                    cm = 0ULL;
                    u64 remb = alive;             // uniform across lanes -> converged shfl
                    while (remb) {
                        int e2 = __builtin_ctzll(remb);
                        remb &= remb - 1ULL;
                        u64 ce = __shfl(col, e2);
                        if ((cm & ce) == 0ULL) cm |= (1ULL << e2);
                    }
                }
                int allowed = 1000 - picks;
                int ncom = __popcll(cm);
                while (ncom > allowed) { cm &= ~(1ULL << (63 - __clzll(cm))); --ncom; }
                if ((cm >> lane) & 1ULL) {
                    int pos = picks + (int)__popcll(cm & ((1ULL << lane) - 1ULL));
                    float bx1, by1, bx2, by2;
                    ldBox4(A.sbox, (size_t)(n * KTOT + c) * 2, bx1, by1, bx2, by2);
                    float* op = &A.out[(n * 1000 + pos) * 5];
                    op[0] = bx1; op[1] = by1; op[2] = bx2; op[3] = by2;
                    op[4] = ldA(&A.ssc[n * KTOT + c]);
                    for (int k = e0; k < e1; ++k) {
                        int dst = (k < LECAP2) ? (int)S.edges[k] : (int)A.espill[(size_t)n * ECAP + k];
                        atomicOr(&S.rem32[dst >> 5], 1u << (dst & 31));
                    }
                }
                picks += ncom;
            }
            if (lane == 0) S.picksS = picks;
        }
        __syncthreads();
        int picksF = S.picksS;
        int basec = (n * 1000 + picksF) * 5, cntz = (1000 - picksF) * 5;
        for (int t2 = tid; t2 < cntz; t2 += 256) A.out[basec + t2] = 0.f;
    }
}

// ==================================================================================
//   FALLBACK: original 9-kernel pipeline (used if cooperative launch unavailable)
// ==================================================================================
__global__ __launch_bounds__(256) void k_zero(u32* __restrict__ z, int nwords) {
    int i = blockIdx.x * 256 + threadIdx.x;
    int stride = gridDim.x * 256;
    for (; i < nwords; i += stride) z[i] = 0;
}

__global__ __launch_bounds__(256) void k_hist(Ptrs P, u32* __restrict__ hist) {
    int p = blockIdx.y; int l = p % 5; int n = p / 5;
    int M4 = c_LM[l] >> 2;
    const float4* base = (const float4*)(P.o[l] + (size_t)n * c_LM[l]);
    __shared__ u32 lh[BINS];
    for (int i = threadIdx.x; i < BINS; i += 256) lh[i] = 0;
    __syncthreads();
    int stride = gridDim.x * 256;
    for (int i = blockIdx.x * 256 + threadIdx.x; i < M4; i += stride) {
        float4 v = base[i];
        atomicAdd(&lh[fkey(v.x) >> BIN_SHIFT], 1u);
        atomicAdd(&lh[fkey(v.y) >> BIN_SHIFT], 1u);
        atomicAdd(&lh[fkey(v.z) >> BIN_SHIFT], 1u);
        atomicAdd(&lh[fkey(v.w) >> BIN_SHIFT], 1u);
    }
    __syncthreads();
    for (int i = threadIdx.x; i < BINS; i += 256) {
        u32 c = lh[i];
        if (c) atomicAdd(&hist[p * BINS + i], c);
    }
}

__global__ __launch_bounds__(256) void k_resolve(const u32* __restrict__ hist,
                                                 int* __restrict__ binB, int* __restrict__ kneed,
                                                 int* __restrict__ g0) {
    int p = blockIdx.x, t = threadIdx.x;
    __shared__ u32 seg[256];
    __shared__ u32 tail[SEGW];
    __shared__ int sgS; __shared__ u32 GS;
    u32 s = 0;
    const u32* hb = hist + p * BINS;
    int base = t * SEGW;
    for (int q = 0; q < SEGW; ++q) s += hb[base + q];
    seg[t] = s;
    __syncthreads();
    if (t == 0) {
        u32 G = 0; int sg = 255;
        for (; sg > 0; --sg) {
            if (G + seg[sg] >= (u32)K_PER_LVL) break;
            G += seg[sg];
        }
        sgS = sg; GS = G;
    }
    __syncthreads();
    int sg = sgS;
    if (t < SEGW) tail[t] = hb[sg * SEGW + t];
    __syncthreads();
    if (t == 0) {
        u32 G = GS; int B = sg * SEGW;
        for (int q = SEGW - 1; q >= 0; --q) {
            u32 c = tail[q];
            if (G + c >= (u32)K_PER_LVL) { B = sg * SEGW + q; break; }
            G += c;
        }
        binB[p] = B;
        kneed[p] = K_PER_LVL - (int)G;
        g0[p] = (int)G;
    }
}

__global__ __launch_bounds__(256) void k_compact(Ptrs P, const int* __restrict__ binB,
                                                 u32* gcnt, u32* ecnt,
                                                 int* __restrict__ sel, u64* __restrict__ eq) {
    int p = blockIdx.y; int l = p % 5; int n = p / 5;
    int M4 = c_LM[l] >> 2; int gg = c_LM[l] / 3;
    const float4* base = (const float4*)(P.o[l] + (size_t)n * c_LM[l]);
    int B = binB[p];
    __shared__ u32 lsel[CBUF];
    __shared__ u64 leq[CBUF];
    __shared__ u32 cSel, cEq, baseSel, baseEq;
    if (threadIdx.x == 0) { cSel = 0; cEq = 0; }
    __syncthreads();
    int stride = gridDim.x * 256;
    for (int i4 = blockIdx.x * 256 + threadIdx.x; i4 < M4; i4 += stride) {
        float4 v = base[i4];
        float vv[4] = {v.x, v.y, v.z, v.w};
        #pragma unroll
        for (int q = 0; q < 4; ++q) {
            u32 k = fkey(vv[q]);
            int bin = (int)(k >> BIN_SHIFT);
            if (bin < B) continue;
            int i = i4 * 4 + q;
            int a = i / gg; int pix = i - a * gg; int m = pix * 3 + a;
            if (bin > B) {
                u32 t = atomicAdd(&cSel, 1u);
                if (t < CBUF) lsel[t] = (u32)m;
                else { u32 pos = atomicAdd(&gcnt[p], 1u); sel[p * K_PER_LVL + pos] = m; }
            } else {
                u64 pk = ((u64)k << 20) | (u64)(0xFFFFFu ^ (u32)m);
                u32 t = atomicAdd(&cEq, 1u);
                if (t < CBUF) leq[t] = pk;
                else { u32 e = atomicAdd(&ecnt[p], 1u); if (e < EQ_CAP) eq[(size_t)p * EQ_CAP + e] = pk; }
            }
        }
    }
    __syncthreads();
    if (threadIdx.x == 0) {
        u32 ns = cSel < CBUF ? cSel : CBUF;
        u32 ne = cEq < CBUF ? cEq : CBUF;
        baseSel = ns ? atomicAdd(&gcnt[p], ns) : 0u;
        baseEq  = ne ? atomicAdd(&ecnt[p], ne) : 0u;
    }
    __syncthreads();
    u32 ns = cSel < CBUF ? cSel : CBUF;
    u32 ne = cEq < CBUF ? cEq : CBUF;
    for (u32 i = threadIdx.x; i < ns; i += 256) sel[p * K_PER_LVL + baseSel + i] = (int)lsel[i];
    for (u32 i = threadIdx.x; i < ne; i += 256) {
        u32 slot = baseEq + i;
        if (slot < EQ_CAP) eq[(size_t)p * EQ_CAP + slot] = leq[i];
    }
}

__global__ __launch_bounds__(256) void k_eqsel(const u32* __restrict__ ecnt, const int* __restrict__ kneed,
                                               const int* __restrict__ g0,
                                               const u64* __restrict__ eq, int* __restrict__ sel) {
    int p = blockIdx.x, t = threadIdx.x;
    int E = (int)ecnt[p]; if (E > EQ_CAP) E = EQ_CAP;
    int KF = kneed[p]; int G0 = g0[p];
    __shared__ u64 a[EQ_CAP];
    for (int i = t; i < E; i += 256) a[i] = eq[(size_t)p * EQ_CAP + i];
    __syncthreads();
    u64 mine[8]; int rk[8];
    #pragma unroll
    for (int q = 0; q < 8; ++q) {
        int i = t + q * 256;
        mine[q] = (i < E) ? a[i] : 0ULL;
        rk[q] = 0;
    }
    for (int j = 0; j < E; ++j) {
        u64 v = a[j];
        #pragma unroll
        for (int q = 0; q < 8; ++q) rk[q] += (v > mine[q]) ? 1 : 0;
    }
    #pragma unroll
    for (int q = 0; q < 8; ++q) {
        int i = t + q * 256;
        if (i < E && rk[q] < KF) {
            int m = (int)(0xFFFFFu ^ (u32)(mine[q] & 0xFFFFFu));
            sel[p * K_PER_LVL + G0 + rk[q]] = m;
        }
    }
}

__global__ void k_feat(Ptrs P, const int* __restrict__ sel, u64* __restrict__ key64,
                       float* __restrict__ csc, float* __restrict__ cbox, float* __restrict__ cobox) {
    int tid = blockIdx.x * 256 + threadIdx.x;
    if (tid >= NIMG * KTOT) return;
    int p = tid / K_PER_LVL, s = tid - p * K_PER_LVL;
    Args A;
    A.P = P; A.sel = (int*)sel; A.key64 = key64; A.csc = csc; A.cbox = cbox; A.cobox = cobox;
    featOneM(A, p, s, sel[p * K_PER_LVL + s]);
}

__global__ __launch_bounds__(256) void k_redge(const u64* __restrict__ key64, u32* __restrict__ rpart,
                                               const float* __restrict__ cobox,
                                               u32* __restrict__ gE, u32* __restrict__ gPairs) {
    int n = blockIdx.y;
    int x = blockIdx.x;
    __shared__ u64 kj[RNK_JB];
    __shared__ float cb[64][4];
    if (x < RNK_TILES) {
        int i0 = (x / 20) * RNK_IB;
        int j0 = (x % 20) * RNK_JB;
        const u64* kb = key64 + (size_t)n * KTOT;
        for (int t = threadIdx.x; t < RNK_JB; t += 256) kj[t] = kb[j0 + t];
        __syncthreads();
        int i1 = i0 + threadIdx.x, i2 = i1 + 256;
        u64 k1 = (i1 < KTOT) ? kb[i1] : ~0ULL;
        u64 k2 = (i2 < KTOT) ? kb[i2] : ~0ULL;
        u32 r1 = 0, r2 = 0;
        #pragma unroll 10
        for (int j = 0; j < RNK_JB; ++j) {
            u64 v = kj[j];
            r1 += (v > k1) ? 1u : 0u;
            r2 += (v > k2) ? 1u : 0u;
        }
        u32* rp = rpart + (size_t)(x % 20) * (NIMG * KTOT) + n * KTOT;
        if (i1 < KTOT) rp[i1] = r1;
        if (i2 < KTOT) rp[i2] = r2;
        return;
    }
    int e = x - RNK_TILES, bi = 0;
    while (true) { int c = 79 - 4 * bi; if (e < c) break; e -= c; ++bi; }
    int bj = 4 * bi + e;
    int i = bi * 256 + threadIdx.x;
    int j0 = bj * 64;
    if (threadIdx.x < 64) {
        int jl = j0 + threadIdx.x;
        if (jl < KTOT) {
            cb[threadIdx.x][0] = cobox[(size_t)(n * KTOT + jl) * 4 + 0];
            cb[threadIdx.x][1] = cobox[(size_t)(n * KTOT + jl) * 4 + 1];
            cb[threadIdx.x][2] = cobox[(size_t)(n * KTOT + jl) * 4 + 2];
            cb[threadIdx.x][3] = cobox[(size_t)(n * KTOT + jl) * 4 + 3];
        } else {
            cb[threadIdx.x][0] = 0.f; cb[threadIdx.x][1] = 0.f;
            cb[threadIdx.x][2] = 0.f; cb[threadIdx.x][3] = 0.f;
        }
    }
    __syncthreads();
    if (i >= KTOT) return;
    float x1 = cobox[(size_t)(n * KTOT + i) * 4 + 0];
    float y1 = cobox[(size_t)(n * KTOT + i) * 4 + 1];
    float x2 = cobox[(size_t)(n * KTOT + i) * 4 + 2];
    float y2 = cobox[(size_t)(n * KTOT + i) * 4 + 3];
    float areai = fmaxf(x2 - x1, 0.f) * fmaxf(y2 - y1, 0.f);
    int lim = KTOT - j0; if (lim > 64) lim = 64;
    for (int jj = 0; jj < lim; ++jj) {
        int j = j0 + jj;
        if (j <= i) continue;
        float bx1 = cb[jj][0], by1 = cb[jj][1], bx2 = cb[jj][2], by2 = cb[jj][3];
        float areaj = fmaxf(bx2 - bx1, 0.f) * fmaxf(by2 - by1, 0.f);
        float ltx = fmaxf(x1, bx1), lty = fmaxf(y1, by1);
        float rbx = fminf(x2, bx2), rby = fminf(y2, by2);
        float iw = fmaxf(rbx - ltx, 0.f), ih = fmaxf(rby - lty, 0.f);
        float inter = iw * ih;
        float iou = inter / (areai + areaj - inter + 1e-9f);
        if (iou > 0.7f) {
            u32 pos = atomicAdd(&gE[n], 1u);
            if (pos < ECAP) gPairs[(size_t)n * ECAP + pos] = ((u32)i << 13) | (u32)j;
        }
    }
}

__global__ __launch_bounds__(256) void k_scat(const u32* __restrict__ rpart, const float* __restrict__ csc,
                       const float* __restrict__ cbox,
                       float* __restrict__ ssc, float* __restrict__ sbox, u32* __restrict__ rankArr) {
    int n = blockIdx.y;
    int i = blockIdx.x * 256 + threadIdx.x;
    if (i >= KTOT) return;
    int idx = n * KTOT + i;
    u32 rank = 0;
    #pragma unroll
    for (int jb = 0; jb < RNK_NJ; ++jb) rank += rpart[(size_t)jb * (NIMG * KTOT) + idx];
    rankArr[idx] = rank;
    int src = idx, dst = n * KTOT + (int)rank;
    ssc[dst] = csc[src];
    sbox[dst * 4 + 0] = cbox[src * 4 + 0]; sbox[dst * 4 + 1] = cbox[src * 4 + 1];
    sbox[dst * 4 + 2] = cbox[src * 4 + 2]; sbox[dst * 4 + 3] = cbox[src * 4 + 3];
}

__global__ __launch_bounds__(256, 1) void k_nms(const float* __restrict__ ssc,
                      const float* __restrict__ sbox, const u32* __restrict__ rankArr,
                      const u32* __restrict__ gE, const u32* __restrict__ gPairs,
                      u16* __restrict__ gEdges, float* __restrict__ out) {
    int n = blockIdx.x, tid = threadIdx.x;
    int lane = tid & 63, wv = tid >> 6;
    __shared__ u32 cnt[KTOT];
    __shared__ u32 offs[KTOT + 1];
    __shared__ u16 edges[LECAP];
    __shared__ u32 rem32[160];
    __shared__ u32 colLo[64], colHi[64];
    __shared__ u32 scanb[256];
    __shared__ int picksS;

    for (int i = tid; i < KTOT; i += 256) cnt[i] = 0;
    if (tid < 160) rem32[tid] = 0xFFFFFFFFu;
    __syncthreads();
    for (int w = wv; w < 79; w += 4) {
        int i = w * 64 + lane;
        bool dead = (i >= KTOT) || !(ssc[n * KTOT + i] > -INFINITY);
        u64 db = __ballot(dead);
        if (lane == 0) { rem32[2 * w] = (u32)db; rem32[2 * w + 1] = (u32)(db >> 32); }
    }
    __syncthreads();

    int E = (int)gE[n]; if (E > ECAP) E = ECAP;
    for (int k = tid; k < E; k += 256) {
        u32 p = gPairs[(size_t)n * ECAP + k];
        u32 ra = rankArr[n * KTOT + (p >> 13)], rb = rankArr[n * KTOT + (p & 0x1FFFu)];
        u32 src = ra < rb ? ra : rb;
        atomicAdd(&cnt[src], 1u);
    }
    __syncthreads();
    u32 s = 0; int base = tid * 20;
    if (tid < 250) for (int q = 0; q < 20; ++q) s += cnt[base + q];
    scanb[tid] = s;
    __syncthreads();
    for (int off = 1; off < 256; off <<= 1) {
        u32 v = (tid >= off) ? scanb[tid - off] : 0;
        __syncthreads();
        scanb[tid] += v;
        __syncthreads();
    }
    u32 tbase = (tid == 0) ? 0u : scanb[tid - 1];
    if (tid < 250) {
        u32 run = tbase;
        for (int q = 0; q < 20; ++q) { offs[base + q] = run; run += cnt[base + q]; }
    }
    if (tid == 0) offs[KTOT] = scanb[255];
    __syncthreads();
    for (int i = tid; i < KTOT; i += 256) cnt[i] = 0;
    __syncthreads();
    for (int k = tid; k < E; k += 256) {
        u32 p = gPairs[(size_t)n * ECAP + k];
        u32 ra = rankArr[n * KTOT + (p >> 13)], rb = rankArr[n * KTOT + (p & 0x1FFFu)];
        u32 src = ra < rb ? ra : rb, dst = ra < rb ? rb : ra;
        u32 slot = offs[src] + atomicAdd(&cnt[src], 1u);
        if (slot < LECAP) edges[slot] = (u16)dst;
        else gEdges[(size_t)n * ECAP + slot] = (u16)dst;
    }
    __syncthreads();

    if (wv == 0) {
        int picks = 0;
        for (int w = 0; w < 79 && picks < 1000; ++w) {
            u64 rw = ((u64)rem32[2 * w + 1] << 32) | rem32[2 * w];
            u64 alive = ~rw;
            if (alive == 0ULL) continue;
            int c = w * 64 + lane;
            bool amAlive = ((alive >> lane) & 1ULL) != 0ULL;
            int e0 = 0, e1 = 0;
            if (amAlive) { e0 = (int)offs[c]; e1 = (int)offs[c + 1]; }
            colLo[lane] = 0; colHi[lane] = 0;
            bool anyIntra = false;
            for (int k = e0; k < e1; ++k) {
                int dst = (k < LECAP) ? (int)edges[k] : (int)gEdges[(size_t)n * ECAP + k];
                if ((dst >> 6) == w) {
                    if (lane < 32) atomicOr(&colLo[dst & 63], 1u << lane);
                    else           atomicOr(&colHi[dst & 63], 1u << (lane - 32));
                    anyIntra = true;
                }
            }
            u64 cm;
            if (__ballot(anyIntra) == 0ULL) {
                cm = alive;
            } else {
                u64 col = ((u64)colHi[lane] << 32) | colLo[lane];
                cm = 0ULL;
                for (int e = 0; e < 64; ++e) {
                    if (!((alive >> e) & 1ULL)) continue;
                    u64 ce = __shfl(col, e);
                    if ((cm & ce) == 0ULL) cm |= (1ULL << e);
                }
            }
            int allowed = 1000 - picks;
            int ncom = __popcll(cm);
            while (ncom > allowed) { cm &= ~(1ULL << (63 - __clzll(cm))); --ncom; }
            if ((cm >> lane) & 1ULL) {
                int pos = picks + (int)__popcll(cm & ((1ULL << lane) - 1ULL));
                const float* bp = &sbox[(size_t)(n * KTOT + c) * 4];
                float* op = &out[(n * 1000 + pos) * 5];
                op[0] = bp[0]; op[1] = bp[1]; op[2] = bp[2]; op[3] = bp[3];
                op[4] = ssc[n * KTOT + c];
                for (int k = e0; k < e1; ++k) {
                    int dst = (k < LECAP) ? (int)edges[k] : (int)gEdges[(size_t)n * ECAP + k];
                    atomicOr(&rem32[dst >> 5], 1u << (dst & 31));
                }
            }
            picks += ncom;
        }
        if (lane == 0) picksS = picks;
    }
    __syncthreads();
    int picksF = picksS;
    int basec = (n * 1000 + picksF) * 5, cntz = (1000 - picksF) * 5;
    for (int t = tid; t < cntz; t += 256) out[basec + t] = 0.f;
}

// ==================================================================================
extern "C" void kernel_launch(void* const* d_in, const int* in_sizes, int n_in,
                              void* d_out, int out_size, void* d_ws, size_t ws_size,
                              hipStream_t stream) {
    if (ws_size < WS_NEEDED) return;

    bool dictOrder = (in_sizes[1] > in_sizes[0]);
    Ptrs P;
    for (int l = 0; l < 5; ++l) {
        P.o[l] = (const float*)d_in[dictOrder ? (2 * l)     : l];
        P.b[l] = (const float*)d_in[dictOrder ? (2 * l + 1) : (5 + l)];
    }
    char* ws = (char*)d_ws;

    Args A;
    A.P = P;
    A.hist   = (u32*)(ws + OFF_HIST);
    A.gcnt   = (u32*)(ws + OFF_GCNT);
    A.ecnt   = (u32*)(ws + OFF_ECNT);
    A.gec    = (u32*)(ws + OFF_GEC);
    A.binB   = (int*)(ws + OFF_BINB);
    A.kneed  = (int*)(ws + OFF_KNEED);
    A.g0     = (int*)(ws + OFF_G0);
    A.sel    = (int*)(ws + OFF_SEL);
    A.eq     = (u64*)(ws + OFF_EQ);
    A.key64  = (u64*)(ws + OFF_KEY64);
    A.csc    = (float*)(ws + OFF_CSC);
    A.cbox   = (float*)(ws + OFF_CBOX);
    A.cobox  = (float*)(ws + OFF_COBOX);
    A.ssc    = (float*)(ws + OFF_SSC);
    A.sbox   = (float*)(ws + OFF_SBOX);
    A.rank   = (u32*)(ws + OFF_RANK);
    A.dead   = (u32*)(ws + OFF_DEAD);
    A.pairs  = (u32*)(ws + OFF_PAIRS);
    A.espill = (u16*)(ws + OFF_ESPILL);
    A.rpart  = (u32*)(ws + OFF_RPART);
    A.out    = (float*)d_out;

    int dev = 0, coop = 0;
    hipGetDevice(&dev);
    hipDeviceGetAttribute(&coop, hipDeviceAttributeCooperativeLaunch, dev);

    hipError_t err = hipErrorUnknown;
    if (coop) {
        int mb = 0;
        if (hipOccupancyMaxActiveBlocksPerMultiprocessor(&mb, k_all<GRID_A>, 256, 0) != hipSuccess)
            mb = 1;
        void* kargs[] = { (void*)&A };
        if (mb >= 2) {
            err = hipLaunchCooperativeKernel((const void*)k_all<GRID_A>, dim3(GRID_A), dim3(256),
                                             kargs, 0, stream);
        } else {
            err = hipLaunchCooperativeKernel((const void*)k_all<GRID_B>, dim3(GRID_B), dim3(256),
                                             kargs, 0, stream);
        }
    }
    if (err != hipSuccess) {
        // fallback: proven 9-kernel pipeline
        k_zero<<<dim3(64), 256, 0, stream>>>(A.hist, (int)ZERO_WORDS);
        k_hist<<<dim3(32, 10), 256, 0, stream>>>(P, A.hist);
        k_resolve<<<10, 256, 0, stream>>>(A.hist, A.binB, A.kneed, A.g0);
        k_compact<<<dim3(64, 10), 256, 0, stream>>>(P, A.binB, A.gcnt, A.ecnt, A.sel, A.eq);
        k_eqsel<<<10, 256, 0, stream>>>(A.ecnt, A.kneed, A.g0, A.eq, A.sel);
        k_feat<<<dim3((NIMG * KTOT + 255) / 256), 256, 0, stream>>>(P, A.sel, A.key64, A.csc, A.cbox, A.cobox);
        k_redge<<<dim3(RNK_TILES + EDGE_TILES, NIMG), 256, 0, stream>>>(A.key64, A.rpart, A.cobox, A.gec, A.pairs);
        k_scat<<<dim3((KTOT + 255) / 256, NIMG), 256, 0, stream>>>(A.rpart, A.csc, A.cbox, A.ssc, A.sbox, A.rank);
        k_nms<<<NIMG, 256, 0, stream>>>(A.ssc, A.sbox, A.rank, A.gec, A.pairs, A.espill, A.out);
    }
}

// Round 6
// 195.948 us; speedup vs baseline: 2.0706x; 1.5971x over previous
//
#include <hip/hip_runtime.h>
#include <cmath>

#pragma clang fp contract(off)

typedef unsigned int u32;
typedef unsigned short u16;
typedef unsigned long long u64;

#define K_PER_LVL 1000
#define KTOT 5000            // 5 levels * 1000
#define NIMG 2
#define BINS 16384           // histogram bins = top 14 bits of fkey (binade/32)
#define BIN_SHIFT 18
#define SEGW (BINS / 256)    // 64 bins per resolve segment
#define EQ_CAP 2048
#define ECAP 32768           // max suppression edges per image (est ~4k; 8x margin)
#define LECAP 24576          // edges held in LDS; overflow spills to global
#define CBUF 1024            // per-block staging capacity in k_compact
#define RNK_IB 512           // rank: i-candidates per block (2 per thread)
#define RNK_JB 250           // rank: j-keys per block
#define RNK_NJ (KTOT / RNK_JB)   // 20 j-blocks
#define RNK_TILES 200        // 10 i-blk * 20 j-blk
#define EDGE_TILES 820       // sum_{bi=0..19} (79 - 4*bi)

__constant__ int c_LG[5] = {512, 256, 128, 64, 32};      // grid dim (square)
__constant__ int c_LS[5] = {4, 8, 16, 32, 64};           // stride
__constant__ int c_LZ[5] = {32, 64, 128, 256, 512};      // anchor size
__constant__ int c_LM[5] = {786432, 196608, 49152, 12288, 3072}; // 3*G*G

struct Ptrs { const float* o[5]; const float* b[5]; };

// monotone float -> uint key (larger float => larger key)
__device__ inline u32 fkey(float f) {
    u32 u = __float_as_uint(f);
    return (u & 0x80000000u) ? ~u : (u | 0x80000000u);
}

// featurize one selected candidate (anchor + decode + clip + score + 64b order key)
// Bit-exact copy of the round-0 k_feat body (absmax 0 verified).
__device__ inline void featOne(const Ptrs& P, int p, int s, int m,
                               u64* __restrict__ key64, float* __restrict__ csc,
                               float* __restrict__ cbox, float* __restrict__ cobox) {
    int n = p / 5, l = p % 5;
    int G = c_LG[l], S = c_LS[l], Z = c_LZ[l];
    int gg = G * G;
    int a = m % 3; int pix = m / 3; int h = pix / G; int w = pix - h * G;

    const float ars[3] = {0.5f, 1.0f, 2.0f};
    float ar = ars[a];
    float hr = sqrtf(ar), wr = 1.0f / hr;
    float wsz = wr * (float)Z, hsz = hr * (float)Z;
    float bx1 = rintf(-0.5f * wsz), by1 = rintf(-0.5f * hsz);
    float bx2 = rintf(0.5f * wsz),  by2 = rintf(0.5f * hsz);
    float sx = (float)(w * S), sy = (float)(h * S);
    float ax1 = sx + bx1, ay1 = sy + by1, ax2 = sx + bx2, ay2 = sy + by2;
    float wa = ax2 - ax1, ha = ay2 - ay1;
    float cxa = ax1 + 0.5f * wa, cya = ay1 + 0.5f * ha;

    const float* bb = P.b[l] + (size_t)n * 12 * gg;
    float dx = bb[(a * 4 + 0) * gg + pix];
    float dy = bb[(a * 4 + 1) * gg + pix];
    const float CLIPV = 4.135166556742356f;  // log(1000/16)
    float dw = fminf(bb[(a * 4 + 2) * gg + pix], CLIPV);
    float dh = fminf(bb[(a * 4 + 3) * gg + pix], CLIPV);
    float cx = dx * wa + cxa, cy = dy * ha + cya;
    float ww = expf(dw) * wa, hh = expf(dh) * ha;
    float x1 = cx - 0.5f * ww, y1 = cy - 0.5f * hh;
    float x2 = cx + 0.5f * ww, y2 = cy + 0.5f * hh;
    x1 = fminf(fmaxf(x1, 0.f), 2048.f);
    y1 = fminf(fmaxf(y1, 0.f), 2048.f);
    x2 = fminf(fmaxf(x2, 0.f), 2048.f);
    y2 = fminf(fmaxf(y2, 0.f), 2048.f);

    float raw = P.o[l][(size_t)n * 3 * gg + a * gg + pix];
    float sc = 1.0f / (1.0f + expf(-raw));
    bool keep = (x2 - x1 >= 1e-3f) && (y2 - y1 >= 1e-3f) && (sc > 0.0f);

    int slot = n * KTOT + l * K_PER_LVL + s;
    // total order key: raw desc, then (level asc, m asc) == reference concat-position order
    u32 tb = ((u32)l << 20) | (u32)m;          // m < 2^20, l < 8  -> 23 bits, unique
    u32 kk = keep ? fkey(raw) : 0u;            // invalid sinks below every valid (finite raw)
    key64[slot] = ((u64)kk << 23) | (u64)(tb ^ 0x7FFFFFu);

    csc[slot] = keep ? sc : -INFINITY;
    cbox[slot * 4 + 0] = x1; cbox[slot * 4 + 1] = y1;
    cbox[slot * 4 + 2] = x2; cbox[slot * 4 + 3] = y2;
    float off = 4097.0f * (float)l;            // lvl * (W+H+1), batched_nms offset
    cobox[slot * 4 + 0] = x1 + off; cobox[slot * 4 + 1] = y1 + off;
    cobox[slot * 4 + 2] = x2 + off; cobox[slot * 4 + 3] = y2 + off;
}

// ---------------- zero hist + counters ----------------
__global__ __launch_bounds__(256) void k_zero(u32* __restrict__ z, int nwords) {
    int i = blockIdx.x * 256 + threadIdx.x;
    int stride = gridDim.x * 256;
    for (; i < nwords; i += stride) z[i] = 0;
}

// ---------------- one-pass 16384-bin histogram (float4 loads, LDS pre-agg) ----------------
__global__ __launch_bounds__(256) void k_hist(Ptrs P, u32* __restrict__ hist) {
    int p = blockIdx.y; int l = p % 5; int n = p / 5;
    int M4 = c_LM[l] >> 2;
    const float4* base = (const float4*)(P.o[l] + (size_t)n * c_LM[l]);
    __shared__ u32 lh[BINS];                     // 64 KB
    for (int i = threadIdx.x; i < BINS; i += 256) lh[i] = 0;
    __syncthreads();
    int stride = gridDim.x * 256;
    for (int i = blockIdx.x * 256 + threadIdx.x; i < M4; i += stride) {
        float4 v = base[i];
        atomicAdd(&lh[fkey(v.x) >> BIN_SHIFT], 1u);
        atomicAdd(&lh[fkey(v.y) >> BIN_SHIFT], 1u);
        atomicAdd(&lh[fkey(v.z) >> BIN_SHIFT], 1u);
        atomicAdd(&lh[fkey(v.w) >> BIN_SHIFT], 1u);
    }
    __syncthreads();
    for (int i = threadIdx.x; i < BINS; i += 256) {
        u32 c = lh[i];
        if (c) atomicAdd(&hist[p * BINS + i], c);
    }
}

// ---------------- resolve: threshold bin B, G = #(keys above B), KF = 1000 - G ----------------
__global__ __launch_bounds__(256) void k_resolve(const u32* __restrict__ hist,
                                                 int* __restrict__ binB, int* __restrict__ kneed,
                                                 int* __restrict__ g0) {
    int p = blockIdx.x, t = threadIdx.x;
    __shared__ u32 seg[256];
    __shared__ u32 tail[SEGW];
    __shared__ int sgS; __shared__ u32 GS;
    u32 s = 0;
    const u32* hb = hist + p * BINS;
    int base = t * SEGW;
    for (int q = 0; q < SEGW; ++q) s += hb[base + q];
    seg[t] = s;
    __syncthreads();
    if (t == 0) {
        u32 G = 0; int sg = 255;
        for (; sg > 0; --sg) {
            if (G + seg[sg] >= (u32)K_PER_LVL) break;
            G += seg[sg];
        }
        sgS = sg; GS = G;
    }
    __syncthreads();
    int sg = sgS;
    if (t < SEGW) tail[t] = hb[sg * SEGW + t];
    __syncthreads();
    if (t == 0) {
        u32 G = GS; int B = sg * SEGW;
        for (int b = SEGW - 1; b >= 0; --b) {
            u32 c = tail[b];
            if (G + c >= (u32)K_PER_LVL) { B = sg * SEGW + b; break; }
            G += c;
        }
        binB[p] = B;
        kneed[p] = K_PER_LVL - (int)G;   // KF taken from boundary bin
        g0[p] = (int)G;                  // count strictly above bin B
    }
}

// ---------------- compact: block-local LDS staging, ONE reservation atomic per block ----------------
__global__ __launch_bounds__(256) void k_compact(Ptrs P, const int* __restrict__ binB,
                                                 u32* gcnt, u32* ecnt,
                                                 int* __restrict__ sel, u64* __restrict__ eq) {
    int p = blockIdx.y; int l = p % 5; int n = p / 5;
    int M4 = c_LM[l] >> 2; int gg = c_LM[l] / 3;
    const float4* base = (const float4*)(P.o[l] + (size_t)n * c_LM[l]);
    int B = binB[p];
    __shared__ u32 lsel[CBUF];
    __shared__ u64 leq[CBUF];
    __shared__ u32 cSel, cEq, baseSel, baseEq;
    if (threadIdx.x == 0) { cSel = 0; cEq = 0; }
    __syncthreads();
    int stride = gridDim.x * 256;
    for (int i4 = blockIdx.x * 256 + threadIdx.x; i4 < M4; i4 += stride) {
        float4 v = base[i4];
        float vv[4] = {v.x, v.y, v.z, v.w};
        #pragma unroll
        for (int q = 0; q < 4; ++q) {
            u32 k = fkey(vv[q]);
            int bin = (int)(k >> BIN_SHIFT);
            if (bin < B) continue;
            int i = i4 * 4 + q;
            // input linear i = a*gg + pix ; flattened m = pix*3 + a  (h,w,a order)
            int a = i / gg; int pix = i - a * gg; int m = pix * 3 + a;
            if (bin > B) {
                u32 t = atomicAdd(&cSel, 1u);
                if (t < CBUF) lsel[t] = (u32)m;
                else { u32 pos = atomicAdd(&gcnt[p], 1u); sel[p * K_PER_LVL + pos] = m; }
            } else {
                u64 pk = ((u64)k << 20) | (u64)(0xFFFFFu ^ (u32)m);
                u32 t = atomicAdd(&cEq, 1u);
                if (t < CBUF) leq[t] = pk;
                else { u32 e = atomicAdd(&ecnt[p], 1u); if (e < EQ_CAP) eq[(size_t)p * EQ_CAP + e] = pk; }
            }
        }
    }
    __syncthreads();
    if (threadIdx.x == 0) {
        u32 ns = cSel < CBUF ? cSel : CBUF;
        u32 ne = cEq < CBUF ? cEq : CBUF;
        baseSel = ns ? atomicAdd(&gcnt[p], ns) : 0u;
        baseEq  = ne ? atomicAdd(&ecnt[p], ne) : 0u;
    }
    __syncthreads();
    u32 ns = cSel < CBUF ? cSel : CBUF;
    u32 ne = cEq < CBUF ? cEq : CBUF;
    for (u32 i = threadIdx.x; i < ns; i += 256) sel[p * K_PER_LVL + baseSel + i] = (int)lsel[i];
    for (u32 i = threadIdx.x; i < ne; i += 256) {
        u32 slot = baseEq + i;
        if (slot < EQ_CAP) eq[(size_t)p * EQ_CAP + slot] = leq[i];
    }
}

// ---------------- fused eqsel + featurize (one launch; no cross-block dependency) ----------------
// Blocks 0..9: rank-by-count selection in the boundary bin, winners featurized straight from
// registers (no sel round-trip). Blocks 10..49: main feat for s < g0[p] via sel[].
__global__ __launch_bounds__(256) void k_eqfeat(Ptrs P, const u32* __restrict__ ecnt,
                       const int* __restrict__ kneed, const int* __restrict__ g0,
                       const u64* __restrict__ eq, const int* __restrict__ sel,
                       u64* __restrict__ key64, float* __restrict__ csc,
                       float* __restrict__ cbox, float* __restrict__ cobox) {
    int b = blockIdx.x, t = threadIdx.x;
    if (b < 10) {
        int p = b;
        int E = (int)ecnt[p]; if (E > EQ_CAP) E = EQ_CAP;
        int KF = kneed[p]; int G0 = g0[p];
        __shared__ u64 a[EQ_CAP];
        for (int i = t; i < E; i += 256) a[i] = eq[(size_t)p * EQ_CAP + i];
        __syncthreads();
        u64 mine[8]; int rk[8];
        #pragma unroll
        for (int q = 0; q < 8; ++q) {
            int i = t + q * 256;
            mine[q] = (i < E) ? a[i] : 0ULL;
            rk[q] = 0;
        }
        for (int j = 0; j < E; ++j) {
            u64 v = a[j];                            // uniform index -> LDS broadcast
            #pragma unroll
            for (int q = 0; q < 8; ++q) rk[q] += (v > mine[q]) ? 1 : 0;
        }
        #pragma unroll
        for (int q = 0; q < 8; ++q) {
            int i = t + q * 256;
            if (i < E && rk[q] < KF) {
                int m = (int)(0xFFFFFu ^ (u32)(mine[q] & 0xFFFFFu));
                featOne(P, p, G0 + rk[q], m, key64, csc, cbox, cobox);
            }
        }
    } else {
        for (int idx = (b - 10) * 256 + t; idx < 10 * K_PER_LVL; idx += 40 * 256) {
            int p = idx / K_PER_LVL, s = idx - p * K_PER_LVL;
            if (s < g0[p]) featOne(P, p, s, sel[p * K_PER_LVL + s], key64, csc, cbox, cobox);
        }
    }
}

// ---------------- fused: rank partial counts + IoU edges on UNSORTED boxes ----------------
__global__ __launch_bounds__(256) void k_redge(const u64* __restrict__ key64, u32* __restrict__ rpart,
                                               const float* __restrict__ cobox,
                                               u32* __restrict__ gE, u32* __restrict__ gPairs) {
    int n = blockIdx.y;
    int x = blockIdx.x;
    __shared__ u64 kj[RNK_JB];
    __shared__ float cb[64][4];
    if (x < RNK_TILES) {
        // ---- rank partials ----
        int i0 = (x / 20) * RNK_IB;
        int j0 = (x % 20) * RNK_JB;
        const u64* kb = key64 + (size_t)n * KTOT;
        for (int t = threadIdx.x; t < RNK_JB; t += 256) kj[t] = kb[j0 + t];
        __syncthreads();
        int i1 = i0 + threadIdx.x, i2 = i1 + 256;
        u64 k1 = (i1 < KTOT) ? kb[i1] : ~0ULL;
        u64 k2 = (i2 < KTOT) ? kb[i2] : ~0ULL;
        u32 r1 = 0, r2 = 0;
        #pragma unroll 10
        for (int j = 0; j < RNK_JB; ++j) {
            u64 v = kj[j];
            r1 += (v > k1) ? 1u : 0u;
            r2 += (v > k2) ? 1u : 0u;
        }
        u32* rp = rpart + (size_t)(x % 20) * (NIMG * KTOT) + n * KTOT;
        if (i1 < KTOT) rp[i1] = r1;
        if (i2 < KTOT) rp[i2] = r2;
        return;
    }
    // ---- edge tile: decode e -> (bi, bj) with bj in [4*bi, 78] ----
    int e = x - RNK_TILES, bi = 0;
    while (true) { int c = 79 - 4 * bi; if (e < c) break; e -= c; ++bi; }
    int bj = 4 * bi + e;
    int i = bi * 256 + threadIdx.x;
    int j0 = bj * 64;
    if (threadIdx.x < 64) {
        int jl = j0 + threadIdx.x;
        if (jl < KTOT) {
            cb[threadIdx.x][0] = cobox[(size_t)(n * KTOT + jl) * 4 + 0];
            cb[threadIdx.x][1] = cobox[(size_t)(n * KTOT + jl) * 4 + 1];
            cb[threadIdx.x][2] = cobox[(size_t)(n * KTOT + jl) * 4 + 2];
            cb[threadIdx.x][3] = cobox[(size_t)(n * KTOT + jl) * 4 + 3];
        } else {
            cb[threadIdx.x][0] = 0.f; cb[threadIdx.x][1] = 0.f;
            cb[threadIdx.x][2] = 0.f; cb[threadIdx.x][3] = 0.f;
        }
    }
    __syncthreads();
    if (i >= KTOT) return;
    float x1 = cobox[(size_t)(n * KTOT + i) * 4 + 0];
    float y1 = cobox[(size_t)(n * KTOT + i) * 4 + 1];
    float x2 = cobox[(size_t)(n * KTOT + i) * 4 + 2];
    float y2 = cobox[(size_t)(n * KTOT + i) * 4 + 3];
    float areai = fmaxf(x2 - x1, 0.f) * fmaxf(y2 - y1, 0.f);
    int lim = KTOT - j0; if (lim > 64) lim = 64;
    for (int jj = 0; jj < lim; ++jj) {
        int j = j0 + jj;
        if (j <= i) continue;
        float bx1 = cb[jj][0], by1 = cb[jj][1], bx2 = cb[jj][2], by2 = cb[jj][3];
        float areaj = fmaxf(bx2 - bx1, 0.f) * fmaxf(by2 - by1, 0.f);
        float ltx = fmaxf(x1, bx1), lty = fmaxf(y1, by1);
        float rbx = fminf(x2, bx2), rby = fminf(y2, by2);
        float iw = fmaxf(rbx - ltx, 0.f), ih = fmaxf(rby - lty, 0.f);
        float inter = iw * ih;
        float iou = inter / (areai + areaj - inter + 1e-9f);
        if (iou > 0.7f) {
            u32 pos = atomicAdd(&gE[n], 1u);
            if (pos < ECAP) gPairs[(size_t)n * ECAP + pos] = ((u32)i << 13) | (u32)j;  // original indices
        }
    }
}

// ---------------- rank part 2: sum partials, scatter payload + rank[] ----------------
__global__ __launch_bounds__(256) void k_scat(const u32* __restrict__ rpart, const float* __restrict__ csc,
                       const float* __restrict__ cbox,
                       float* __restrict__ ssc, float* __restrict__ sbox, u32* __restrict__ rankArr) {
    int n = blockIdx.y;
    int i = blockIdx.x * 256 + threadIdx.x;
    if (i >= KTOT) return;
    int idx = n * KTOT + i;
    u32 rank = 0;
    #pragma unroll
    for (int jb = 0; jb < RNK_NJ; ++jb) rank += rpart[(size_t)jb * (NIMG * KTOT) + idx];
    rankArr[idx] = rank;
    int src = idx, dst = n * KTOT + (int)rank;
    ssc[dst] = csc[src];
    sbox[dst * 4 + 0] = cbox[src * 4 + 0]; sbox[dst * 4 + 1] = cbox[src * 4 + 1];
    sbox[dst * 4 + 2] = cbox[src * 4 + 2]; sbox[dst * 4 + 3] = cbox[src * 4 + 3];
}

// ---------------- greedy NMS sweep over sparse CSR (pairs remapped via rank[]) ----------------
__global__ __launch_bounds__(256, 1) void k_nms(const float* __restrict__ ssc,
                      const float* __restrict__ sbox, const u32* __restrict__ rankArr,
                      const u32* __restrict__ gE, u32* __restrict__ gPairs,
                      u16* __restrict__ gEdges, float* __restrict__ out) {
    int n = blockIdx.x, tid = threadIdx.x;
    int lane = tid & 63, wv = tid >> 6;          // 4 waves
    __shared__ u32 cnt[KTOT];                    // 20 KB (count, then fill cursor)
    __shared__ u32 offs[KTOT + 1];               // 20 KB
    __shared__ u16 edges[LECAP];                 // 48 KB
    __shared__ u32 rem32[160];                   // dead bitmap (2 u32 per 64-word)
    __shared__ u32 colLo[64], colHi[64];
    __shared__ u32 scanb[256];
    __shared__ int picksS;

    for (int i = tid; i < KTOT; i += 256) cnt[i] = 0;
    if (tid < 160) rem32[tid] = 0xFFFFFFFFu;
    __syncthreads();
    for (int w = wv; w < 79; w += 4) {
        int i = w * 64 + lane;
        bool dead = (i >= KTOT) || !(ssc[n * KTOT + i] > -INFINITY);
        u64 db = __ballot(dead);
        if (lane == 0) { rem32[2 * w] = (u32)db; rem32[2 * w + 1] = (u32)(db >> 32); }
    }
    __syncthreads();

    // ---- CSR count pass: remap pairs (orig idx) -> ranks, store remapped in place ----
    // (ranks are identical across graph replays -> idempotent; pairs rewritten each launch)
    int E = (int)gE[n]; if (E > ECAP) E = ECAP;
    for (int k = tid; k < E; k += 256) {
        u32 p = gPairs[(size_t)n * ECAP + k];
        u32 ra = rankArr[n * KTOT + (p >> 13)], rb = rankArr[n * KTOT + (p & 0x1FFFu)];
        u32 src = ra < rb ? ra : rb, dst = ra < rb ? rb : ra;
        gPairs[(size_t)n * ECAP + k] = (src << 13) | dst;
        atomicAdd(&cnt[src], 1u);
    }
    __syncthreads();
    u32 s = 0; int base = tid * 20;
    if (tid < 250) for (int q = 0; q < 20; ++q) s += cnt[base + q];
    scanb[tid] = s;
    __syncthreads();
    for (int off = 1; off < 256; off <<= 1) {
        u32 v = (tid >= off) ? scanb[tid - off] : 0;
        __syncthreads();
        scanb[tid] += v;
        __syncthreads();
    }
    u32 tbase = (tid == 0) ? 0u : scanb[tid - 1];
    if (tid < 250) {
        u32 run = tbase;
        for (int q = 0; q < 20; ++q) { offs[base + q] = run; run += cnt[base + q]; }
    }
    if (tid == 0) offs[KTOT] = scanb[255];
    __syncthreads();
    for (int i = tid; i < KTOT; i += 256) cnt[i] = 0;
    __syncthreads();
    // ---- CSR fill pass: one load per edge (pairs already remapped) ----
    for (int k = tid; k < E; k += 256) {
        u32 p = gPairs[(size_t)n * ECAP + k];
        u32 src = p >> 13, dst = p & 0x1FFFu;
        u32 slot = offs[src] + atomicAdd(&cnt[src], 1u);
        if (slot < LECAP) edges[slot] = (u16)dst;
        else gEdges[(size_t)n * ECAP + slot] = (u16)dst;
    }
    __syncthreads();

    // ---- wave-0 sweep: rank order, no global memory on the critical path ----
    if (wv == 0) {
        int picks = 0;
        for (int w = 0; w < 79 && picks < 1000; ++w) {
            u64 rw = ((u64)rem32[2 * w + 1] << 32) | rem32[2 * w];
            u64 alive = ~rw;
            if (alive == 0ULL) continue;
            int c = w * 64 + lane;
            bool amAlive = ((alive >> lane) & 1ULL) != 0ULL;
            int e0 = 0, e1 = 0;
            if (amAlive) { e0 = (int)offs[c]; e1 = (int)offs[c + 1]; }
            colLo[lane] = 0; colHi[lane] = 0;
            bool anyIntra = false;
            for (int k = e0; k < e1; ++k) {
                int dst = (k < LECAP) ? (int)edges[k] : (int)gEdges[(size_t)n * ECAP + k];
                if ((dst >> 6) == w) {
                    if (lane < 32) atomicOr(&colLo[dst & 63], 1u << lane);
                    else           atomicOr(&colHi[dst & 63], 1u << (lane - 32));
                    anyIntra = true;
                }
            }
            u64 cm;
            if (__ballot(anyIntra) == 0ULL) {
                cm = alive;
            } else {
                u64 col = ((u64)colHi[lane] << 32) | colLo[lane];
                cm = 0ULL;
                u64 remb = alive;                // uniform across lanes -> converged shfl
                while (remb) {
                    int e = __builtin_ctzll(remb);
                    remb &= remb - 1ULL;
                    u64 ce = __shfl(col, e);
                    if ((cm & ce) == 0ULL) cm |= (1ULL << e);
                }
            }
            int allowed = 1000 - picks;
            int ncom = __popcll(cm);
            while (ncom > allowed) { cm &= ~(1ULL << (63 - __clzll(cm))); --ncom; }
            if ((cm >> lane) & 1ULL) {
                int pos = picks + (int)__popcll(cm & ((1ULL << lane) - 1ULL));
                const float* bp = &sbox[(size_t)(n * KTOT + c) * 4];
                float* op = &out[(n * 1000 + pos) * 5];
                op[0] = bp[0]; op[1] = bp[1]; op[2] = bp[2]; op[3] = bp[3];
                op[4] = ssc[n * KTOT + c];
                for (int k = e0; k < e1; ++k) {
                    int dst = (k < LECAP) ? (int)edges[k] : (int)gEdges[(size_t)n * ECAP + k];
                    atomicOr(&rem32[dst >> 5], 1u << (dst & 31));
                }
            }
            picks += ncom;
        }
        if (lane == 0) picksS = picks;
    }
    __syncthreads();
    int picksF = picksS;
    int basec = (n * 1000 + picksF) * 5, cntz = (1000 - picksF) * 5;
    for (int t = tid; t < cntz; t += 256) out[basec + t] = 0.f;
}

// ---------------- workspace layout ----------------
constexpr size_t OFF_HIST   = 0;                                       // zeroed region start
constexpr size_t OFF_GCNT   = OFF_HIST + 10 * BINS * 4;
constexpr size_t OFF_ECNT   = OFF_GCNT + 64;
constexpr size_t OFF_GEC    = OFF_ECNT + 64;                           // edge counters (2 u32)
constexpr size_t ZERO_WORDS = (10 * BINS * 4 + 192) / 4;               // hist + gcnt + ecnt + gec
constexpr size_t OFF_BINB   = OFF_GEC + 64;
constexpr size_t OFF_KNEED  = OFF_BINB + 64;
constexpr size_t OFF_G0     = OFF_KNEED + 64;
constexpr size_t OFF_SEL    = OFF_G0 + 64;
constexpr size_t OFF_EQ     = OFF_SEL + 10 * K_PER_LVL * 4;            // 8-aligned
constexpr size_t OFF_KEY64  = OFF_EQ + (size_t)10 * EQ_CAP * 8;
constexpr size_t OFF_CSC    = OFF_KEY64 + (size_t)NIMG * KTOT * 8;
constexpr size_t OFF_CBOX   = OFF_CSC + (size_t)NIMG * KTOT * 4;
constexpr size_t OFF_COBOX  = OFF_CBOX + (size_t)NIMG * KTOT * 16;
constexpr size_t OFF_SSC    = OFF_COBOX + (size_t)NIMG * KTOT * 16;
constexpr size_t OFF_SBOX   = OFF_SSC + (size_t)NIMG * KTOT * 4;
constexpr size_t OFF_RANK   = OFF_SBOX + (size_t)NIMG * KTOT * 16;     // u32[NIMG*KTOT]
constexpr size_t OFF_PAIRS  = OFF_RANK + (size_t)NIMG * KTOT * 4;      // u32[NIMG*ECAP]
constexpr size_t OFF_ESPILL = OFF_PAIRS + (size_t)NIMG * ECAP * 4;     // u16[NIMG*ECAP]
constexpr size_t OFF_RPART  = OFF_ESPILL + (size_t)NIMG * ECAP * 2;    // u32[RNK_NJ][NIMG*KTOT]
constexpr size_t WS_NEEDED  = OFF_RPART + (size_t)RNK_NJ * NIMG * KTOT * 4;

extern "C" void kernel_launch(void* const* d_in, const int* in_sizes, int n_in,
                              void* d_out, int out_size, void* d_ws, size_t ws_size,
                              hipStream_t stream) {
    if (ws_size < WS_NEEDED) return;

    // Detect input ordering from sizes: dict order interleaves (obj0,box0,...)
    bool dictOrder = (in_sizes[1] > in_sizes[0]);
    Ptrs P;
    for (int l = 0; l < 5; ++l) {
        P.o[l] = (const float*)d_in[dictOrder ? (2 * l)     : l];
        P.b[l] = (const float*)d_in[dictOrder ? (2 * l + 1) : (5 + l)];
    }
    char* ws = (char*)d_ws;
    u32*   hist   = (u32*)(ws + OFF_HIST);
    u32*   gcnt   = (u32*)(ws + OFF_GCNT);
    u32*   ecnt   = (u32*)(ws + OFF_ECNT);
    u32*   gec    = (u32*)(ws + OFF_GEC);
    int*   binB   = (int*)(ws + OFF_BINB);
    int*   kneed  = (int*)(ws + OFF_KNEED);
    int*   g0     = (int*)(ws + OFF_G0);
    int*   sel    = (int*)(ws + OFF_SEL);
    u64*   eq     = (u64*)(ws + OFF_EQ);
    u64*   key64  = (u64*)(ws + OFF_KEY64);
    float* csc    = (float*)(ws + OFF_CSC);
    float* cbox   = (float*)(ws + OFF_CBOX);
    float* cobox  = (float*)(ws + OFF_COBOX);
    float* ssc    = (float*)(ws + OFF_SSC);
    float* sbox   = (float*)(ws + OFF_SBOX);
    u32*   rankA  = (u32*)(ws + OFF_RANK);
    u32*   pairs  = (u32*)(ws + OFF_PAIRS);
    u16*   espill = (u16*)(ws + OFF_ESPILL);
    u32*   rpart  = (u32*)(ws + OFF_RPART);
    float* out    = (float*)d_out;

    k_zero<<<dim3(64), 256, 0, stream>>>(hist, (int)ZERO_WORDS);
    k_hist<<<dim3(32, 10), 256, 0, stream>>>(P, hist);
    k_resolve<<<10, 256, 0, stream>>>(hist, binB, kneed, g0);
    k_compact<<<dim3(64, 10), 256, 0, stream>>>(P, binB, gcnt, ecnt, sel, eq);
    k_eqfeat<<<50, 256, 0, stream>>>(P, ecnt, kneed, g0, eq, sel, key64, csc, cbox, cobox);
    k_redge<<<dim3(RNK_TILES + EDGE_TILES, NIMG), 256, 0, stream>>>(key64, rpart, cobox, gec, pairs);
    k_scat<<<dim3((KTOT + 255) / 256, NIMG), 256, 0, stream>>>(rpart, csc, cbox, ssc, sbox, rankA);
    k_nms<<<NIMG, 256, 0, stream>>>(ssc, sbox, rankA, gec, pairs, espill, out);
}

// Round 7
// 193.624 us; speedup vs baseline: 2.0954x; 1.0120x over previous
//
#include <hip/hip_runtime.h>
#include <cmath>

#pragma clang fp contract(off)

typedef unsigned int u32;
typedef unsigned short u16;
typedef unsigned long long u64;

#define K_PER_LVL 1000
#define KTOT 5000            // 5 levels * 1000
#define NIMG 2
#define BINS 16384           // histogram bins = top 14 bits of fkey (binade/32)
#define BIN_SHIFT 18
#define SEGW (BINS / 256)    // 64 bins per resolve segment
#define EQ_CAP 2048
#define ECAP 32768           // max suppression edges per image (est ~4k; 8x margin)
#define LECAP 24576          // edges held in LDS; overflow spills to global
#define CBUF 1024            // per-block staging capacity in k_compact
#define RNK_IB 512           // rank: i-candidates per block (2 per thread)
#define RNK_JB 250           // rank: j-keys per block
#define RNK_NJ (KTOT / RNK_JB)   // 20 j-blocks
#define RNK_TILES 200        // 10 i-blk * 20 j-blk
#define EDGE_TILES 820       // sum_{bi=0..19} (79 - 4*bi)

__constant__ int c_LG[5] = {512, 256, 128, 64, 32};      // grid dim (square)
__constant__ int c_LS[5] = {4, 8, 16, 32, 64};           // stride
__constant__ int c_LZ[5] = {32, 64, 128, 256, 512};      // anchor size
__constant__ int c_LM[5] = {786432, 196608, 49152, 12288, 3072}; // 3*G*G

struct Ptrs { const float* o[5]; const float* b[5]; };

// monotone float -> uint key (larger float => larger key)
__device__ inline u32 fkey(float f) {
    u32 u = __float_as_uint(f);
    return (u & 0x80000000u) ? ~u : (u | 0x80000000u);
}

// featurize one selected candidate (anchor + decode + clip + score + 64b order key)
// Bit-exact copy of the round-0 k_feat body (absmax 0 verified).
__device__ inline void featOne(const Ptrs& P, int p, int s, int m,
                               u64* __restrict__ key64, float* __restrict__ csc,
                               float* __restrict__ cbox, float* __restrict__ cobox) {
    int n = p / 5, l = p % 5;
    int G = c_LG[l], S = c_LS[l], Z = c_LZ[l];
    int gg = G * G;
    int a = m % 3; int pix = m / 3; int h = pix / G; int w = pix - h * G;

    const float ars[3] = {0.5f, 1.0f, 2.0f};
    float ar = ars[a];
    float hr = sqrtf(ar), wr = 1.0f / hr;
    float wsz = wr * (float)Z, hsz = hr * (float)Z;
    float bx1 = rintf(-0.5f * wsz), by1 = rintf(-0.5f * hsz);
    float bx2 = rintf(0.5f * wsz),  by2 = rintf(0.5f * hsz);
    float sx = (float)(w * S), sy = (float)(h * S);
    float ax1 = sx + bx1, ay1 = sy + by1, ax2 = sx + bx2, ay2 = sy + by2;
    float wa = ax2 - ax1, ha = ay2 - ay1;
    float cxa = ax1 + 0.5f * wa, cya = ay1 + 0.5f * ha;

    const float* bb = P.b[l] + (size_t)n * 12 * gg;
    float dx = bb[(a * 4 + 0) * gg + pix];
    float dy = bb[(a * 4 + 1) * gg + pix];
    const float CLIPV = 4.135166556742356f;  // log(1000/16)
    float dw = fminf(bb[(a * 4 + 2) * gg + pix], CLIPV);
    float dh = fminf(bb[(a * 4 + 3) * gg + pix], CLIPV);
    float cx = dx * wa + cxa, cy = dy * ha + cya;
    float ww = expf(dw) * wa, hh = expf(dh) * ha;
    float x1 = cx - 0.5f * ww, y1 = cy - 0.5f * hh;
    float x2 = cx + 0.5f * ww, y2 = cy + 0.5f * hh;
    x1 = fminf(fmaxf(x1, 0.f), 2048.f);
    y1 = fminf(fmaxf(y1, 0.f), 2048.f);
    x2 = fminf(fmaxf(x2, 0.f), 2048.f);
    y2 = fminf(fmaxf(y2, 0.f), 2048.f);

    float raw = P.o[l][(size_t)n * 3 * gg + a * gg + pix];
    float sc = 1.0f / (1.0f + expf(-raw));
    bool keep = (x2 - x1 >= 1e-3f) && (y2 - y1 >= 1e-3f) && (sc > 0.0f);

    int slot = n * KTOT + l * K_PER_LVL + s;
    // total order key: raw desc, then (level asc, m asc) == reference concat-position order
    u32 tb = ((u32)l << 20) | (u32)m;          // m < 2^20, l < 8  -> 23 bits, unique
    u32 kk = keep ? fkey(raw) : 0u;            // invalid sinks below every valid (finite raw)
    key64[slot] = ((u64)kk << 23) | (u64)(tb ^ 0x7FFFFFu);

    csc[slot] = keep ? sc : -INFINITY;
    cbox[slot * 4 + 0] = x1; cbox[slot * 4 + 1] = y1;
    cbox[slot * 4 + 2] = x2; cbox[slot * 4 + 3] = y2;
    float off = 4097.0f * (float)l;            // lvl * (W+H+1), batched_nms offset
    cobox[slot * 4 + 0] = x1 + off; cobox[slot * 4 + 1] = y1 + off;
    cobox[slot * 4 + 2] = x2 + off; cobox[slot * 4 + 3] = y2 + off;
}

// ---------------- zero hist + counters + rank ----------------
__global__ __launch_bounds__(256) void k_zero(u32* __restrict__ z, int nwords) {
    int i = blockIdx.x * 256 + threadIdx.x;
    int stride = gridDim.x * 256;
    for (; i < nwords; i += stride) z[i] = 0;
}

// ---------------- one-pass 16384-bin histogram (float4 loads, LDS pre-agg) ----------------
__global__ __launch_bounds__(256) void k_hist(Ptrs P, u32* __restrict__ hist) {
    int p = blockIdx.y; int l = p % 5; int n = p / 5;
    int M4 = c_LM[l] >> 2;
    const float4* base = (const float4*)(P.o[l] + (size_t)n * c_LM[l]);
    __shared__ u32 lh[BINS];                     // 64 KB
    for (int i = threadIdx.x; i < BINS; i += 256) lh[i] = 0;
    __syncthreads();
    int stride = gridDim.x * 256;
    for (int i = blockIdx.x * 256 + threadIdx.x; i < M4; i += stride) {
        float4 v = base[i];
        atomicAdd(&lh[fkey(v.x) >> BIN_SHIFT], 1u);
        atomicAdd(&lh[fkey(v.y) >> BIN_SHIFT], 1u);
        atomicAdd(&lh[fkey(v.z) >> BIN_SHIFT], 1u);
        atomicAdd(&lh[fkey(v.w) >> BIN_SHIFT], 1u);
    }
    __syncthreads();
    for (int i = threadIdx.x; i < BINS; i += 256) {
        u32 c = lh[i];
        if (c) atomicAdd(&hist[p * BINS + i], c);
    }
}

// ---------------- resolve: threshold bin B, G = #(keys above B), KF = 1000 - G ----------------
__global__ __launch_bounds__(256) void k_resolve(const u32* __restrict__ hist,
                                                 int* __restrict__ binB, int* __restrict__ kneed,
                                                 int* __restrict__ g0) {
    int p = blockIdx.x, t = threadIdx.x;
    __shared__ u32 seg[256];
    __shared__ u32 tail[SEGW];
    __shared__ int sgS; __shared__ u32 GS;
    u32 s = 0;
    const u32* hb = hist + p * BINS;
    int base = t * SEGW;
    for (int q = 0; q < SEGW; ++q) s += hb[base + q];
    seg[t] = s;
    __syncthreads();
    if (t == 0) {
        u32 G = 0; int sg = 255;
        for (; sg > 0; --sg) {
            if (G + seg[sg] >= (u32)K_PER_LVL) break;
            G += seg[sg];
        }
        sgS = sg; GS = G;
    }
    __syncthreads();
    int sg = sgS;
    if (t < SEGW) tail[t] = hb[sg * SEGW + t];
    __syncthreads();
    if (t == 0) {
        u32 G = GS; int B = sg * SEGW;
        for (int b = SEGW - 1; b >= 0; --b) {
            u32 c = tail[b];
            if (G + c >= (u32)K_PER_LVL) { B = sg * SEGW + b; break; }
            G += c;
        }
        binB[p] = B;
        kneed[p] = K_PER_LVL - (int)G;   // KF taken from boundary bin
        g0[p] = (int)G;                  // count strictly above bin B
    }
}

// ---------------- compact: block-local LDS staging, ONE reservation atomic per block ----------------
__global__ __launch_bounds__(256) void k_compact(Ptrs P, const int* __restrict__ binB,
                                                 u32* gcnt, u32* ecnt,
                                                 int* __restrict__ sel, u64* __restrict__ eq) {
    int p = blockIdx.y; int l = p % 5; int n = p / 5;
    int M4 = c_LM[l] >> 2; int gg = c_LM[l] / 3;
    const float4* base = (const float4*)(P.o[l] + (size_t)n * c_LM[l]);
    int B = binB[p];
    __shared__ u32 lsel[CBUF];
    __shared__ u64 leq[CBUF];
    __shared__ u32 cSel, cEq, baseSel, baseEq;
    if (threadIdx.x == 0) { cSel = 0; cEq = 0; }
    __syncthreads();
    int stride = gridDim.x * 256;
    for (int i4 = blockIdx.x * 256 + threadIdx.x; i4 < M4; i4 += stride) {
        float4 v = base[i4];
        float vv[4] = {v.x, v.y, v.z, v.w};
        #pragma unroll
        for (int q = 0; q < 4; ++q) {
            u32 k = fkey(vv[q]);
            int bin = (int)(k >> BIN_SHIFT);
            if (bin < B) continue;
            int i = i4 * 4 + q;
            // input linear i = a*gg + pix ; flattened m = pix*3 + a  (h,w,a order)
            int a = i / gg; int pix = i - a * gg; int m = pix * 3 + a;
            if (bin > B) {
                u32 t = atomicAdd(&cSel, 1u);
                if (t < CBUF) lsel[t] = (u32)m;
                else { u32 pos = atomicAdd(&gcnt[p], 1u); sel[p * K_PER_LVL + pos] = m; }
            } else {
                u64 pk = ((u64)k << 20) | (u64)(0xFFFFFu ^ (u32)m);
                u32 t = atomicAdd(&cEq, 1u);
                if (t < CBUF) leq[t] = pk;
                else { u32 e = atomicAdd(&ecnt[p], 1u); if (e < EQ_CAP) eq[(size_t)p * EQ_CAP + e] = pk; }
            }
        }
    }
    __syncthreads();
    if (threadIdx.x == 0) {
        u32 ns = cSel < CBUF ? cSel : CBUF;
        u32 ne = cEq < CBUF ? cEq : CBUF;
        baseSel = ns ? atomicAdd(&gcnt[p], ns) : 0u;
        baseEq  = ne ? atomicAdd(&ecnt[p], ne) : 0u;
    }
    __syncthreads();
    u32 ns = cSel < CBUF ? cSel : CBUF;
    u32 ne = cEq < CBUF ? cEq : CBUF;
    for (u32 i = threadIdx.x; i < ns; i += 256) sel[p * K_PER_LVL + baseSel + i] = (int)lsel[i];
    for (u32 i = threadIdx.x; i < ne; i += 256) {
        u32 slot = baseEq + i;
        if (slot < EQ_CAP) eq[(size_t)p * EQ_CAP + slot] = leq[i];
    }
}

// ---------------- fused eqsel + featurize (one launch; no cross-block dependency) ----------------
__global__ __launch_bounds__(256) void k_eqfeat(Ptrs P, const u32* __restrict__ ecnt,
                       const int* __restrict__ kneed, const int* __restrict__ g0,
                       const u64* __restrict__ eq, const int* __restrict__ sel,
                       u64* __restrict__ key64, float* __restrict__ csc,
                       float* __restrict__ cbox, float* __restrict__ cobox) {
    int b = blockIdx.x, t = threadIdx.x;
    if (b < 10) {
        int p = b;
        int E = (int)ecnt[p]; if (E > EQ_CAP) E = EQ_CAP;
        int KF = kneed[p]; int G0 = g0[p];
        __shared__ u64 a[EQ_CAP];
        for (int i = t; i < E; i += 256) a[i] = eq[(size_t)p * EQ_CAP + i];
        __syncthreads();
        u64 mine[8]; int rk[8];
        #pragma unroll
        for (int q = 0; q < 8; ++q) {
            int i = t + q * 256;
            mine[q] = (i < E) ? a[i] : 0ULL;
            rk[q] = 0;
        }
        for (int j = 0; j < E; ++j) {
            u64 v = a[j];                            // uniform index -> LDS broadcast
            #pragma unroll
            for (int q = 0; q < 8; ++q) rk[q] += (v > mine[q]) ? 1 : 0;
        }
        #pragma unroll
        for (int q = 0; q < 8; ++q) {
            int i = t + q * 256;
            if (i < E && rk[q] < KF) {
                int m = (int)(0xFFFFFu ^ (u32)(mine[q] & 0xFFFFFu));
                featOne(P, p, G0 + rk[q], m, key64, csc, cbox, cobox);
            }
        }
    } else {
        for (int idx = (b - 10) * 256 + t; idx < 10 * K_PER_LVL; idx += 40 * 256) {
            int p = idx / K_PER_LVL, s = idx - p * K_PER_LVL;
            if (s < g0[p]) featOne(P, p, s, sel[p * K_PER_LVL + s], key64, csc, cbox, cobox);
        }
    }
}

// ---------------- fused: rank partials (atomic accumulate) + IoU edges ----------------
__global__ __launch_bounds__(256) void k_redge(const u64* __restrict__ key64, u32* __restrict__ rankArr,
                                               const float* __restrict__ cobox,
                                               u32* __restrict__ gE, u32* __restrict__ gPairs) {
    int n = blockIdx.y;
    int x = blockIdx.x;
    __shared__ u64 kj[RNK_JB];
    __shared__ float cb[64][4];
    if (x < RNK_TILES) {
        // ---- rank partials: accumulate straight into rank[] (zeroed per launch) ----
        int i0 = (x / 20) * RNK_IB;
        int j0 = (x % 20) * RNK_JB;
        const u64* kb = key64 + (size_t)n * KTOT;
        for (int t = threadIdx.x; t < RNK_JB; t += 256) kj[t] = kb[j0 + t];
        __syncthreads();
        int i1 = i0 + threadIdx.x, i2 = i1 + 256;
        u64 k1 = (i1 < KTOT) ? kb[i1] : ~0ULL;
        u64 k2 = (i2 < KTOT) ? kb[i2] : ~0ULL;
        u32 r1 = 0, r2 = 0;
        #pragma unroll 10
        for (int j = 0; j < RNK_JB; ++j) {
            u64 v = kj[j];
            r1 += (v > k1) ? 1u : 0u;
            r2 += (v > k2) ? 1u : 0u;
        }
        if (i1 < KTOT && r1) atomicAdd(&rankArr[n * KTOT + i1], r1);
        if (i2 < KTOT && r2) atomicAdd(&rankArr[n * KTOT + i2], r2);
        return;
    }
    // ---- edge tile: decode e -> (bi, bj) with bj in [4*bi, 78] ----
    int e = x - RNK_TILES, bi = 0;
    while (true) { int c = 79 - 4 * bi; if (e < c) break; e -= c; ++bi; }
    int bj = 4 * bi + e;
    int i = bi * 256 + threadIdx.x;
    int j0 = bj * 64;
    if (threadIdx.x < 64) {
        int jl = j0 + threadIdx.x;
        if (jl < KTOT) {
            cb[threadIdx.x][0] = cobox[(size_t)(n * KTOT + jl) * 4 + 0];
            cb[threadIdx.x][1] = cobox[(size_t)(n * KTOT + jl) * 4 + 1];
            cb[threadIdx.x][2] = cobox[(size_t)(n * KTOT + jl) * 4 + 2];
            cb[threadIdx.x][3] = cobox[(size_t)(n * KTOT + jl) * 4 + 3];
        } else {
            cb[threadIdx.x][0] = 0.f; cb[threadIdx.x][1] = 0.f;
            cb[threadIdx.x][2] = 0.f; cb[threadIdx.x][3] = 0.f;
        }
    }
    __syncthreads();
    if (i >= KTOT) return;
    float x1 = cobox[(size_t)(n * KTOT + i) * 4 + 0];
    float y1 = cobox[(size_t)(n * KTOT + i) * 4 + 1];
    float x2 = cobox[(size_t)(n * KTOT + i) * 4 + 2];
    float y2 = cobox[(size_t)(n * KTOT + i) * 4 + 3];
    float areai = fmaxf(x2 - x1, 0.f) * fmaxf(y2 - y1, 0.f);
    int lim = KTOT - j0; if (lim > 64) lim = 64;
    for (int jj = 0; jj < lim; ++jj) {
        int j = j0 + jj;
        if (j <= i) continue;
        float bx1 = cb[jj][0], by1 = cb[jj][1], bx2 = cb[jj][2], by2 = cb[jj][3];
        float areaj = fmaxf(bx2 - bx1, 0.f) * fmaxf(by2 - by1, 0.f);
        float ltx = fmaxf(x1, bx1), lty = fmaxf(y1, by1);
        float rbx = fminf(x2, bx2), rby = fminf(y2, by2);
        float iw = fmaxf(rbx - ltx, 0.f), ih = fmaxf(rby - lty, 0.f);
        float inter = iw * ih;
        float iou = inter / (areai + areaj - inter + 1e-9f);
        if (iou > 0.7f) {
            u32 pos = atomicAdd(&gE[n], 1u);
            if (pos < ECAP) gPairs[(size_t)n * ECAP + pos] = ((u32)i << 13) | (u32)j;  // original indices
        }
    }
}

// ---------------- greedy NMS sweep over sparse CSR (inverse-permutation gather) ----------------
__global__ __launch_bounds__(256, 1) void k_nms(const float* __restrict__ csc,
                      const float* __restrict__ cbox, const u32* __restrict__ rankArr,
                      const u32* __restrict__ gE, u32* __restrict__ gPairs,
                      u16* __restrict__ gEdges, float* __restrict__ out) {
    int n = blockIdx.x, tid = threadIdx.x;
    int lane = tid & 63, wv = tid >> 6;          // 4 waves
    __shared__ u32 cnt[KTOT];                    // 20 KB (count, then fill cursor)
    __shared__ u32 offs[KTOT + 1];               // 20 KB
    __shared__ u16 edges[LECAP];                 // 48 KB
    __shared__ u16 invL[KTOT];                   // 10 KB: rank -> original index
    __shared__ u32 rem32[160];                   // dead bitmap (2 u32 per 64-word)
    __shared__ u32 colLo[64], colHi[64];
    __shared__ u32 scanb[256];
    __shared__ int picksS;

    for (int i = tid; i < KTOT; i += 256) cnt[i] = 0;
    if (tid < 160) rem32[tid] = 0xFFFFFFFFu;
    // inverse permutation (ranks are a permutation of [0,KTOT): keys unique)
    for (int i = tid; i < KTOT; i += 256) invL[rankArr[n * KTOT + i]] = (u16)i;
    __syncthreads();
    for (int w = wv; w < 79; w += 4) {
        int i = w * 64 + lane;
        bool dead = (i >= KTOT) || !(csc[n * KTOT + (int)invL[i]] > -INFINITY);
        u64 db = __ballot(dead);
        if (lane == 0) { rem32[2 * w] = (u32)db; rem32[2 * w + 1] = (u32)(db >> 32); }
    }
    __syncthreads();

    // ---- CSR count pass: remap pairs (orig idx) -> ranks, store remapped in place ----
    // (pairs rewritten fresh by k_redge each launch -> replay-safe)
    int E = (int)gE[n]; if (E > ECAP) E = ECAP;
    for (int k = tid; k < E; k += 256) {
        u32 p = gPairs[(size_t)n * ECAP + k];
        u32 ra = rankArr[n * KTOT + (p >> 13)], rb = rankArr[n * KTOT + (p & 0x1FFFu)];
        u32 src = ra < rb ? ra : rb, dst = ra < rb ? rb : ra;
        gPairs[(size_t)n * ECAP + k] = (src << 13) | dst;
        atomicAdd(&cnt[src], 1u);
    }
    __syncthreads();
    u32 s = 0; int base = tid * 20;
    if (tid < 250) for (int q = 0; q < 20; ++q) s += cnt[base + q];
    scanb[tid] = s;
    __syncthreads();
    for (int off = 1; off < 256; off <<= 1) {
        u32 v = (tid >= off) ? scanb[tid - off] : 0;
        __syncthreads();
        scanb[tid] += v;
        __syncthreads();
    }
    u32 tbase = (tid == 0) ? 0u : scanb[tid - 1];
    if (tid < 250) {
        u32 run = tbase;
        for (int q = 0; q < 20; ++q) { offs[base + q] = run; run += cnt[base + q]; }
    }
    if (tid == 0) offs[KTOT] = scanb[255];
    __syncthreads();
    for (int i = tid; i < KTOT; i += 256) cnt[i] = 0;
    __syncthreads();
    // ---- CSR fill pass: one load per edge (pairs already remapped) ----
    for (int k = tid; k < E; k += 256) {
        u32 p = gPairs[(size_t)n * ECAP + k];
        u32 src = p >> 13, dst = p & 0x1FFFu;
        u32 slot = offs[src] + atomicAdd(&cnt[src], 1u);
        if (slot < LECAP) edges[slot] = (u16)dst;
        else gEdges[(size_t)n * ECAP + slot] = (u16)dst;
    }
    __syncthreads();

    // ---- wave-0 sweep: rank order; output gathered via invL ----
    if (wv == 0) {
        int picks = 0;
        for (int w = 0; w < 79 && picks < 1000; ++w) {
            u64 rw = ((u64)rem32[2 * w + 1] << 32) | rem32[2 * w];
            u64 alive = ~rw;
            if (alive == 0ULL) continue;
            int c = w * 64 + lane;
            bool amAlive = ((alive >> lane) & 1ULL) != 0ULL;
            int e0 = 0, e1 = 0;
            if (amAlive) { e0 = (int)offs[c]; e1 = (int)offs[c + 1]; }
            colLo[lane] = 0; colHi[lane] = 0;
            bool anyIntra = false;
            for (int k = e0; k < e1; ++k) {
                int dst = (k < LECAP) ? (int)edges[k] : (int)gEdges[(size_t)n * ECAP + k];
                if ((dst >> 6) == w) {
                    if (lane < 32) atomicOr(&colLo[dst & 63], 1u << lane);
                    else           atomicOr(&colHi[dst & 63], 1u << (lane - 32));
                    anyIntra = true;
                }
            }
            u64 cm;
            if (__ballot(anyIntra) == 0ULL) {
                cm = alive;
            } else {
                u64 col = ((u64)colHi[lane] << 32) | colLo[lane];
                cm = 0ULL;
                u64 remb = alive;                // uniform across lanes -> converged shfl
                while (remb) {
                    int e = __builtin_ctzll(remb);
                    remb &= remb - 1ULL;
                    u64 ce = __shfl(col, e);
                    if ((cm & ce) == 0ULL) cm |= (1ULL << e);
                }
            }
            int allowed = 1000 - picks;
            int ncom = __popcll(cm);
            while (ncom > allowed) { cm &= ~(1ULL << (63 - __clzll(cm))); --ncom; }
            if ((cm >> lane) & 1ULL) {
                int pos = picks + (int)__popcll(cm & ((1ULL << lane) - 1ULL));
                int orig = (int)invL[c];
                const float* bp = &cbox[(size_t)(n * KTOT + orig) * 4];
                float* op = &out[(n * 1000 + pos) * 5];
                op[0] = bp[0]; op[1] = bp[1]; op[2] = bp[2]; op[3] = bp[3];
                op[4] = csc[n * KTOT + orig];
                for (int k = e0; k < e1; ++k) {
                    int dst = (k < LECAP) ? (int)edges[k] : (int)gEdges[(size_t)n * ECAP + k];
                    atomicOr(&rem32[dst >> 5], 1u << (dst & 31));
                }
            }
            picks += ncom;
        }
        if (lane == 0) picksS = picks;
    }
    __syncthreads();
    int picksF = picksS;
    int basec = (n * 1000 + picksF) * 5, cntz = (1000 - picksF) * 5;
    for (int t = tid; t < cntz; t += 256) out[basec + t] = 0.f;
}

// ---------------- workspace layout ----------------
constexpr size_t OFF_HIST   = 0;                                       // zeroed region start
constexpr size_t OFF_GCNT   = OFF_HIST + 10 * BINS * 4;
constexpr size_t OFF_ECNT   = OFF_GCNT + 64;
constexpr size_t OFF_GEC    = OFF_ECNT + 64;                           // edge counters (2 u32)
constexpr size_t OFF_RANK   = OFF_GEC + 64;                            // u32[NIMG*KTOT] (zeroed)
constexpr size_t ZERO_WORDS = (10 * BINS * 4 + 192 + (size_t)NIMG * KTOT * 4) / 4;
constexpr size_t OFF_BINB   = OFF_RANK + (size_t)NIMG * KTOT * 4;      // 40000 B, 64-aligned
constexpr size_t OFF_KNEED  = OFF_BINB + 64;
constexpr size_t OFF_G0     = OFF_KNEED + 64;
constexpr size_t OFF_SEL    = OFF_G0 + 64;
constexpr size_t OFF_EQ     = OFF_SEL + 10 * K_PER_LVL * 4;            // 8-aligned
constexpr size_t OFF_KEY64  = OFF_EQ + (size_t)10 * EQ_CAP * 8;
constexpr size_t OFF_CSC    = OFF_KEY64 + (size_t)NIMG * KTOT * 8;
constexpr size_t OFF_CBOX   = OFF_CSC + (size_t)NIMG * KTOT * 4;
constexpr size_t OFF_COBOX  = OFF_CBOX + (size_t)NIMG * KTOT * 16;
constexpr size_t OFF_PAIRS  = OFF_COBOX + (size_t)NIMG * KTOT * 16;    // u32[NIMG*ECAP]
constexpr size_t OFF_ESPILL = OFF_PAIRS + (size_t)NIMG * ECAP * 4;     // u16[NIMG*ECAP]
constexpr size_t WS_NEEDED  = OFF_ESPILL + (size_t)NIMG * ECAP * 2;

extern "C" void kernel_launch(void* const* d_in, const int* in_sizes, int n_in,
                              void* d_out, int out_size, void* d_ws, size_t ws_size,
                              hipStream_t stream) {
    if (ws_size < WS_NEEDED) return;

    // Detect input ordering from sizes: dict order interleaves (obj0,box0,...)
    bool dictOrder = (in_sizes[1] > in_sizes[0]);
    Ptrs P;
    for (int l = 0; l < 5; ++l) {
        P.o[l] = (const float*)d_in[dictOrder ? (2 * l)     : l];
        P.b[l] = (const float*)d_in[dictOrder ? (2 * l + 1) : (5 + l)];
    }
    char* ws = (char*)d_ws;
    u32*   hist   = (u32*)(ws + OFF_HIST);
    u32*   gcnt   = (u32*)(ws + OFF_GCNT);
    u32*   ecnt   = (u32*)(ws + OFF_ECNT);
    u32*   gec    = (u32*)(ws + OFF_GEC);
    u32*   rankA  = (u32*)(ws + OFF_RANK);
    int*   binB   = (int*)(ws + OFF_BINB);
    int*   kneed  = (int*)(ws + OFF_KNEED);
    int*   g0     = (int*)(ws + OFF_G0);
    int*   sel    = (int*)(ws + OFF_SEL);
    u64*   eq     = (u64*)(ws + OFF_EQ);
    u64*   key64  = (u64*)(ws + OFF_KEY64);
    float* csc    = (float*)(ws + OFF_CSC);
    float* cbox   = (float*)(ws + OFF_CBOX);
    float* cobox  = (float*)(ws + OFF_COBOX);
    u32*   pairs  = (u32*)(ws + OFF_PAIRS);
    u16*   espill = (u16*)(ws + OFF_ESPILL);
    float* out    = (float*)d_out;

    k_zero<<<dim3(64), 256, 0, stream>>>(hist, (int)ZERO_WORDS);
    k_hist<<<dim3(32, 10), 256, 0, stream>>>(P, hist);
    k_resolve<<<10, 256, 0, stream>>>(hist, binB, kneed, g0);
    k_compact<<<dim3(64, 10), 256, 0, stream>>>(P, binB, gcnt, ecnt, sel, eq);
    k_eqfeat<<<50, 256, 0, stream>>>(P, ecnt, kneed, g0, eq, sel, key64, csc, cbox, cobox);
    k_redge<<<dim3(RNK_TILES + EDGE_TILES, NIMG), 256, 0, stream>>>(key64, rankA, cobox, gec, pairs);
    k_nms<<<NIMG, 256, 0, stream>>>(csc, cbox, rankA, gec, pairs, espill, out);
}